// Round 1
// baseline (3727.497 us; speedup 1.0000x reference)
//
#include <hip/hip_runtime.h>
#include <math.h>

// Problem constants (from reference)
constexpr int N_ = 50000;
constexpr int E_ = 400000;
constexpr int H_ = 128;
constexpr int OUT_ = 64;
constexpr int B_ = 3;
constexpr int ITERS_ = 2;
constexpr float EPS_ = 0.01f;

// ---------------------------------------------------------------------------
// Generic register-blocked matvec: Y[r, 0..127] = act(X[r, :] @ W^T + bias)
// W is [128,128] row-major (row = output channel). T rows per 128-thread block.
// ACT: 0=none, 1=relu, 2=tanh
// ---------------------------------------------------------------------------
template <int ACT, bool HAS_BIAS>
__global__ __launch_bounds__(128) void matvec128_k(
    const float* __restrict__ X, const float* __restrict__ W,
    const float* __restrict__ bias, float* __restrict__ Y, int nrows) {
  constexpr int T = 16;
  __shared__ float xs[T][H_];
  const int tid = threadIdx.x;
  const int r0 = blockIdx.x * T;
#pragma unroll
  for (int t = 0; t < T; ++t) {
    int row = r0 + t;
    xs[t][tid] = (row < nrows) ? X[(size_t)row * H_ + tid] : 0.f;
  }
  __syncthreads();
  float acc[T];
#pragma unroll
  for (int t = 0; t < T; ++t) acc[t] = 0.f;
  const float4* W4 = (const float4*)(W + (size_t)tid * H_);
#pragma unroll 8
  for (int k4 = 0; k4 < H_ / 4; ++k4) {
    float4 w = W4[k4];
#pragma unroll
    for (int t = 0; t < T; ++t) {
      float4 xv = *(const float4*)&xs[t][k4 * 4];
      acc[t] = fmaf(w.x, xv.x, acc[t]);
      acc[t] = fmaf(w.y, xv.y, acc[t]);
      acc[t] = fmaf(w.z, xv.z, acc[t]);
      acc[t] = fmaf(w.w, xv.w, acc[t]);
    }
  }
  float b = HAS_BIAS ? bias[tid] : 0.f;
#pragma unroll
  for (int t = 0; t < T; ++t) {
    int row = r0 + t;
    if (row < nrows) {
      float y = acc[t] + b;
      if (ACT == 1) y = fmaxf(y, 0.f);
      if (ACT == 2) y = tanhf(y);
      Y[(size_t)row * H_ + tid] = y;
    }
  }
}

// ---------------------------------------------------------------------------
// Edge resistance: for each edge e:
//   ef = [x[src], x[dst]]  (256)
//   h  = relu(W1 @ ef + b1)   (W1 is [128,256])
//   r  = | w2 . h + b2 |
//   r_out[e] = r;  atomicAdd(deg[src[e]], r)
// TE edges per 128-thread block. Thread j owns output channel j.
// ---------------------------------------------------------------------------
template <int TE>
__global__ __launch_bounds__(128) void edge_resist_k(
    const float* __restrict__ x, const int* __restrict__ src,
    const int* __restrict__ dst, const float* __restrict__ W1,
    const float* __restrict__ b1, const float* __restrict__ w2,
    const float* __restrict__ b2, float* __restrict__ r_out,
    float* __restrict__ deg, int nE) {
  __shared__ float ef[TE][2 * H_];
  __shared__ float wsum[2][TE];
  const int tid = threadIdx.x;
  const int e0 = blockIdx.x * TE;
#pragma unroll
  for (int t = 0; t < TE; ++t) {
    int e = e0 + t;
    int s = 0, d = 0;
    if (e < nE) { s = src[e]; d = dst[e]; }
    ef[t][tid] = x[(size_t)s * H_ + tid];
    ef[t][H_ + tid] = x[(size_t)d * H_ + tid];
  }
  __syncthreads();
  float acc[TE];
#pragma unroll
  for (int t = 0; t < TE; ++t) acc[t] = 0.f;
  const float4* W4 = (const float4*)(W1 + (size_t)tid * (2 * H_));
#pragma unroll 4
  for (int k4 = 0; k4 < (2 * H_) / 4; ++k4) {
    float4 w = W4[k4];
#pragma unroll
    for (int t = 0; t < TE; ++t) {
      float4 xv = *(const float4*)&ef[t][k4 * 4];
      acc[t] = fmaf(w.x, xv.x, acc[t]);
      acc[t] = fmaf(w.y, xv.y, acc[t]);
      acc[t] = fmaf(w.z, xv.z, acc[t]);
      acc[t] = fmaf(w.w, xv.w, acc[t]);
    }
  }
  const float bb = b1[tid];
  const float w2v = w2[tid];
  float p[TE];
#pragma unroll
  for (int t = 0; t < TE; ++t) p[t] = fmaxf(acc[t] + bb, 0.f) * w2v;
  // reduce across 128 threads (2 waves)
#pragma unroll
  for (int t = 0; t < TE; ++t) {
    float v = p[t];
#pragma unroll
    for (int off = 32; off > 0; off >>= 1) v += __shfl_xor(v, off);
    p[t] = v;
  }
  if ((tid & 63) == 0) {
    int wave = tid >> 6;
#pragma unroll
    for (int t = 0; t < TE; ++t) wsum[wave][t] = p[t];
  }
  __syncthreads();
  if (tid < TE) {
    int e = e0 + tid;
    if (e < nE) {
      float rv = fabsf(wsum[0][tid] + wsum[1][tid] + b2[0]);
      r_out[e] = rv;
      atomicAdd(&deg[src[e]], rv);
    }
  }
}

// ---------------------------------------------------------------------------
// Scatter: agg[dst[e], :] += r[e] * f[src[e], :]   (atomic)
// 2 edges per 256-thread block step, grid-stride.
// ---------------------------------------------------------------------------
__global__ __launch_bounds__(256) void scatter_k(
    const float* __restrict__ f, const int* __restrict__ src,
    const int* __restrict__ dst, const float* __restrict__ r,
    float* __restrict__ agg, int nE) {
  const int j = threadIdx.x & (H_ - 1);
  for (int e = blockIdx.x * 2 + (threadIdx.x >> 7); e < nE;
       e += gridDim.x * 2) {
    float rv = r[e];
    float val = rv * f[(size_t)src[e] * H_ + j];
    atomicAdd(&agg[(size_t)dst[e] * H_ + j], val);
  }
}

// ---------------------------------------------------------------------------
// Update: per node n, channel j:
//   diss = relu(x[n] @ Wd^T + bd)[j]
//   conv = deg[n]*f[n,j] - agg[n,j]
//   v = v - EPS*(conv + diss*v);  x = x + EPS*v
// ---------------------------------------------------------------------------
template <int T>
__global__ __launch_bounds__(128) void update_k(
    float* __restrict__ x, float* __restrict__ v, const float* __restrict__ f,
    const float* __restrict__ agg, const float* __restrict__ deg,
    const float* __restrict__ Wd, const float* __restrict__ bd, int nrows) {
  __shared__ float xs[T][H_];
  const int tid = threadIdx.x;
  const int r0 = blockIdx.x * T;
#pragma unroll
  for (int t = 0; t < T; ++t) {
    int row = r0 + t;
    xs[t][tid] = (row < nrows) ? x[(size_t)row * H_ + tid] : 0.f;
  }
  __syncthreads();
  float acc[T];
#pragma unroll
  for (int t = 0; t < T; ++t) acc[t] = 0.f;
  const float4* W4 = (const float4*)(Wd + (size_t)tid * H_);
#pragma unroll 8
  for (int k4 = 0; k4 < H_ / 4; ++k4) {
    float4 w = W4[k4];
#pragma unroll
    for (int t = 0; t < T; ++t) {
      float4 xv = *(const float4*)&xs[t][k4 * 4];
      acc[t] = fmaf(w.x, xv.x, acc[t]);
      acc[t] = fmaf(w.y, xv.y, acc[t]);
      acc[t] = fmaf(w.z, xv.z, acc[t]);
      acc[t] = fmaf(w.w, xv.w, acc[t]);
    }
  }
  const float bb = bd[tid];
#pragma unroll
  for (int t = 0; t < T; ++t) {
    int row = r0 + t;
    if (row < nrows) {
      float diss = fmaxf(acc[t] + bb, 0.f);
      size_t idx = (size_t)row * H_ + tid;
      float fv = f[idx];
      float av = agg[idx];
      float conv = deg[row] * fv - av;
      float vv = v[idx];
      vv = vv - EPS_ * (conv + diss * vv);
      v[idx] = vv;
      x[idx] = xs[t][tid] + EPS_ * vv;
    }
  }
}

// ---------------------------------------------------------------------------
// Readout: out[r, 0..63] = X[r,:] @ ro_w^T + ro_b. 64-thread block, T rows.
// ---------------------------------------------------------------------------
template <int T>
__global__ __launch_bounds__(64) void readout_k(
    const float* __restrict__ X, const float* __restrict__ W,
    const float* __restrict__ bias, float* __restrict__ out, int nrows) {
  __shared__ float xs[T][H_];
  const int tid = threadIdx.x;
  const int r0 = blockIdx.x * T;
#pragma unroll
  for (int t = 0; t < T; ++t) {
    int row = r0 + t;
#pragma unroll
    for (int kk = tid; kk < H_; kk += 64)
      xs[t][kk] = (row < nrows) ? X[(size_t)row * H_ + kk] : 0.f;
  }
  __syncthreads();
  float acc[T];
#pragma unroll
  for (int t = 0; t < T; ++t) acc[t] = 0.f;
  const float4* W4 = (const float4*)(W + (size_t)tid * H_);
#pragma unroll 8
  for (int k4 = 0; k4 < H_ / 4; ++k4) {
    float4 w = W4[k4];
#pragma unroll
    for (int t = 0; t < T; ++t) {
      float4 xv = *(const float4*)&xs[t][k4 * 4];
      acc[t] = fmaf(w.x, xv.x, acc[t]);
      acc[t] = fmaf(w.y, xv.y, acc[t]);
      acc[t] = fmaf(w.z, xv.z, acc[t]);
      acc[t] = fmaf(w.w, xv.w, acc[t]);
    }
  }
  const float b = bias[tid];
#pragma unroll
  for (int t = 0; t < T; ++t) {
    int row = r0 + t;
    if (row < nrows) out[(size_t)row * OUT_ + tid] = acc[t] + b;
  }
}

extern "C" void kernel_launch(void* const* d_in, const int* in_sizes, int n_in,
                              void* d_out, int out_size, void* d_ws,
                              size_t ws_size, hipStream_t stream) {
  const float* x_in = (const float*)d_in[0];
  const int* ei = (const int*)d_in[1];
  const int* src = ei;
  const int* dst = ei + E_;
  const float* emb_w = (const float*)d_in[2];
  const float* emb_b = (const float*)d_in[3];
  const float* lap_w = (const float*)d_in[4];
  const float* er_w1 = (const float*)d_in[5];
  const float* er_b1 = (const float*)d_in[6];
  const float* er_w2 = (const float*)d_in[7];
  const float* er_b2 = (const float*)d_in[8];
  const float* diss_w = (const float*)d_in[9];
  const float* diss_b = (const float*)d_in[10];
  const float* mlp_w1 = (const float*)d_in[11];
  const float* mlp_b1 = (const float*)d_in[12];
  const float* mlp_w2 = (const float*)d_in[13];
  const float* mlp_b2 = (const float*)d_in[14];
  const float* ro_w = (const float*)d_in[15];
  const float* ro_b = (const float*)d_in[16];
  float* out = (float*)d_out;

  // workspace layout (floats)
  float* ws = (float*)d_ws;
  float* x = ws;                    // N*128
  float* v = x + (size_t)N_ * H_;   // N*128
  float* f = v + (size_t)N_ * H_;   // N*128 (also mlp intermediate)
  float* agg = f + (size_t)N_ * H_; // N*128
  float* r = agg + (size_t)N_ * H_; // E
  float* deg = r + E_;              // N

  const int mv_grid = (N_ + 15) / 16;         // 3125
  const int er_grid = (E_ + 15) / 16;         // 25000
  const size_t nodeF_bytes = (size_t)N_ * H_ * sizeof(float);

  // x = x_in @ emb_w^T + emb_b
  matvec128_k<0, true><<<mv_grid, 128, 0, stream>>>(x_in, emb_w, emb_b, x, N_);

  for (int b = 0; b < B_; ++b) {
    const float* W1 = er_w1 + (size_t)b * H_ * 2 * H_;
    const float* b1 = er_b1 + (size_t)b * H_;
    const float* w2 = er_w2 + (size_t)b * H_;
    const float* b2 = er_b2 + b;
    const float* Wl = lap_w + (size_t)b * H_ * H_;
    const float* Wd = diss_w + (size_t)b * H_ * H_;
    const float* bd = diss_b + (size_t)b * H_;
    const float* Wm1 = mlp_w1 + (size_t)b * H_ * H_;
    const float* bm1 = mlp_b1 + (size_t)b * H_;
    const float* Wm2 = mlp_w2 + (size_t)b * H_ * H_;
    const float* bm2 = mlp_b2 + (size_t)b * H_;

    hipMemsetAsync(deg, 0, (size_t)N_ * sizeof(float), stream);
    edge_resist_k<16><<<er_grid, 128, 0, stream>>>(x, src, dst, W1, b1, w2,
                                                   b2, r, deg, E_);
    hipMemsetAsync(v, 0, nodeF_bytes, stream);
    for (int it = 0; it < ITERS_; ++it) {
      matvec128_k<0, false><<<mv_grid, 128, 0, stream>>>(x, Wl, nullptr, f,
                                                         N_);
      hipMemsetAsync(agg, 0, nodeF_bytes, stream);
      scatter_k<<<4096, 256, 0, stream>>>(f, src, dst, r, agg, E_);
      update_k<16><<<mv_grid, 128, 0, stream>>>(x, v, f, agg, deg, Wd, bd,
                                                N_);
    }
    // x = tanh(x @ Wm1^T + bm1) @ Wm2^T + bm2   (f as intermediate)
    matvec128_k<2, true><<<mv_grid, 128, 0, stream>>>(x, Wm1, bm1, f, N_);
    matvec128_k<0, true><<<mv_grid, 128, 0, stream>>>(f, Wm2, bm2, x, N_);
  }
  readout_k<16><<<mv_grid, 64, 0, stream>>>(x, ro_w, ro_b, out, N_);
}

// Round 2
// 2272.138 us; speedup vs baseline: 1.6405x; 1.6405x over previous
//
#include <hip/hip_runtime.h>
#include <math.h>

constexpr int N_ = 50000;
constexpr int E_ = 400000;
constexpr int H_ = 128;
constexpr int OUT_ = 64;
constexpr int B_ = 3;
constexpr int ITERS_ = 2;
constexpr float EPS_ = 0.01f;

// ---------------------------------------------------------------------------
// Single GEMV: Y[r, j] = act(X[r,:] . W[j,:] + bias[j]); W row-major [128,128].
// 128 threads (thread j = output channel), T rows per block.
// X row loads are wave-uniform -> scalar loads (s_load), freeing VALU slots.
// ACT: 0 none, 1 relu, 2 tanh
// ---------------------------------------------------------------------------
template <int ACT, bool HASB, int T>
__global__ __launch_bounds__(128) void gemv_k(
    const float* __restrict__ X, const float* __restrict__ W,
    const float* __restrict__ bias, float* __restrict__ Y) {
  const int tid = threadIdx.x;
  const size_t r0 = (size_t)blockIdx.x * T;
  float acc[T];
#pragma unroll
  for (int t = 0; t < T; ++t) acc[t] = 0.f;
  const float4* W4 = (const float4*)(W + (size_t)tid * H_);
#pragma unroll 4
  for (int k4 = 0; k4 < H_ / 4; ++k4) {
    float4 w = W4[k4];
#pragma unroll
    for (int t = 0; t < T; ++t) {
      const float4 xv = *(const float4*)(X + (r0 + t) * H_ + k4 * 4);
      acc[t] = fmaf(w.x, xv.x, acc[t]);
      acc[t] = fmaf(w.y, xv.y, acc[t]);
      acc[t] = fmaf(w.z, xv.z, acc[t]);
      acc[t] = fmaf(w.w, xv.w, acc[t]);
    }
  }
  const float b = HASB ? bias[tid] : 0.f;
#pragma unroll
  for (int t = 0; t < T; ++t) {
    float y = acc[t] + b;
    if (ACT == 1) y = fmaxf(y, 0.f);
    if (ACT == 2) y = tanhf(y);
    Y[(r0 + t) * H_ + tid] = y;
  }
}

// ---------------------------------------------------------------------------
// Dual GEMV sharing the same input rows: two weight matrices (row stride WS),
// two outputs. Used for (P1,P2) [WS=256] and (f,diss) [WS=128].
// ---------------------------------------------------------------------------
template <int ACT0, int ACT1, bool HB0, bool HB1, int T, int WS>
__global__ __launch_bounds__(128) void gemv2_k(
    const float* __restrict__ X, const float* __restrict__ W0,
    const float* __restrict__ b0p, const float* __restrict__ W1,
    const float* __restrict__ b1p, float* __restrict__ Y0,
    float* __restrict__ Y1) {
  const int tid = threadIdx.x;
  const size_t r0 = (size_t)blockIdx.x * T;
  float acc0[T], acc1[T];
#pragma unroll
  for (int t = 0; t < T; ++t) { acc0[t] = 0.f; acc1[t] = 0.f; }
  const float4* W04 = (const float4*)(W0 + (size_t)tid * WS);
  const float4* W14 = (const float4*)(W1 + (size_t)tid * WS);
#pragma unroll 4
  for (int k4 = 0; k4 < H_ / 4; ++k4) {
    float4 w0 = W04[k4];
    float4 w1 = W14[k4];
#pragma unroll
    for (int t = 0; t < T; ++t) {
      const float4 xv = *(const float4*)(X + (r0 + t) * H_ + k4 * 4);
      acc0[t] = fmaf(w0.x, xv.x, acc0[t]);
      acc0[t] = fmaf(w0.y, xv.y, acc0[t]);
      acc0[t] = fmaf(w0.z, xv.z, acc0[t]);
      acc0[t] = fmaf(w0.w, xv.w, acc0[t]);
      acc1[t] = fmaf(w1.x, xv.x, acc1[t]);
      acc1[t] = fmaf(w1.y, xv.y, acc1[t]);
      acc1[t] = fmaf(w1.z, xv.z, acc1[t]);
      acc1[t] = fmaf(w1.w, xv.w, acc1[t]);
    }
  }
  const float b0 = HB0 ? b0p[tid] : 0.f;
  const float b1 = HB1 ? b1p[tid] : 0.f;
#pragma unroll
  for (int t = 0; t < T; ++t) {
    float y0 = acc0[t] + b0;
    float y1 = acc1[t] + b1;
    if (ACT0 == 1) y0 = fmaxf(y0, 0.f);
    if (ACT0 == 2) y0 = tanhf(y0);
    if (ACT1 == 1) y1 = fmaxf(y1, 0.f);
    if (ACT1 == 2) y1 = tanhf(y1);
    Y0[(r0 + t) * H_ + tid] = y0;
    Y1[(r0 + t) * H_ + tid] = y1;
  }
}

// ---------------------------------------------------------------------------
// Readout: out[r, 0..63] = X[r,:] . W[j,:] + b[j]. 64 threads, T rows.
// ---------------------------------------------------------------------------
template <int T>
__global__ __launch_bounds__(64) void readout_k(
    const float* __restrict__ X, const float* __restrict__ W,
    const float* __restrict__ bias, float* __restrict__ out) {
  const int tid = threadIdx.x;
  const size_t r0 = (size_t)blockIdx.x * T;
  float acc[T];
#pragma unroll
  for (int t = 0; t < T; ++t) acc[t] = 0.f;
  const float4* W4 = (const float4*)(W + (size_t)tid * H_);
#pragma unroll 4
  for (int k4 = 0; k4 < H_ / 4; ++k4) {
    float4 w = W4[k4];
#pragma unroll
    for (int t = 0; t < T; ++t) {
      const float4 xv = *(const float4*)(X + (r0 + t) * H_ + k4 * 4);
      acc[t] = fmaf(w.x, xv.x, acc[t]);
      acc[t] = fmaf(w.y, xv.y, acc[t]);
      acc[t] = fmaf(w.z, xv.z, acc[t]);
      acc[t] = fmaf(w.w, xv.w, acc[t]);
    }
  }
  const float b = bias[tid];
#pragma unroll
  for (int t = 0; t < T; ++t) out[(r0 + t) * OUT_ + tid] = acc[t] + b;
}

// ---------------------------------------------------------------------------
// Edge resistance from P tables: r = |w2 . relu(P1[src]+P2[dst]) + b2|
// (b1 is folded into P1). 32 lanes per edge, 4 ch each; 8 edges / 256-block.
// Also deg[src] += r (scalar atomic).
// ---------------------------------------------------------------------------
__global__ __launch_bounds__(256) void edge_r_k(
    const float* __restrict__ P1, const float* __restrict__ P2,
    const int* __restrict__ src, const int* __restrict__ dst,
    const float* __restrict__ w2, const float* __restrict__ b2,
    float* __restrict__ r_out, float* __restrict__ deg) {
  const int tid = threadIdx.x;
  const int lane = tid & 63;
  const int half = lane >> 5;
  const int l = lane & 31;
  const int wid = tid >> 6;
  const size_t e = (size_t)blockIdx.x * 8 + wid * 2 + half;
  const float4 wv = *(const float4*)(w2 + l * 4);
  const int s = src[e];
  const int d = dst[e];
  const float4 a = *(const float4*)(P1 + (size_t)s * H_ + l * 4);
  const float4 c = *(const float4*)(P2 + (size_t)d * H_ + l * 4);
  float sum = fmaxf(a.x + c.x, 0.f) * wv.x;
  sum = fmaf(fmaxf(a.y + c.y, 0.f), wv.y, sum);
  sum = fmaf(fmaxf(a.z + c.z, 0.f), wv.z, sum);
  sum = fmaf(fmaxf(a.w + c.w, 0.f), wv.w, sum);
#pragma unroll
  for (int off = 16; off > 0; off >>= 1) sum += __shfl_xor(sum, off);
  if (l == 0) {
    const float rv = fabsf(sum + b2[0]);
    r_out[e] = rv;
    atomicAdd(&deg[s], rv);
  }
}

// ---------------------------------------------------------------------------
// CSR build (by dst), topology-only, once per launch.
// ---------------------------------------------------------------------------
__global__ void hist_k(const int* __restrict__ dst, int* __restrict__ cnt) {
  const int e = blockIdx.x * 256 + threadIdx.x;
  if (e < E_) atomicAdd(&cnt[dst[e]], 1);
}

__global__ __launch_bounds__(1024) void scan_k(int* __restrict__ cnt,
                                               int* __restrict__ rowptr,
                                               int* __restrict__ cursor) {
  __shared__ int part[1024];
  const int tid = threadIdx.x;
  constexpr int CH = (N_ + 1023) / 1024;  // 49
  const int base = tid * CH;
  int s = 0;
  for (int i = 0; i < CH; ++i) {
    const int idx = base + i;
    if (idx < N_) s += cnt[idx];
  }
  part[tid] = s;
  __syncthreads();
  for (int off = 1; off < 1024; off <<= 1) {
    const int v = part[tid];
    const int u = (tid >= off) ? part[tid - off] : 0;
    __syncthreads();
    part[tid] = v + u;
    __syncthreads();
  }
  int run = (tid == 0) ? 0 : part[tid - 1];
  for (int i = 0; i < CH; ++i) {
    const int idx = base + i;
    if (idx < N_) {
      const int c = cnt[idx];  // cnt/cursor may alias: read before write
      rowptr[idx] = run;
      cursor[idx] = run;
      run += c;
    }
  }
  if (tid == 1023) rowptr[N_] = E_;
}

__global__ void permute_k(const int* __restrict__ dst, int* __restrict__ cursor,
                          int* __restrict__ perm) {
  const int e = blockIdx.x * 256 + threadIdx.x;
  if (e < E_) {
    const int p = atomicAdd(&cursor[dst[e]], 1);
    perm[p] = e;
  }
}

// ---------------------------------------------------------------------------
// Fused aggregate + update. One wave per node, lane -> 2 channels (float2).
//   agg = sum_{e: dst[e]=n} r[e] * f[src[e]]
//   conv = deg[n]*f[n] - agg; v -= EPS*(conv + diss*v); x += EPS*v
// FIRST: v starts at 0 (skip v read).
// ---------------------------------------------------------------------------
template <bool FIRST>
__global__ __launch_bounds__(256) void agg_update_k(
    float* __restrict__ x, float* __restrict__ v, const float* __restrict__ f,
    const float* __restrict__ diss, const float* __restrict__ deg,
    const float* __restrict__ r, const int* __restrict__ src,
    const int* __restrict__ rowptr, const int* __restrict__ perm) {
  const int wid = threadIdx.x >> 6;
  const int lane = threadIdx.x & 63;
  const int n = blockIdx.x * 4 + wid;
  const int beg = rowptr[n];
  const int end = rowptr[n + 1];
  const float2* f2 = (const float2*)f;
  float ax = 0.f, ay = 0.f;
  for (int i = beg; i < end; ++i) {
    const int e = perm[i];
    const float rv = r[e];
    const int s = src[e];
    const float2 fv = f2[(size_t)s * 64 + lane];
    ax = fmaf(rv, fv.x, ax);
    ay = fmaf(rv, fv.y, ay);
  }
  const size_t idx = (size_t)n * 64 + lane;
  const float2 fn = f2[idx];
  const float dg = deg[n];
  const float cx = dg * fn.x - ax;
  const float cy = dg * fn.y - ay;
  const float2 ds = ((const float2*)diss)[idx];
  float2 vv;
  if (FIRST) {
    vv.x = -EPS_ * cx;
    vv.y = -EPS_ * cy;
  } else {
    vv = ((const float2*)v)[idx];
    vv.x = vv.x - EPS_ * (cx + ds.x * vv.x);
    vv.y = vv.y - EPS_ * (cy + ds.y * vv.y);
  }
  ((float2*)v)[idx] = vv;
  float2 xv = ((const float2*)x)[idx];
  xv.x += EPS_ * vv.x;
  xv.y += EPS_ * vv.y;
  ((float2*)x)[idx] = xv;
}

extern "C" void kernel_launch(void* const* d_in, const int* in_sizes, int n_in,
                              void* d_out, int out_size, void* d_ws,
                              size_t ws_size, hipStream_t stream) {
  const float* x_in = (const float*)d_in[0];
  const int* ei = (const int*)d_in[1];
  const int* src = ei;
  const int* dst = ei + E_;
  const float* emb_w = (const float*)d_in[2];
  const float* emb_b = (const float*)d_in[3];
  const float* lap_w = (const float*)d_in[4];
  const float* er_w1 = (const float*)d_in[5];
  const float* er_b1 = (const float*)d_in[6];
  const float* er_w2 = (const float*)d_in[7];
  const float* er_b2 = (const float*)d_in[8];
  const float* diss_w = (const float*)d_in[9];
  const float* diss_b = (const float*)d_in[10];
  const float* mlp_w1 = (const float*)d_in[11];
  const float* mlp_b1 = (const float*)d_in[12];
  const float* mlp_w2 = (const float*)d_in[13];
  const float* mlp_b2 = (const float*)d_in[14];
  const float* ro_w = (const float*)d_in[15];
  const float* ro_b = (const float*)d_in[16];
  float* out = (float*)d_out;

  // workspace layout
  const size_t NF = (size_t)N_ * H_;
  float* ws = (float*)d_ws;
  float* x = ws;            // N*128
  float* v = x + NF;        // N*128
  float* A = v + NF;        // N*128  (P1 / f / mlp tmp)
  float* Bb = A + NF;       // N*128  (P2 / diss)
  float* r = Bb + NF;       // E
  float* deg = r + E_;      // N
  int* rowptr = (int*)(deg + N_);  // N+1
  int* cursor = rowptr + (N_ + 1); // N
  int* perm = cursor + N_;         // E

  constexpr int T = 16;
  const int mv_grid = N_ / T;       // 3125
  const int e_grid = (E_ + 255) / 256;

  // x = emb(x_in)
  gemv_k<0, true, T><<<mv_grid, 128, 0, stream>>>(x_in, emb_w, emb_b, x);

  // CSR by dst (topology fixed for whole launch)
  hipMemsetAsync(cursor, 0, N_ * sizeof(int), stream);
  hist_k<<<e_grid, 256, 0, stream>>>(dst, cursor);
  scan_k<<<1, 1024, 0, stream>>>(cursor, rowptr, cursor);
  permute_k<<<e_grid, 256, 0, stream>>>(dst, cursor, perm);

  for (int b = 0; b < B_; ++b) {
    const float* W1 = er_w1 + (size_t)b * H_ * 2 * H_;
    const float* b1 = er_b1 + (size_t)b * H_;
    const float* w2 = er_w2 + (size_t)b * H_;
    const float* b2 = er_b2 + b;
    const float* Wl = lap_w + (size_t)b * H_ * H_;
    const float* Wd = diss_w + (size_t)b * H_ * H_;
    const float* bd = diss_b + (size_t)b * H_;
    const float* Wm1 = mlp_w1 + (size_t)b * H_ * H_;
    const float* bm1 = mlp_b1 + (size_t)b * H_;
    const float* Wm2 = mlp_w2 + (size_t)b * H_ * H_;
    const float* bm2 = mlp_b2 + (size_t)b * H_;

    // P1 = x@W1a^T + b1 (bias folded), P2 = x@W1b^T
    gemv2_k<0, 0, true, false, T, 2 * H_><<<mv_grid, 128, 0, stream>>>(
        x, W1, b1, W1 + H_, nullptr, A, Bb);
    hipMemsetAsync(deg, 0, N_ * sizeof(float), stream);
    edge_r_k<<<E_ / 8, 256, 0, stream>>>(A, Bb, src, dst, w2, b2, r, deg);

    for (int it = 0; it < ITERS_; ++it) {
      // f = x@Wl^T ; diss = relu(x@Wd^T + bd)
      gemv2_k<0, 1, false, true, T, H_><<<mv_grid, 128, 0, stream>>>(
          x, Wl, nullptr, Wd, bd, A, Bb);
      if (it == 0)
        agg_update_k<true><<<N_ / 4, 256, 0, stream>>>(x, v, A, Bb, deg, r,
                                                       src, rowptr, perm);
      else
        agg_update_k<false><<<N_ / 4, 256, 0, stream>>>(x, v, A, Bb, deg, r,
                                                        src, rowptr, perm);
    }
    // x = tanh(x@Wm1^T + bm1) @ Wm2^T + bm2
    gemv_k<2, true, T><<<mv_grid, 128, 0, stream>>>(x, Wm1, bm1, A);
    gemv_k<0, true, T><<<mv_grid, 128, 0, stream>>>(A, Wm2, bm2, x);
  }
  readout_k<T><<<mv_grid, 64, 0, stream>>>(x, ro_w, ro_b, out);
}

// Round 3
// 2037.333 us; speedup vs baseline: 1.8296x; 1.1153x over previous
//
#include <hip/hip_runtime.h>
#include <hip/hip_bf16.h>
#include <math.h>

constexpr int N_ = 50000;
constexpr int E_ = 400000;
constexpr int H_ = 128;
constexpr int OUT_ = 64;
constexpr int B_ = 3;
constexpr int ITERS_ = 2;
constexpr float EPS_ = 0.01f;

typedef __hip_bfloat16 bf16;

__device__ inline float b2f(unsigned short u) {
  union { unsigned int i; float f; } c;
  c.i = ((unsigned int)u) << 16;
  return c.f;
}

template <typename T>
__device__ inline void stor(T* p, float v) { *p = v; }
template <>
__device__ inline void stor<bf16>(bf16* p, float v) { *p = __float2bfloat16(v); }

// ---------------------------------------------------------------------------
// Single GEMV (fp32 out): Y[r, j] = act(X[r,:] . W[j,:] + b[j]); W [128,128].
// ---------------------------------------------------------------------------
template <int ACT, bool HASB, int T>
__global__ __launch_bounds__(128) void gemv_k(
    const float* __restrict__ X, const float* __restrict__ W,
    const float* __restrict__ bias, float* __restrict__ Y) {
  const int tid = threadIdx.x;
  const size_t r0 = (size_t)blockIdx.x * T;
  float acc[T];
#pragma unroll
  for (int t = 0; t < T; ++t) acc[t] = 0.f;
  const float4* W4 = (const float4*)(W + (size_t)tid * H_);
#pragma unroll 4
  for (int k4 = 0; k4 < H_ / 4; ++k4) {
    float4 w = W4[k4];
#pragma unroll
    for (int t = 0; t < T; ++t) {
      const float4 xv = *(const float4*)(X + (r0 + t) * H_ + k4 * 4);
      acc[t] = fmaf(w.x, xv.x, acc[t]);
      acc[t] = fmaf(w.y, xv.y, acc[t]);
      acc[t] = fmaf(w.z, xv.z, acc[t]);
      acc[t] = fmaf(w.w, xv.w, acc[t]);
    }
  }
  const float b = HASB ? bias[tid] : 0.f;
#pragma unroll
  for (int t = 0; t < T; ++t) {
    float y = acc[t] + b;
    if (ACT == 1) y = fmaxf(y, 0.f);
    if (ACT == 2) y = tanhf(y);
    Y[(r0 + t) * H_ + tid] = y;
  }
}

// ---------------------------------------------------------------------------
// Dual GEMV sharing input rows; templated output dtypes (fp32 or bf16).
// ---------------------------------------------------------------------------
template <int ACT0, int ACT1, bool HB0, bool HB1, int T, int WS, typename O0,
          typename O1>
__global__ __launch_bounds__(128) void gemv2_k(
    const float* __restrict__ X, const float* __restrict__ W0,
    const float* __restrict__ b0p, const float* __restrict__ W1,
    const float* __restrict__ b1p, O0* __restrict__ Y0, O1* __restrict__ Y1) {
  const int tid = threadIdx.x;
  const size_t r0 = (size_t)blockIdx.x * T;
  float acc0[T], acc1[T];
#pragma unroll
  for (int t = 0; t < T; ++t) { acc0[t] = 0.f; acc1[t] = 0.f; }
  const float4* W04 = (const float4*)(W0 + (size_t)tid * WS);
  const float4* W14 = (const float4*)(W1 + (size_t)tid * WS);
#pragma unroll 4
  for (int k4 = 0; k4 < H_ / 4; ++k4) {
    float4 w0 = W04[k4];
    float4 w1 = W14[k4];
#pragma unroll
    for (int t = 0; t < T; ++t) {
      const float4 xv = *(const float4*)(X + (r0 + t) * H_ + k4 * 4);
      acc0[t] = fmaf(w0.x, xv.x, acc0[t]);
      acc0[t] = fmaf(w0.y, xv.y, acc0[t]);
      acc0[t] = fmaf(w0.z, xv.z, acc0[t]);
      acc0[t] = fmaf(w0.w, xv.w, acc0[t]);
      acc1[t] = fmaf(w1.x, xv.x, acc1[t]);
      acc1[t] = fmaf(w1.y, xv.y, acc1[t]);
      acc1[t] = fmaf(w1.z, xv.z, acc1[t]);
      acc1[t] = fmaf(w1.w, xv.w, acc1[t]);
    }
  }
  const float b0 = HB0 ? b0p[tid] : 0.f;
  const float b1 = HB1 ? b1p[tid] : 0.f;
#pragma unroll
  for (int t = 0; t < T; ++t) {
    float y0 = acc0[t] + b0;
    float y1 = acc1[t] + b1;
    if (ACT0 == 1) y0 = fmaxf(y0, 0.f);
    if (ACT0 == 2) y0 = tanhf(y0);
    if (ACT1 == 1) y1 = fmaxf(y1, 0.f);
    if (ACT1 == 2) y1 = tanhf(y1);
    stor(Y0 + (r0 + t) * H_ + tid, y0);
    stor(Y1 + (r0 + t) * H_ + tid, y1);
  }
}

// ---------------------------------------------------------------------------
// Readout
// ---------------------------------------------------------------------------
template <int T>
__global__ __launch_bounds__(64) void readout_k(
    const float* __restrict__ X, const float* __restrict__ W,
    const float* __restrict__ bias, float* __restrict__ out) {
  const int tid = threadIdx.x;
  const size_t r0 = (size_t)blockIdx.x * T;
  float acc[T];
#pragma unroll
  for (int t = 0; t < T; ++t) acc[t] = 0.f;
  const float4* W4 = (const float4*)(W + (size_t)tid * H_);
#pragma unroll 4
  for (int k4 = 0; k4 < H_ / 4; ++k4) {
    float4 w = W4[k4];
#pragma unroll
    for (int t = 0; t < T; ++t) {
      const float4 xv = *(const float4*)(X + (r0 + t) * H_ + k4 * 4);
      acc[t] = fmaf(w.x, xv.x, acc[t]);
      acc[t] = fmaf(w.y, xv.y, acc[t]);
      acc[t] = fmaf(w.z, xv.z, acc[t]);
      acc[t] = fmaf(w.w, xv.w, acc[t]);
    }
  }
  const float b = bias[tid];
#pragma unroll
  for (int t = 0; t < T; ++t) out[(r0 + t) * OUT_ + tid] = acc[t] + b;
}

// ---------------------------------------------------------------------------
// Edge resistance from bf16 P tables: r = |w2 . relu(P1[src]+P2[dst]) + b2|
// 32 lanes per edge (4 ch each, 8B/lane); deg[src] += r.
// ---------------------------------------------------------------------------
__global__ __launch_bounds__(256) void edge_r_k(
    const unsigned short* __restrict__ P1, const unsigned short* __restrict__ P2,
    const int* __restrict__ src, const int* __restrict__ dst,
    const float* __restrict__ w2, const float* __restrict__ b2,
    float* __restrict__ r_out, float* __restrict__ deg) {
  const int tid = threadIdx.x;
  const int lane = tid & 63;
  const int half = lane >> 5;
  const int l = lane & 31;
  const int wid = tid >> 6;
  const size_t e = (size_t)blockIdx.x * 8 + wid * 2 + half;
  const float4 wv = *(const float4*)(w2 + l * 4);
  const int s = src[e];
  const int d = dst[e];
  const ushort4 a4 = *(const ushort4*)(P1 + (size_t)s * H_ + l * 4);
  const ushort4 c4 = *(const ushort4*)(P2 + (size_t)d * H_ + l * 4);
  float sum = fmaxf(b2f(a4.x) + b2f(c4.x), 0.f) * wv.x;
  sum = fmaf(fmaxf(b2f(a4.y) + b2f(c4.y), 0.f), wv.y, sum);
  sum = fmaf(fmaxf(b2f(a4.z) + b2f(c4.z), 0.f), wv.z, sum);
  sum = fmaf(fmaxf(b2f(a4.w) + b2f(c4.w), 0.f), wv.w, sum);
#pragma unroll
  for (int off = 16; off > 0; off >>= 1) sum += __shfl_xor(sum, off);
  if (l == 0) {
    const float rv = fabsf(sum + b2[0]);
    r_out[e] = rv;
    atomicAdd(&deg[s], rv);
  }
}

// ---------------------------------------------------------------------------
// CSR build (by dst): hist -> 3-kernel parallel scan -> permute.
// ---------------------------------------------------------------------------
constexpr int NSC = (N_ + 1023) / 1024;  // 49

__global__ void hist_k(const int* __restrict__ dst, int* __restrict__ cnt) {
  const int e = blockIdx.x * 256 + threadIdx.x;
  if (e < E_) atomicAdd(&cnt[dst[e]], 1);
}

__global__ __launch_bounds__(1024) void partial_k(const int* __restrict__ cnt,
                                                  int* __restrict__ psum) {
  __shared__ int sm[1024];
  const int tid = threadIdx.x;
  const int i = blockIdx.x * 1024 + tid;
  sm[tid] = (i < N_) ? cnt[i] : 0;
  __syncthreads();
  for (int off = 512; off > 0; off >>= 1) {
    if (tid < off) sm[tid] += sm[tid + off];
    __syncthreads();
  }
  if (tid == 0) psum[blockIdx.x] = sm[0];
}

__global__ __launch_bounds__(64) void scanp_k(int* __restrict__ psum) {
  const int tid = threadIdx.x;
  int v = (tid < NSC) ? psum[tid] : 0;
  const int orig = v;
#pragma unroll
  for (int off = 1; off < 64; off <<= 1) {
    const int u = __shfl_up(v, off);
    if (tid >= off) v += u;
  }
  if (tid < NSC) psum[tid] = v - orig;  // exclusive
}

__global__ __launch_bounds__(1024) void rowptr_k(const int* __restrict__ cnt,
                                                 const int* __restrict__ psum,
                                                 int* __restrict__ rowptr,
                                                 int* __restrict__ cursor) {
  __shared__ int sm[1024];
  const int tid = threadIdx.x;
  const int i = blockIdx.x * 1024 + tid;
  const int orig = (i < N_) ? cnt[i] : 0;
  sm[tid] = orig;
  __syncthreads();
  for (int off = 1; off < 1024; off <<= 1) {
    const int mine = sm[tid];
    const int u = (tid >= off) ? sm[tid - off] : 0;
    __syncthreads();
    sm[tid] = mine + u;
    __syncthreads();
  }
  const int excl = sm[tid] - orig + psum[blockIdx.x];
  if (i < N_) {
    rowptr[i] = excl;
    cursor[i] = excl;
  }
  if (i == 0) rowptr[N_] = E_;
}

__global__ void permute_k(const int* __restrict__ dst, int* __restrict__ cursor,
                          int* __restrict__ perm) {
  const int e = blockIdx.x * 256 + threadIdx.x;
  if (e < E_) {
    const int p = atomicAdd(&cursor[dst[e]], 1);
    perm[p] = e;
  }
}

// ---------------------------------------------------------------------------
// Fused aggregate + update. One wave per node; f is bf16 (4B/lane gathers).
//   agg = sum_{e: dst[e]=n} r[e]*f[src[e]]; conv = deg*f[n] - agg
//   v -= EPS*(conv + diss*v); x += EPS*v    (FIRST: v starts at 0)
// ---------------------------------------------------------------------------
template <bool FIRST>
__global__ __launch_bounds__(256) void agg_update_k(
    float* __restrict__ x, float* __restrict__ v,
    const unsigned int* __restrict__ f, const float* __restrict__ diss,
    const float* __restrict__ deg, const float* __restrict__ r,
    const int* __restrict__ src, const int* __restrict__ rowptr,
    const int* __restrict__ perm) {
  const int wid = threadIdx.x >> 6;
  const int lane = threadIdx.x & 63;
  const int n = blockIdx.x * 4 + wid;
  const int beg = rowptr[n];
  const int end = rowptr[n + 1];
  float ax = 0.f, ay = 0.f;
  for (int i = beg; i < end; ++i) {
    const int e = perm[i];
    const float rv = r[e];
    const int s = src[e];
    const unsigned int fv = f[(size_t)s * 64 + lane];
    ax = fmaf(rv, b2f((unsigned short)(fv & 0xffffu)), ax);
    ay = fmaf(rv, b2f((unsigned short)(fv >> 16)), ay);
  }
  const size_t idx = (size_t)n * 64 + lane;
  const unsigned int fnv = f[idx];
  const float dg = deg[n];
  const float cx = dg * b2f((unsigned short)(fnv & 0xffffu)) - ax;
  const float cy = dg * b2f((unsigned short)(fnv >> 16)) - ay;
  const float2 ds = ((const float2*)diss)[idx];
  float2 vv;
  if (FIRST) {
    vv.x = -EPS_ * cx;
    vv.y = -EPS_ * cy;
  } else {
    vv = ((const float2*)v)[idx];
    vv.x = vv.x - EPS_ * (cx + ds.x * vv.x);
    vv.y = vv.y - EPS_ * (cy + ds.y * vv.y);
  }
  ((float2*)v)[idx] = vv;
  float2 xv = ((const float2*)x)[idx];
  xv.x += EPS_ * vv.x;
  xv.y += EPS_ * vv.y;
  ((float2*)x)[idx] = xv;
}

extern "C" void kernel_launch(void* const* d_in, const int* in_sizes, int n_in,
                              void* d_out, int out_size, void* d_ws,
                              size_t ws_size, hipStream_t stream) {
  const float* x_in = (const float*)d_in[0];
  const int* ei = (const int*)d_in[1];
  const int* src = ei;
  const int* dst = ei + E_;
  const float* emb_w = (const float*)d_in[2];
  const float* emb_b = (const float*)d_in[3];
  const float* lap_w = (const float*)d_in[4];
  const float* er_w1 = (const float*)d_in[5];
  const float* er_b1 = (const float*)d_in[6];
  const float* er_w2 = (const float*)d_in[7];
  const float* er_b2 = (const float*)d_in[8];
  const float* diss_w = (const float*)d_in[9];
  const float* diss_b = (const float*)d_in[10];
  const float* mlp_w1 = (const float*)d_in[11];
  const float* mlp_b1 = (const float*)d_in[12];
  const float* mlp_w2 = (const float*)d_in[13];
  const float* mlp_b2 = (const float*)d_in[14];
  const float* ro_w = (const float*)d_in[15];
  const float* ro_b = (const float*)d_in[16];
  float* out = (float*)d_out;

  // workspace layout
  const size_t NF = (size_t)N_ * H_;
  float* ws = (float*)d_ws;
  float* x = ws;             // N*128 f32
  float* v = x + NF;         // N*128 f32
  float* A = v + NF;         // N*128 f32 (P1 bf16 / f bf16 / mlp tmp f32)
  float* Bb = A + NF;        // N*128 f32 (P2 bf16 / diss f32)
  float* r = Bb + NF;        // E
  float* deg = r + E_;       // N
  int* rowptr = (int*)(deg + N_);   // N+1
  int* cursor = rowptr + (N_ + 1);  // N
  int* perm = cursor + N_;          // E
  int* psum = perm + E_;            // NSC

  constexpr int T = 16;
  const int mv_grid = N_ / T;  // 3125
  const int e_grid = (E_ + 255) / 256;

  // x = emb(x_in)
  gemv_k<0, true, T><<<mv_grid, 128, 0, stream>>>(x_in, emb_w, emb_b, x);

  // CSR by dst (topology fixed for whole launch)
  hipMemsetAsync(cursor, 0, N_ * sizeof(int), stream);
  hist_k<<<e_grid, 256, 0, stream>>>(dst, cursor);
  partial_k<<<NSC, 1024, 0, stream>>>(cursor, psum);
  scanp_k<<<1, 64, 0, stream>>>(psum);
  rowptr_k<<<NSC, 1024, 0, stream>>>(cursor, psum, rowptr, cursor);
  permute_k<<<e_grid, 256, 0, stream>>>(dst, cursor, perm);

  for (int b = 0; b < B_; ++b) {
    const float* W1 = er_w1 + (size_t)b * H_ * 2 * H_;
    const float* b1 = er_b1 + (size_t)b * H_;
    const float* w2 = er_w2 + (size_t)b * H_;
    const float* b2 = er_b2 + b;
    const float* Wl = lap_w + (size_t)b * H_ * H_;
    const float* Wd = diss_w + (size_t)b * H_ * H_;
    const float* bd = diss_b + (size_t)b * H_;
    const float* Wm1 = mlp_w1 + (size_t)b * H_ * H_;
    const float* bm1 = mlp_b1 + (size_t)b * H_;
    const float* Wm2 = mlp_w2 + (size_t)b * H_ * H_;
    const float* bm2 = mlp_b2 + (size_t)b * H_;

    // P1 = x@W1a^T + b1 (bf16), P2 = x@W1b^T (bf16)
    gemv2_k<0, 0, true, false, T, 2 * H_, bf16, bf16>
        <<<mv_grid, 128, 0, stream>>>(x, W1, b1, W1 + H_, nullptr, (bf16*)A,
                                      (bf16*)Bb);
    hipMemsetAsync(deg, 0, N_ * sizeof(float), stream);
    edge_r_k<<<E_ / 8, 256, 0, stream>>>((const unsigned short*)A,
                                         (const unsigned short*)Bb, src, dst,
                                         w2, b2, r, deg);

    for (int it = 0; it < ITERS_; ++it) {
      // f = x@Wl^T (bf16) ; diss = relu(x@Wd^T + bd) (f32)
      gemv2_k<0, 1, false, true, T, H_, bf16, float>
          <<<mv_grid, 128, 0, stream>>>(x, Wl, nullptr, Wd, bd, (bf16*)A, Bb);
      if (it == 0)
        agg_update_k<true><<<N_ / 4, 256, 0, stream>>>(
            x, v, (const unsigned int*)A, Bb, deg, r, src, rowptr, perm);
      else
        agg_update_k<false><<<N_ / 4, 256, 0, stream>>>(
            x, v, (const unsigned int*)A, Bb, deg, r, src, rowptr, perm);
    }
    // x = tanh(x@Wm1^T + bm1) @ Wm2^T + bm2
    gemv_k<2, true, T><<<mv_grid, 128, 0, stream>>>(x, Wm1, bm1, A);
    gemv_k<0, true, T><<<mv_grid, 128, 0, stream>>>(A, Wm2, bm2, x);
  }
  readout_k<T><<<mv_grid, 64, 0, stream>>>(x, ro_w, ro_b, out);
}

// Round 4
// 1209.140 us; speedup vs baseline: 3.0828x; 1.6849x over previous
//
#include <hip/hip_runtime.h>
#include <math.h>

constexpr int N_ = 50000;
constexpr int E_ = 400000;
constexpr int H_ = 128;
constexpr int OUT_ = 64;
constexpr int B_ = 3;
constexpr int ITERS_ = 2;
constexpr float EPS_ = 0.01f;

typedef unsigned short u16;
typedef short v8s __attribute__((ext_vector_type(8)));
typedef float v4f __attribute__((ext_vector_type(4)));

__device__ inline float b2f(u16 u) {
  union { unsigned int i; float f; } c;
  c.i = ((unsigned int)u) << 16;
  return c.f;
}
__device__ inline u16 f2b(float f) {
  union { float f; unsigned int u; } c;
  c.f = f;
  unsigned int r = c.u + 0x7fffu + ((c.u >> 16) & 1u);  // RNE
  return (u16)(r >> 16);
}

// ---------------------------------------------------------------------------
// MFMA GEMM: Y[r, n] = act(Xb[r,:128] . Wb[n,:128] + bias[n])
// Xb bf16 [N][128]; Wb bf16 [16*NCT][128] row-major. Block = 4 waves x 16 rows.
// Wave computes 16 rows x 16*NCT cols via mfma_f32_16x16x32_bf16.
// A frag: lane l holds A[l&15][(l>>4)*8+j]; B frag: B[(l>>4)*8+j][l&15];
// D: row=(l>>4)*4+i, col=l&15  (verified layouts, cdna4 guide §3).
// ACT0 applies to cols<128, ACT1 to cols>=128 (0 none,1 relu,2 tanh).
// MODE 0: bf16 Y0 (cols<128), bf16 Y1 (cols>=128), strides 128.
// MODE 1: fp32 Y0 + bf16 Y1 mirrors (full width, NCT<=8).
// MODE 2: fp32 Y0, row stride 64 (readout).
// ---------------------------------------------------------------------------
template <int NCT, int ACT0, int ACT1, int MODE>
__global__ __launch_bounds__(256) void mm_k(
    const u16* __restrict__ Xb, const u16* __restrict__ Wb,
    const float* __restrict__ bias, void* __restrict__ Y0,
    void* __restrict__ Y1) {
  const int lane = threadIdx.x & 63;
  const int wv = threadIdx.x >> 6;
  const int rowbase = blockIdx.x * 64 + wv * 16;
  int arow = rowbase + (lane & 15);
  if (arow >= N_) arow = N_ - 1;
  const int kc = (lane >> 4) * 8;

  v8s a[4];
#pragma unroll
  for (int ks = 0; ks < 4; ++ks)
    a[ks] = *(const v8s*)(Xb + (size_t)arow * H_ + ks * 32 + kc);

  v4f acc[NCT];
#pragma unroll
  for (int ct = 0; ct < NCT; ++ct) acc[ct] = (v4f)0.f;

  const int bn = lane & 15;
#pragma unroll
  for (int ct = 0; ct < NCT; ++ct) {
    const u16* wp = Wb + (size_t)(ct * 16 + bn) * H_ + kc;
#pragma unroll
    for (int ks = 0; ks < 4; ++ks) {
      v8s b = *(const v8s*)(wp + ks * 32);
      acc[ct] = __builtin_amdgcn_mfma_f32_16x16x32_bf16(a[ks], b, acc[ct], 0, 0, 0);
    }
  }

  const int rbase = rowbase + (lane >> 4) * 4;
  const int ncol = lane & 15;
#pragma unroll
  for (int ct = 0; ct < NCT; ++ct) {
    const int n = ct * 16 + ncol;
    const float bv = bias[n];
#pragma unroll
    for (int i = 0; i < 4; ++i) {
      const int r = rbase + i;
      if (r >= N_) continue;
      float y = acc[ct][i] + bv;
      if (n < H_) {
        if (ACT0 == 1) y = fmaxf(y, 0.f);
        if (ACT0 == 2) y = tanhf(y);
      } else {
        if (ACT1 == 1) y = fmaxf(y, 0.f);
        if (ACT1 == 2) y = tanhf(y);
      }
      if (MODE == 0) {
        if (n < H_)
          ((u16*)Y0)[(size_t)r * H_ + n] = f2b(y);
        else
          ((u16*)Y1)[(size_t)r * H_ + n - H_] = f2b(y);
      } else if (MODE == 1) {
        ((float*)Y0)[(size_t)r * H_ + n] = y;
        ((u16*)Y1)[(size_t)r * H_ + n] = f2b(y);
      } else {
        ((float*)Y0)[(size_t)r * OUT_ + n] = y;
      }
    }
  }
}

// ---------------------------------------------------------------------------
// Weight pack: all fp32 weights -> one bf16 arena (layout documented below).
// ---------------------------------------------------------------------------
constexpr int WB_EMB = 0;                 // 128x128
constexpr int WB_RO = 16384;              // 64x128
constexpr int WB_BLK = 24576;             // per block: 98304
// per block: Wp 256x128 (er_w1 split), Wfd 256x128 (lap;diss), Wm1, Wm2
constexpr int WB_TOTAL = 24576 + 3 * 98304;  // 319488

__global__ void convall_k(const float* __restrict__ emb_w,
                          const float* __restrict__ ro_w,
                          const float* __restrict__ er_w1,
                          const float* __restrict__ lap_w,
                          const float* __restrict__ diss_w,
                          const float* __restrict__ mlp_w1,
                          const float* __restrict__ mlp_w2,
                          u16* __restrict__ wb) {
  const int idx = blockIdx.x * 256 + threadIdx.x;
  if (idx >= WB_TOTAL) return;
  const float* src;
  size_t soff;
  if (idx < 16384) {
    src = emb_w; soff = idx;
  } else if (idx < 24576) {
    src = ro_w; soff = idx - 16384;
  } else {
    int t = idx - 24576;
    const int b = t / 98304;
    t -= b * 98304;
    if (t < 32768) {  // Wp: rows<128 -> er_w1 cols 0-127; rows>=128 -> cols 128-255
      const int r = t >> 7, c = t & 127;
      src = er_w1 + (size_t)b * 32768;
      soff = (r < 128) ? ((size_t)r * 256 + c) : ((size_t)(r - 128) * 256 + 128 + c);
    } else if (t < 65536) {  // Wfd: rows<128 lap, rows>=128 diss
      const int u = t - 32768;
      if (u < 16384) { src = lap_w + (size_t)b * 16384; soff = u; }
      else { src = diss_w + (size_t)b * 16384; soff = u - 16384; }
    } else if (t < 81920) {
      src = mlp_w1 + (size_t)b * 16384; soff = t - 65536;
    } else {
      src = mlp_w2 + (size_t)b * 16384; soff = t - 81920;
    }
  }
  wb[idx] = f2b(src[soff]);
}

// bias packs: bp[b] = [er_b1[b]; 0], bfd[b] = [0; diss_b[b]]
__global__ void biasp_k(const float* __restrict__ er_b1,
                        const float* __restrict__ diss_b,
                        float* __restrict__ bp, float* __restrict__ bfd) {
  const int b = blockIdx.x, t = threadIdx.x;
  bp[b * 256 + t] = (t < 128) ? er_b1[b * 128 + t] : 0.f;
  bfd[b * 256 + t] = (t < 128) ? 0.f : diss_b[b * 128 + (t - 128)];
}

// x_in fp32 -> bf16
__global__ void convx_k(const float* __restrict__ src, u16* __restrict__ dst) {
  const size_t i = ((size_t)blockIdx.x * 256 + threadIdx.x) * 4;
  const float4 v = *(const float4*)(src + i);
  ushort4 o;
  o.x = f2b(v.x); o.y = f2b(v.y); o.z = f2b(v.z); o.w = f2b(v.w);
  *(ushort4*)(dst + i) = o;
}

// ---------------------------------------------------------------------------
// Edge resistance from bf16 P tables: r = |w2 . relu(P1[src]+P2[dst]) + b2|
// 32 lanes per edge (4 ch each); deg[src] += r.
// ---------------------------------------------------------------------------
__global__ __launch_bounds__(256) void edge_r_k(
    const u16* __restrict__ P1, const u16* __restrict__ P2,
    const int* __restrict__ src, const int* __restrict__ dst,
    const float* __restrict__ w2, const float* __restrict__ b2,
    float* __restrict__ r_out, float* __restrict__ deg) {
  const int tid = threadIdx.x;
  const int lane = tid & 63;
  const int half = lane >> 5;
  const int l = lane & 31;
  const int wid = tid >> 6;
  const size_t e = (size_t)blockIdx.x * 8 + wid * 2 + half;
  const float4 wv = *(const float4*)(w2 + l * 4);
  const int s = src[e];
  const int d = dst[e];
  const ushort4 a4 = *(const ushort4*)(P1 + (size_t)s * H_ + l * 4);
  const ushort4 c4 = *(const ushort4*)(P2 + (size_t)d * H_ + l * 4);
  float sum = fmaxf(b2f(a4.x) + b2f(c4.x), 0.f) * wv.x;
  sum = fmaf(fmaxf(b2f(a4.y) + b2f(c4.y), 0.f), wv.y, sum);
  sum = fmaf(fmaxf(b2f(a4.z) + b2f(c4.z), 0.f), wv.z, sum);
  sum = fmaf(fmaxf(b2f(a4.w) + b2f(c4.w), 0.f), wv.w, sum);
#pragma unroll
  for (int off = 16; off > 0; off >>= 1) sum += __shfl_xor(sum, off);
  if (l == 0) {
    const float rv = fabsf(sum + b2[0]);
    r_out[e] = rv;
    atomicAdd(&deg[s], rv);
  }
}

// ---------------------------------------------------------------------------
// CSR build (by dst): hist -> parallel scan -> permute.
// ---------------------------------------------------------------------------
constexpr int NSC = (N_ + 1023) / 1024;  // 49

__global__ void hist_k(const int* __restrict__ dst, int* __restrict__ cnt) {
  const int e = blockIdx.x * 256 + threadIdx.x;
  if (e < E_) atomicAdd(&cnt[dst[e]], 1);
}

__global__ __launch_bounds__(1024) void partial_k(const int* __restrict__ cnt,
                                                  int* __restrict__ psum) {
  __shared__ int sm[1024];
  const int tid = threadIdx.x;
  const int i = blockIdx.x * 1024 + tid;
  sm[tid] = (i < N_) ? cnt[i] : 0;
  __syncthreads();
  for (int off = 512; off > 0; off >>= 1) {
    if (tid < off) sm[tid] += sm[tid + off];
    __syncthreads();
  }
  if (tid == 0) psum[blockIdx.x] = sm[0];
}

__global__ __launch_bounds__(64) void scanp_k(int* __restrict__ psum) {
  const int tid = threadIdx.x;
  int v = (tid < NSC) ? psum[tid] : 0;
  const int orig = v;
#pragma unroll
  for (int off = 1; off < 64; off <<= 1) {
    const int u = __shfl_up(v, off);
    if (tid >= off) v += u;
  }
  if (tid < NSC) psum[tid] = v - orig;  // exclusive
}

__global__ __launch_bounds__(1024) void rowptr_k(const int* __restrict__ cnt,
                                                 const int* __restrict__ psum,
                                                 int* __restrict__ rowptr,
                                                 int* __restrict__ cursor) {
  __shared__ int sm[1024];
  const int tid = threadIdx.x;
  const int i = blockIdx.x * 1024 + tid;
  const int orig = (i < N_) ? cnt[i] : 0;
  sm[tid] = orig;
  __syncthreads();
  for (int off = 1; off < 1024; off <<= 1) {
    const int mine = sm[tid];
    const int u = (tid >= off) ? sm[tid - off] : 0;
    __syncthreads();
    sm[tid] = mine + u;
    __syncthreads();
  }
  const int excl = sm[tid] - orig + psum[blockIdx.x];
  if (i < N_) {
    rowptr[i] = excl;
    cursor[i] = excl;
  }
  if (i == 0) rowptr[N_] = E_;
}

__global__ void permute_k(const int* __restrict__ dst, int* __restrict__ cursor,
                          int* __restrict__ perm) {
  const int e = blockIdx.x * 256 + threadIdx.x;
  if (e < E_) {
    const int p = atomicAdd(&cursor[dst[e]], 1);
    perm[p] = e;
  }
}

// ---------------------------------------------------------------------------
// Fused aggregate + update. One wave per node; f & diss bf16; x,v fp32.
// Writes x, v, and xb (bf16 mirror of x).
// ---------------------------------------------------------------------------
template <bool FIRST>
__global__ __launch_bounds__(256) void agg_update_k(
    float* __restrict__ x, float* __restrict__ v,
    const unsigned int* __restrict__ f, const unsigned int* __restrict__ diss,
    const float* __restrict__ deg, const float* __restrict__ r,
    const int* __restrict__ src, const int* __restrict__ rowptr,
    const int* __restrict__ perm, unsigned int* __restrict__ xb) {
  const int wid = threadIdx.x >> 6;
  const int lane = threadIdx.x & 63;
  const int n = blockIdx.x * 4 + wid;
  const int beg = rowptr[n];
  const int end = rowptr[n + 1];
  float ax = 0.f, ay = 0.f;
  for (int i = beg; i < end; ++i) {
    const int e = perm[i];
    const float rv = r[e];
    const int s = src[e];
    const unsigned int fv = f[(size_t)s * 64 + lane];
    ax = fmaf(rv, b2f((u16)(fv & 0xffffu)), ax);
    ay = fmaf(rv, b2f((u16)(fv >> 16)), ay);
  }
  const size_t idx = (size_t)n * 64 + lane;
  const unsigned int fnv = f[idx];
  const float dg = deg[n];
  const float cx = dg * b2f((u16)(fnv & 0xffffu)) - ax;
  const float cy = dg * b2f((u16)(fnv >> 16)) - ay;
  const unsigned int dv = diss[idx];
  float2 vv;
  if (FIRST) {
    vv.x = -EPS_ * cx;
    vv.y = -EPS_ * cy;
  } else {
    vv = ((const float2*)v)[idx];
    vv.x = vv.x - EPS_ * (cx + b2f((u16)(dv & 0xffffu)) * vv.x);
    vv.y = vv.y - EPS_ * (cy + b2f((u16)(dv >> 16)) * vv.y);
  }
  ((float2*)v)[idx] = vv;
  float2 xv = ((const float2*)x)[idx];
  xv.x += EPS_ * vv.x;
  xv.y += EPS_ * vv.y;
  ((float2*)x)[idx] = xv;
  xb[idx] = (unsigned int)f2b(xv.x) | ((unsigned int)f2b(xv.y) << 16);
}

extern "C" void kernel_launch(void* const* d_in, const int* in_sizes, int n_in,
                              void* d_out, int out_size, void* d_ws,
                              size_t ws_size, hipStream_t stream) {
  const float* x_in = (const float*)d_in[0];
  const int* ei = (const int*)d_in[1];
  const int* src = ei;
  const int* dst = ei + E_;
  const float* emb_w = (const float*)d_in[2];
  const float* emb_b = (const float*)d_in[3];
  const float* lap_w = (const float*)d_in[4];
  const float* er_w1 = (const float*)d_in[5];
  const float* er_b1 = (const float*)d_in[6];
  const float* er_w2 = (const float*)d_in[7];
  const float* er_b2 = (const float*)d_in[8];
  const float* diss_w = (const float*)d_in[9];
  const float* diss_b = (const float*)d_in[10];
  const float* mlp_w1 = (const float*)d_in[11];
  const float* mlp_b1 = (const float*)d_in[12];
  const float* mlp_w2 = (const float*)d_in[13];
  const float* mlp_b2 = (const float*)d_in[14];
  const float* ro_w = (const float*)d_in[15];
  const float* ro_b = (const float*)d_in[16];
  float* out = (float*)d_out;

  // workspace layout (float units)
  const size_t NF = (size_t)N_ * H_;
  float* ws = (float*)d_ws;
  float* x = ws;                    // NF fp32
  float* v = x + NF;                // NF fp32
  u16* A = (u16*)(v + NF);          // NF bf16 (xin_b / P1 / f / mlp tmp)
  u16* Bb = A + NF;                 // NF bf16 (P2 / diss)
  u16* xb = Bb + NF;                // NF bf16 (x mirror)
  float* r = (float*)(xb + NF);     // E
  float* deg = r + E_;              // N
  int* rowptr = (int*)(deg + N_);   // N+1
  int* cursor = rowptr + (N_ + 1);  // N
  int* perm = cursor + N_;          // E
  int* psum = perm + E_;            // NSC
  u16* wb = (u16*)(psum + NSC);     // WB_TOTAL bf16
  float* bp = (float*)(wb + WB_TOTAL + (WB_TOTAL & 1));  // 3*256
  float* bfd = bp + 3 * 256;        // 3*256

  const int mm_grid = (N_ + 63) / 64;  // 782
  const int e_grid = (E_ + 255) / 256;

  // pack weights/biases, convert x_in
  convall_k<<<(WB_TOTAL + 255) / 256, 256, 0, stream>>>(
      emb_w, ro_w, er_w1, lap_w, diss_w, mlp_w1, mlp_w2, wb);
  biasp_k<<<3, 256, 0, stream>>>(er_b1, diss_b, bp, bfd);
  convx_k<<<(int)(NF / 1024), 256, 0, stream>>>(x_in, A);

  // CSR by dst (topology fixed for whole launch)
  hipMemsetAsync(cursor, 0, N_ * sizeof(int), stream);
  hist_k<<<e_grid, 256, 0, stream>>>(dst, cursor);
  partial_k<<<NSC, 1024, 0, stream>>>(cursor, psum);
  scanp_k<<<1, 64, 0, stream>>>(psum);
  rowptr_k<<<NSC, 1024, 0, stream>>>(cursor, psum, rowptr, cursor);
  permute_k<<<e_grid, 256, 0, stream>>>(dst, cursor, perm);

  // x = emb(x_in): fp32 x + bf16 xb
  mm_k<8, 0, 0, 1><<<mm_grid, 256, 0, stream>>>(A, wb + WB_EMB, emb_b, x, xb);

  for (int b = 0; b < B_; ++b) {
    const u16* Wp = wb + WB_BLK + (size_t)b * 98304;
    const u16* Wfd = Wp + 32768;
    const u16* Wm1 = Wfd + 32768;
    const u16* Wm2 = Wm1 + 16384;
    const float* b2 = er_b2 + b;
    const float* w2 = er_w2 + (size_t)b * H_;

    // P1 = xb@W1a^T + b1, P2 = xb@W1b^T  (both bf16)
    mm_k<16, 0, 0, 0><<<mm_grid, 256, 0, stream>>>(xb, Wp, bp + b * 256, A, Bb);
    hipMemsetAsync(deg, 0, N_ * sizeof(float), stream);
    edge_r_k<<<E_ / 8, 256, 0, stream>>>(A, Bb, src, dst, w2, b2, r, deg);

    for (int it = 0; it < ITERS_; ++it) {
      // f = xb@Wl^T (bf16); diss = relu(xb@Wd^T + bd) (bf16)
      mm_k<16, 0, 1, 0><<<mm_grid, 256, 0, stream>>>(xb, Wfd, bfd + b * 256, A,
                                                     Bb);
      if (it == 0)
        agg_update_k<true><<<N_ / 4, 256, 0, stream>>>(
            x, v, (const unsigned int*)A, (const unsigned int*)Bb, deg, r, src,
            rowptr, perm, (unsigned int*)xb);
      else
        agg_update_k<false><<<N_ / 4, 256, 0, stream>>>(
            x, v, (const unsigned int*)A, (const unsigned int*)Bb, deg, r, src,
            rowptr, perm, (unsigned int*)xb);
    }
    // tmp = tanh(xb@Wm1^T + bm1) (bf16);  x = tmp@Wm2^T + bm2 (fp32 + bf16)
    mm_k<8, 2, 0, 0><<<mm_grid, 256, 0, stream>>>(xb, Wm1, mlp_b1 + b * H_, A,
                                                  nullptr);
    mm_k<8, 0, 0, 1><<<mm_grid, 256, 0, stream>>>(A, Wm2, mlp_b2 + b * H_, x,
                                                  xb);
  }
  mm_k<4, 0, 0, 2><<<mm_grid, 256, 0, stream>>>(xb, wb + WB_RO, ro_b, out,
                                                nullptr);
}

// Round 5
// 1082.120 us; speedup vs baseline: 3.4446x; 1.1174x over previous
//
#include <hip/hip_runtime.h>
#include <math.h>

constexpr int N_ = 50000;
constexpr int E_ = 400000;
constexpr int H_ = 128;
constexpr int OUT_ = 64;
constexpr int B_ = 3;
constexpr int ITERS_ = 2;
constexpr float EPS_ = 0.01f;

typedef unsigned short u16;
typedef short v8s __attribute__((ext_vector_type(8)));
typedef float v4f __attribute__((ext_vector_type(4)));

__device__ inline float b2f(u16 u) {
  union { unsigned int i; float f; } c;
  c.i = ((unsigned int)u) << 16;
  return c.f;
}
__device__ inline u16 f2b(float f) {
  union { float f; unsigned int u; } c;
  c.f = f;
  unsigned int r = c.u + 0x7fffu + ((c.u >> 16) & 1u);  // RNE
  return (u16)(r >> 16);
}

// ---------------------------------------------------------------------------
// MFMA GEMM: Y[r, n] = act(Xb[r,:128] . Wb[n,:128] + bias[n])
// Xb bf16 [N][128]; Wb bf16 [16*NCT][128] row-major. Block = 4 waves x 16 rows.
// A frag: lane l holds A[l&15][(l>>4)*8+j]; B frag: B[(l>>4)*8+j][l&15];
// D: row=(l>>4)*4+i, col=l&15  (verified layouts, cdna4 guide §3).
// ACT0 applies to cols<128, ACT1 to cols>=128 (0 none,1 relu,2 tanh).
// MODE 0: bf16 Y0 (cols<128), bf16 Y1 (cols>=128), strides 128.
// MODE 1: fp32 Y0 + bf16 Y1 mirrors (full width, NCT<=8).
// MODE 2: fp32 Y0, row stride 64 (readout).
// ---------------------------------------------------------------------------
template <int NCT, int ACT0, int ACT1, int MODE>
__global__ __launch_bounds__(256) void mm_k(
    const u16* __restrict__ Xb, const u16* __restrict__ Wb,
    const float* __restrict__ bias, void* __restrict__ Y0,
    void* __restrict__ Y1) {
  const int lane = threadIdx.x & 63;
  const int wv = threadIdx.x >> 6;
  const int rowbase = blockIdx.x * 64 + wv * 16;
  int arow = rowbase + (lane & 15);
  if (arow >= N_) arow = N_ - 1;
  const int kc = (lane >> 4) * 8;

  v8s a[4];
#pragma unroll
  for (int ks = 0; ks < 4; ++ks)
    a[ks] = *(const v8s*)(Xb + (size_t)arow * H_ + ks * 32 + kc);

  v4f acc[NCT];
#pragma unroll
  for (int ct = 0; ct < NCT; ++ct) acc[ct] = (v4f)0.f;

  const int bn = lane & 15;
#pragma unroll
  for (int ct = 0; ct < NCT; ++ct) {
    const u16* wp = Wb + (size_t)(ct * 16 + bn) * H_ + kc;
#pragma unroll
    for (int ks = 0; ks < 4; ++ks) {
      v8s b = *(const v8s*)(wp + ks * 32);
      acc[ct] = __builtin_amdgcn_mfma_f32_16x16x32_bf16(a[ks], b, acc[ct], 0, 0, 0);
    }
  }

  const int rbase = rowbase + (lane >> 4) * 4;
  const int ncol = lane & 15;
#pragma unroll
  for (int ct = 0; ct < NCT; ++ct) {
    const int n = ct * 16 + ncol;
    const float bv = bias[n];
#pragma unroll
    for (int i = 0; i < 4; ++i) {
      const int r = rbase + i;
      if (r >= N_) continue;
      float y = acc[ct][i] + bv;
      if (n < H_) {
        if (ACT0 == 1) y = fmaxf(y, 0.f);
        if (ACT0 == 2) y = tanhf(y);
      } else {
        if (ACT1 == 1) y = fmaxf(y, 0.f);
        if (ACT1 == 2) y = tanhf(y);
      }
      if (MODE == 0) {
        if (n < H_)
          ((u16*)Y0)[(size_t)r * H_ + n] = f2b(y);
        else
          ((u16*)Y1)[(size_t)r * H_ + n - H_] = f2b(y);
      } else if (MODE == 1) {
        ((float*)Y0)[(size_t)r * H_ + n] = y;
        ((u16*)Y1)[(size_t)r * H_ + n] = f2b(y);
      } else {
        ((float*)Y0)[(size_t)r * OUT_ + n] = y;
      }
    }
  }
}

// ---------------------------------------------------------------------------
// Weight pack: all fp32 weights -> one bf16 arena.
// ---------------------------------------------------------------------------
constexpr int WB_EMB = 0;                 // 128x128
constexpr int WB_RO = 16384;              // 64x128
constexpr int WB_BLK = 24576;             // per block: 98304
constexpr int WB_TOTAL = 24576 + 3 * 98304;  // 319488

__global__ void convall_k(const float* __restrict__ emb_w,
                          const float* __restrict__ ro_w,
                          const float* __restrict__ er_w1,
                          const float* __restrict__ lap_w,
                          const float* __restrict__ diss_w,
                          const float* __restrict__ mlp_w1,
                          const float* __restrict__ mlp_w2,
                          u16* __restrict__ wb) {
  const int idx = blockIdx.x * 256 + threadIdx.x;
  if (idx >= WB_TOTAL) return;
  const float* src;
  size_t soff;
  if (idx < 16384) {
    src = emb_w; soff = idx;
  } else if (idx < 24576) {
    src = ro_w; soff = idx - 16384;
  } else {
    int t = idx - 24576;
    const int b = t / 98304;
    t -= b * 98304;
    if (t < 32768) {  // Wp: rows<128 -> er_w1 cols 0-127; rows>=128 -> cols 128-255
      const int r = t >> 7, c = t & 127;
      src = er_w1 + (size_t)b * 32768;
      soff = (r < 128) ? ((size_t)r * 256 + c) : ((size_t)(r - 128) * 256 + 128 + c);
    } else if (t < 65536) {  // Wfd: rows<128 lap, rows>=128 diss
      const int u = t - 32768;
      if (u < 16384) { src = lap_w + (size_t)b * 16384; soff = u; }
      else { src = diss_w + (size_t)b * 16384; soff = u - 16384; }
    } else if (t < 81920) {
      src = mlp_w1 + (size_t)b * 16384; soff = t - 65536;
    } else {
      src = mlp_w2 + (size_t)b * 16384; soff = t - 81920;
    }
  }
  wb[idx] = f2b(src[soff]);
}

// bias packs: bp[b] = [er_b1[b]; 0], bfd[b] = [0; diss_b[b]]
__global__ void biasp_k(const float* __restrict__ er_b1,
                        const float* __restrict__ diss_b,
                        float* __restrict__ bp, float* __restrict__ bfd) {
  const int b = blockIdx.x, t = threadIdx.x;
  bp[b * 256 + t] = (t < 128) ? er_b1[b * 128 + t] : 0.f;
  bfd[b * 256 + t] = (t < 128) ? 0.f : diss_b[b * 128 + (t - 128)];
}

// x_in fp32 -> bf16
__global__ void convx_k(const float* __restrict__ src, u16* __restrict__ dst) {
  const size_t i = ((size_t)blockIdx.x * 256 + threadIdx.x) * 4;
  const float4 v = *(const float4*)(src + i);
  ushort4 o;
  o.x = f2b(v.x); o.y = f2b(v.y); o.z = f2b(v.z); o.w = f2b(v.w);
  *(ushort4*)(dst + i) = o;
}

// ---------------------------------------------------------------------------
// Edge resistance, dst-sorted order: r_s[i] = |w2 . relu(P1[ss[i]]+P2[ds[i]]) + b2|
// Consecutive i share the same dst row -> P2 gathers hit L1/L2.
// 32 lanes per edge (4 ch each); deg[src] += r.
// ---------------------------------------------------------------------------
__global__ __launch_bounds__(256) void edge_r_k(
    const u16* __restrict__ P1, const u16* __restrict__ P2,
    const int* __restrict__ ss, const int* __restrict__ ds,
    const float* __restrict__ w2, const float* __restrict__ b2,
    float* __restrict__ r_out, float* __restrict__ deg) {
  const int tid = threadIdx.x;
  const int lane = tid & 63;
  const int half = lane >> 5;
  const int l = lane & 31;
  const int wid = tid >> 6;
  const size_t e = (size_t)blockIdx.x * 8 + wid * 2 + half;
  const float4 wv = *(const float4*)(w2 + l * 4);
  const int s = ss[e];
  const int d = ds[e];
  const ushort4 a4 = *(const ushort4*)(P1 + (size_t)s * H_ + l * 4);
  const ushort4 c4 = *(const ushort4*)(P2 + (size_t)d * H_ + l * 4);
  float sum = fmaxf(b2f(a4.x) + b2f(c4.x), 0.f) * wv.x;
  sum = fmaf(fmaxf(b2f(a4.y) + b2f(c4.y), 0.f), wv.y, sum);
  sum = fmaf(fmaxf(b2f(a4.z) + b2f(c4.z), 0.f), wv.z, sum);
  sum = fmaf(fmaxf(b2f(a4.w) + b2f(c4.w), 0.f), wv.w, sum);
#pragma unroll
  for (int off = 16; off > 0; off >>= 1) sum += __shfl_xor(sum, off);
  if (l == 0) {
    const float rv = fabsf(sum + b2[0]);
    r_out[e] = rv;
    atomicAdd(&deg[s], rv);
  }
}

// ---------------------------------------------------------------------------
// CSR build (by dst): hist -> parallel scan -> sorted src/dst arrays.
// ---------------------------------------------------------------------------
constexpr int NSC = (N_ + 1023) / 1024;  // 49

__global__ void hist_k(const int* __restrict__ dst, int* __restrict__ cnt) {
  const int e = blockIdx.x * 256 + threadIdx.x;
  if (e < E_) atomicAdd(&cnt[dst[e]], 1);
}

__global__ __launch_bounds__(1024) void partial_k(const int* __restrict__ cnt,
                                                  int* __restrict__ psum) {
  __shared__ int sm[1024];
  const int tid = threadIdx.x;
  const int i = blockIdx.x * 1024 + tid;
  sm[tid] = (i < N_) ? cnt[i] : 0;
  __syncthreads();
  for (int off = 512; off > 0; off >>= 1) {
    if (tid < off) sm[tid] += sm[tid + off];
    __syncthreads();
  }
  if (tid == 0) psum[blockIdx.x] = sm[0];
}

__global__ __launch_bounds__(64) void scanp_k(int* __restrict__ psum) {
  const int tid = threadIdx.x;
  int v = (tid < NSC) ? psum[tid] : 0;
  const int orig = v;
#pragma unroll
  for (int off = 1; off < 64; off <<= 1) {
    const int u = __shfl_up(v, off);
    if (tid >= off) v += u;
  }
  if (tid < NSC) psum[tid] = v - orig;  // exclusive
}

__global__ __launch_bounds__(1024) void rowptr_k(const int* __restrict__ cnt,
                                                 const int* __restrict__ psum,
                                                 int* __restrict__ rowptr,
                                                 int* __restrict__ cursor) {
  __shared__ int sm[1024];
  const int tid = threadIdx.x;
  const int i = blockIdx.x * 1024 + tid;
  const int orig = (i < N_) ? cnt[i] : 0;
  sm[tid] = orig;
  __syncthreads();
  for (int off = 1; off < 1024; off <<= 1) {
    const int mine = sm[tid];
    const int u = (tid >= off) ? sm[tid - off] : 0;
    __syncthreads();
    sm[tid] = mine + u;
    __syncthreads();
  }
  const int excl = sm[tid] - orig + psum[blockIdx.x];
  if (i < N_) {
    rowptr[i] = excl;
    cursor[i] = excl;
  }
  if (i == 0) rowptr[N_] = E_;
}

__global__ void permute_k(const int* __restrict__ src,
                          const int* __restrict__ dst, int* __restrict__ cursor,
                          int* __restrict__ ss, int* __restrict__ ds) {
  const int e = blockIdx.x * 256 + threadIdx.x;
  if (e < E_) {
    const int d = dst[e];
    const int p = atomicAdd(&cursor[d], 1);
    ss[p] = src[e];
    ds[p] = d;
  }
}

// ---------------------------------------------------------------------------
// Fused aggregate + update. One wave per node; f, diss, v all bf16; x fp32.
// r/ss reads are sequential (CSR order). Writes x, vb, xb.
// ---------------------------------------------------------------------------
template <bool FIRST>
__global__ __launch_bounds__(256) void agg_update_k(
    float* __restrict__ x, unsigned int* __restrict__ vb,
    const unsigned int* __restrict__ f, const unsigned int* __restrict__ diss,
    const float* __restrict__ deg, const float* __restrict__ r,
    const int* __restrict__ ss, const int* __restrict__ rowptr,
    unsigned int* __restrict__ xb) {
  const int wid = threadIdx.x >> 6;
  const int lane = threadIdx.x & 63;
  const int n = blockIdx.x * 4 + wid;
  const int beg = rowptr[n];
  const int end = rowptr[n + 1];
  float ax = 0.f, ay = 0.f;
  for (int i = beg; i < end; ++i) {
    const float rv = r[i];
    const int s = ss[i];
    const unsigned int fv = f[(size_t)s * 64 + lane];
    ax = fmaf(rv, b2f((u16)(fv & 0xffffu)), ax);
    ay = fmaf(rv, b2f((u16)(fv >> 16)), ay);
  }
  const size_t idx = (size_t)n * 64 + lane;
  const unsigned int fnv = f[idx];
  const float dg = deg[n];
  const float cx = dg * b2f((u16)(fnv & 0xffffu)) - ax;
  const float cy = dg * b2f((u16)(fnv >> 16)) - ay;
  float vx, vy;
  if (FIRST) {
    vx = -EPS_ * cx;
    vy = -EPS_ * cy;
  } else {
    const unsigned int dv = diss[idx];
    const unsigned int vv = vb[idx];
    vx = b2f((u16)(vv & 0xffffu));
    vy = b2f((u16)(vv >> 16));
    vx = vx - EPS_ * (cx + b2f((u16)(dv & 0xffffu)) * vx);
    vy = vy - EPS_ * (cy + b2f((u16)(dv >> 16)) * vy);
  }
  vb[idx] = (unsigned int)f2b(vx) | ((unsigned int)f2b(vy) << 16);
  float2 xv = ((const float2*)x)[idx];
  xv.x += EPS_ * vx;
  xv.y += EPS_ * vy;
  ((float2*)x)[idx] = xv;
  xb[idx] = (unsigned int)f2b(xv.x) | ((unsigned int)f2b(xv.y) << 16);
}

extern "C" void kernel_launch(void* const* d_in, const int* in_sizes, int n_in,
                              void* d_out, int out_size, void* d_ws,
                              size_t ws_size, hipStream_t stream) {
  const float* x_in = (const float*)d_in[0];
  const int* ei = (const int*)d_in[1];
  const int* src = ei;
  const int* dst = ei + E_;
  const float* emb_w = (const float*)d_in[2];
  const float* emb_b = (const float*)d_in[3];
  const float* lap_w = (const float*)d_in[4];
  const float* er_w1 = (const float*)d_in[5];
  const float* er_b1 = (const float*)d_in[6];
  const float* er_w2 = (const float*)d_in[7];
  const float* er_b2 = (const float*)d_in[8];
  const float* diss_w = (const float*)d_in[9];
  const float* diss_b = (const float*)d_in[10];
  const float* mlp_w1 = (const float*)d_in[11];
  const float* mlp_b1 = (const float*)d_in[12];
  const float* mlp_w2 = (const float*)d_in[13];
  const float* mlp_b2 = (const float*)d_in[14];
  const float* ro_w = (const float*)d_in[15];
  const float* ro_b = (const float*)d_in[16];
  float* out = (float*)d_out;

  // workspace layout (float units)
  const size_t NF = (size_t)N_ * H_;
  float* ws = (float*)d_ws;
  float* x = ws;                    // NF fp32
  u16* A = (u16*)(x + NF);          // NF bf16 (xin_b / P1 / f / mlp tmp)
  u16* Bb = A + NF;                 // NF bf16 (P2 / diss)
  u16* xb = Bb + NF;                // NF bf16 (x mirror)
  u16* vb = xb + NF;                // NF bf16 (v)
  float* r = (float*)(vb + NF);     // E (dst-sorted)
  float* deg = r + E_;              // N
  int* rowptr = (int*)(deg + N_);   // N+1
  int* cursor = rowptr + (N_ + 1);  // N
  int* ss = cursor + N_;            // E (src, dst-sorted)
  int* ds = ss + E_;                // E (dst, dst-sorted)
  int* psum = ds + E_;              // NSC
  u16* wb = (u16*)(psum + NSC);     // WB_TOTAL bf16
  float* bp = (float*)(wb + WB_TOTAL + (WB_TOTAL & 1));  // 3*256
  float* bfd = bp + 3 * 256;        // 3*256

  const int mm_grid = (N_ + 63) / 64;  // 782
  const int e_grid = (E_ + 255) / 256;

  // pack weights/biases, convert x_in
  convall_k<<<(WB_TOTAL + 255) / 256, 256, 0, stream>>>(
      emb_w, ro_w, er_w1, lap_w, diss_w, mlp_w1, mlp_w2, wb);
  biasp_k<<<3, 256, 0, stream>>>(er_b1, diss_b, bp, bfd);
  convx_k<<<(int)(NF / 1024), 256, 0, stream>>>(x_in, A);

  // CSR by dst (topology fixed for whole launch)
  hipMemsetAsync(cursor, 0, N_ * sizeof(int), stream);
  hist_k<<<e_grid, 256, 0, stream>>>(dst, cursor);
  partial_k<<<NSC, 1024, 0, stream>>>(cursor, psum);
  scanp_k<<<1, 64, 0, stream>>>(psum);
  rowptr_k<<<NSC, 1024, 0, stream>>>(cursor, psum, rowptr, cursor);
  permute_k<<<e_grid, 256, 0, stream>>>(src, dst, cursor, ss, ds);

  // x = emb(x_in): fp32 x + bf16 xb
  mm_k<8, 0, 0, 1><<<mm_grid, 256, 0, stream>>>(A, wb + WB_EMB, emb_b, x, xb);

  for (int b = 0; b < B_; ++b) {
    const u16* Wp = wb + WB_BLK + (size_t)b * 98304;
    const u16* Wfd = Wp + 32768;
    const u16* Wm1 = Wfd + 32768;
    const u16* Wm2 = Wm1 + 16384;
    const float* b2 = er_b2 + b;
    const float* w2 = er_w2 + (size_t)b * H_;

    // P1 = xb@W1a^T + b1, P2 = xb@W1b^T  (both bf16)
    mm_k<16, 0, 0, 0><<<mm_grid, 256, 0, stream>>>(xb, Wp, bp + b * 256, A, Bb);
    hipMemsetAsync(deg, 0, N_ * sizeof(float), stream);
    edge_r_k<<<E_ / 8, 256, 0, stream>>>(A, Bb, ss, ds, w2, b2, r, deg);

    for (int it = 0; it < ITERS_; ++it) {
      // f = xb@Wl^T (bf16); diss = relu(xb@Wd^T + bd) (bf16)
      mm_k<16, 0, 1, 0><<<mm_grid, 256, 0, stream>>>(xb, Wfd, bfd + b * 256, A,
                                                     Bb);
      if (it == 0)
        agg_update_k<true><<<N_ / 4, 256, 0, stream>>>(
            x, (unsigned int*)vb, (const unsigned int*)A,
            (const unsigned int*)Bb, deg, r, ss, rowptr, (unsigned int*)xb);
      else
        agg_update_k<false><<<N_ / 4, 256, 0, stream>>>(
            x, (unsigned int*)vb, (const unsigned int*)A,
            (const unsigned int*)Bb, deg, r, ss, rowptr, (unsigned int*)xb);
    }
    // tmp = tanh(xb@Wm1^T + bm1) (bf16);  x = tmp@Wm2^T + bm2 (fp32 + bf16)
    mm_k<8, 2, 0, 0><<<mm_grid, 256, 0, stream>>>(xb, Wm1, mlp_b1 + b * H_, A,
                                                  nullptr);
    mm_k<8, 0, 0, 1><<<mm_grid, 256, 0, stream>>>(A, Wm2, mlp_b2 + b * H_, x,
                                                  xb);
  }
  mm_k<4, 0, 0, 2><<<mm_grid, 256, 0, stream>>>(xb, wb + WB_RO, ro_b, out,
                                                nullptr);
}

// Round 6
// 1028.021 us; speedup vs baseline: 3.6259x; 1.0526x over previous
//
#include <hip/hip_runtime.h>
#include <math.h>

constexpr int N_ = 50000;
constexpr int E_ = 400000;
constexpr int H_ = 128;
constexpr int OUT_ = 64;
constexpr int B_ = 3;
constexpr int ITERS_ = 2;
constexpr float EPS_ = 0.01f;

typedef unsigned short u16;
typedef short v8s __attribute__((ext_vector_type(8)));
typedef float v4f __attribute__((ext_vector_type(4)));

__device__ inline float b2f(u16 u) {
  union { unsigned int i; float f; } c;
  c.i = ((unsigned int)u) << 16;
  return c.f;
}
__device__ inline u16 f2b(float f) {
  union { float f; unsigned int u; } c;
  c.f = f;
  unsigned int r = c.u + 0x7fffu + ((c.u >> 16) & 1u);  // RNE
  return (u16)(r >> 16);
}
__device__ inline unsigned int pk(float a, float b) {
  return (unsigned int)f2b(a) | ((unsigned int)f2b(b) << 16);
}

// ---------------------------------------------------------------------------
// MFMA GEMM: Y[r, n] = act(Xb[r,:128] . Wb[n,:128] + bias[n])
// Block = 4 waves x 16 rows. A frag: lane l holds A[l&15][(l>>4)*8+j];
// B frag: B[(l>>4)*8+j][l&15]; D: row=(l>>4)*4+i, col=l&15.
// MODE 0: bf16 Y0 (cols<128) / bf16 Y1 (cols>=128), strides 128.
// MODE 2: fp32 Y0, row stride 64 (readout).
// ---------------------------------------------------------------------------
template <int NCT, int ACT0, int ACT1, int MODE>
__global__ __launch_bounds__(256) void mm_k(
    const u16* __restrict__ Xb, const u16* __restrict__ Wb,
    const float* __restrict__ bias, void* __restrict__ Y0,
    void* __restrict__ Y1) {
  const int lane = threadIdx.x & 63;
  const int wv = threadIdx.x >> 6;
  const int rowbase = blockIdx.x * 64 + wv * 16;
  int arow = rowbase + (lane & 15);
  if (arow >= N_) arow = N_ - 1;
  const int kc = (lane >> 4) * 8;

  v8s a[4];
#pragma unroll
  for (int ks = 0; ks < 4; ++ks)
    a[ks] = *(const v8s*)(Xb + (size_t)arow * H_ + ks * 32 + kc);

  v4f acc[NCT];
#pragma unroll
  for (int ct = 0; ct < NCT; ++ct) acc[ct] = (v4f)0.f;

  const int bn = lane & 15;
#pragma unroll
  for (int ct = 0; ct < NCT; ++ct) {
    const u16* wp = Wb + (size_t)(ct * 16 + bn) * H_ + kc;
#pragma unroll
    for (int ks = 0; ks < 4; ++ks) {
      v8s b = *(const v8s*)(wp + ks * 32);
      acc[ct] = __builtin_amdgcn_mfma_f32_16x16x32_bf16(a[ks], b, acc[ct], 0, 0, 0);
    }
  }

  const int rbase = rowbase + (lane >> 4) * 4;
  const int ncol = lane & 15;
#pragma unroll
  for (int ct = 0; ct < NCT; ++ct) {
    const int n = ct * 16 + ncol;
    const float bv = bias[n];
#pragma unroll
    for (int i = 0; i < 4; ++i) {
      const int r = rbase + i;
      if (r >= N_) continue;
      float y = acc[ct][i] + bv;
      if (n < H_) {
        if (ACT0 == 1) y = fmaxf(y, 0.f);
        if (ACT0 == 2) y = tanhf(y);
      } else {
        if (ACT1 == 1) y = fmaxf(y, 0.f);
        if (ACT1 == 2) y = tanhf(y);
      }
      if (MODE == 0) {
        if (n < H_)
          ((u16*)Y0)[(size_t)r * H_ + n] = f2b(y);
        else
          ((u16*)Y1)[(size_t)r * H_ + n - H_] = f2b(y);
      } else {
        ((float*)Y0)[(size_t)r * OUT_ + n] = y;
      }
    }
  }
}

// ---------------------------------------------------------------------------
// Fused MLP: Yb = tanh(Xb@Wm1^T + bm1) @ Wm2^T + bm2, all bf16 I/O.
// Intermediate 64x128 tile staged in LDS (row-padded to 136 to spread banks).
// In-place safe: each wave reads/writes only its own 16 rows, reads complete
// before the barrier, stores happen after.
// ---------------------------------------------------------------------------
__global__ __launch_bounds__(256) void mlp_k(
    const u16* __restrict__ Xb, const u16* __restrict__ Wm1,
    const float* __restrict__ bm1, const u16* __restrict__ Wm2,
    const float* __restrict__ bm2, u16* __restrict__ Yb) {
  __shared__ u16 tmp[64][136];
  const int lane = threadIdx.x & 63;
  const int wv = threadIdx.x >> 6;
  const int rowbase = blockIdx.x * 64 + wv * 16;
  int arow = rowbase + (lane & 15);
  if (arow >= N_) arow = N_ - 1;
  const int kc = (lane >> 4) * 8;
  const int bn = lane & 15;
  const int ncol = lane & 15;
  const int rloc = wv * 16 + (lane >> 4) * 4;

  v8s a[4];
#pragma unroll
  for (int ks = 0; ks < 4; ++ks)
    a[ks] = *(const v8s*)(Xb + (size_t)arow * H_ + ks * 32 + kc);

  v4f acc[8];
#pragma unroll
  for (int ct = 0; ct < 8; ++ct) acc[ct] = (v4f)0.f;
#pragma unroll
  for (int ct = 0; ct < 8; ++ct) {
    const u16* wp = Wm1 + (size_t)(ct * 16 + bn) * H_ + kc;
#pragma unroll
    for (int ks = 0; ks < 4; ++ks) {
      v8s b = *(const v8s*)(wp + ks * 32);
      acc[ct] = __builtin_amdgcn_mfma_f32_16x16x32_bf16(a[ks], b, acc[ct], 0, 0, 0);
    }
  }
#pragma unroll
  for (int ct = 0; ct < 8; ++ct) {
    const float bv = bm1[ct * 16 + ncol];
#pragma unroll
    for (int i = 0; i < 4; ++i)
      tmp[rloc + i][ct * 16 + ncol] = f2b(tanhf(acc[ct][i] + bv));
  }
  __syncthreads();

  const int rl2 = wv * 16 + (lane & 15);
  v8s a2[4];
#pragma unroll
  for (int ks = 0; ks < 4; ++ks)
    a2[ks] = *(const v8s*)&tmp[rl2][ks * 32 + kc];

  v4f acc2[8];
#pragma unroll
  for (int ct = 0; ct < 8; ++ct) acc2[ct] = (v4f)0.f;
#pragma unroll
  for (int ct = 0; ct < 8; ++ct) {
    const u16* wp = Wm2 + (size_t)(ct * 16 + bn) * H_ + kc;
#pragma unroll
    for (int ks = 0; ks < 4; ++ks) {
      v8s b = *(const v8s*)(wp + ks * 32);
      acc2[ct] = __builtin_amdgcn_mfma_f32_16x16x32_bf16(a2[ks], b, acc2[ct], 0, 0, 0);
    }
  }
  const int rbase = rowbase + (lane >> 4) * 4;
#pragma unroll
  for (int ct = 0; ct < 8; ++ct) {
    const float bv = bm2[ct * 16 + ncol];
#pragma unroll
    for (int i = 0; i < 4; ++i) {
      const int r = rbase + i;
      if (r < N_) Yb[(size_t)r * H_ + ct * 16 + ncol] = f2b(acc2[ct][i] + bv);
    }
  }
}

// ---------------------------------------------------------------------------
// Weight pack: all fp32 weights -> one bf16 arena.
// ---------------------------------------------------------------------------
constexpr int WB_EMB = 0;                 // 128x128
constexpr int WB_RO = 16384;              // 64x128
constexpr int WB_BLK = 24576;             // per block: 98304
constexpr int WB_TOTAL = 24576 + 3 * 98304;  // 319488

__global__ void convall_k(const float* __restrict__ emb_w,
                          const float* __restrict__ ro_w,
                          const float* __restrict__ er_w1,
                          const float* __restrict__ lap_w,
                          const float* __restrict__ diss_w,
                          const float* __restrict__ mlp_w1,
                          const float* __restrict__ mlp_w2,
                          u16* __restrict__ wb) {
  const int idx = blockIdx.x * 256 + threadIdx.x;
  if (idx >= WB_TOTAL) return;
  const float* src;
  size_t soff;
  if (idx < 16384) {
    src = emb_w; soff = idx;
  } else if (idx < 24576) {
    src = ro_w; soff = idx - 16384;
  } else {
    int t = idx - 24576;
    const int b = t / 98304;
    t -= b * 98304;
    if (t < 32768) {  // Wp: rows<128 -> er_w1 cols 0-127; rows>=128 -> cols 128-255
      const int r = t >> 7, c = t & 127;
      src = er_w1 + (size_t)b * 32768;
      soff = (r < 128) ? ((size_t)r * 256 + c) : ((size_t)(r - 128) * 256 + 128 + c);
    } else if (t < 65536) {  // Wfd: rows<128 lap, rows>=128 diss
      const int u = t - 32768;
      if (u < 16384) { src = lap_w + (size_t)b * 16384; soff = u; }
      else { src = diss_w + (size_t)b * 16384; soff = u - 16384; }
    } else if (t < 81920) {
      src = mlp_w1 + (size_t)b * 16384; soff = t - 65536;
    } else {
      src = mlp_w2 + (size_t)b * 16384; soff = t - 81920;
    }
  }
  wb[idx] = f2b(src[soff]);
}

// bias packs: bp[b] = [er_b1[b]; 0], bfd[b] = [0; diss_b[b]]
__global__ void biasp_k(const float* __restrict__ er_b1,
                        const float* __restrict__ diss_b,
                        float* __restrict__ bp, float* __restrict__ bfd) {
  const int b = blockIdx.x, t = threadIdx.x;
  bp[b * 256 + t] = (t < 128) ? er_b1[b * 128 + t] : 0.f;
  bfd[b * 256 + t] = (t < 128) ? 0.f : diss_b[b * 128 + (t - 128)];
}

// x_in fp32 -> bf16
__global__ void convx_k(const float* __restrict__ src, u16* __restrict__ dst) {
  const size_t i = ((size_t)blockIdx.x * 256 + threadIdx.x) * 4;
  const float4 v = *(const float4*)(src + i);
  ushort4 o;
  o.x = f2b(v.x); o.y = f2b(v.y); o.z = f2b(v.z); o.w = f2b(v.w);
  *(ushort4*)(dst + i) = o;
}

// ---------------------------------------------------------------------------
// Edge resistance, dst-sorted order: r[i] = |w2 . relu(P1[ss[i]]+P2[ds[i]]) + b2|
// 32 lanes per edge (4 ch each); deg[src] += r.
// ---------------------------------------------------------------------------
__global__ __launch_bounds__(256) void edge_r_k(
    const u16* __restrict__ P1, const u16* __restrict__ P2,
    const int* __restrict__ ss, const int* __restrict__ ds,
    const float* __restrict__ w2, const float* __restrict__ b2,
    float* __restrict__ r_out, float* __restrict__ deg) {
  const int tid = threadIdx.x;
  const int lane = tid & 63;
  const int half = lane >> 5;
  const int l = lane & 31;
  const int wid = tid >> 6;
  const size_t e = (size_t)blockIdx.x * 8 + wid * 2 + half;
  const float4 wv = *(const float4*)(w2 + l * 4);
  const int s = ss[e];
  const int d = ds[e];
  const ushort4 a4 = *(const ushort4*)(P1 + (size_t)s * H_ + l * 4);
  const ushort4 c4 = *(const ushort4*)(P2 + (size_t)d * H_ + l * 4);
  float sum = fmaxf(b2f(a4.x) + b2f(c4.x), 0.f) * wv.x;
  sum = fmaf(fmaxf(b2f(a4.y) + b2f(c4.y), 0.f), wv.y, sum);
  sum = fmaf(fmaxf(b2f(a4.z) + b2f(c4.z), 0.f), wv.z, sum);
  sum = fmaf(fmaxf(b2f(a4.w) + b2f(c4.w), 0.f), wv.w, sum);
#pragma unroll
  for (int off = 16; off > 0; off >>= 1) sum += __shfl_xor(sum, off);
  if (l == 0) {
    const float rv = fabsf(sum + b2[0]);
    r_out[e] = rv;
    atomicAdd(&deg[s], rv);
  }
}

// ---------------------------------------------------------------------------
// CSR build (by dst): hist -> parallel scan -> sorted src/dst arrays.
// ---------------------------------------------------------------------------
constexpr int NSC = (N_ + 1023) / 1024;  // 49

__global__ void hist_k(const int* __restrict__ dst, int* __restrict__ cnt) {
  const int e = blockIdx.x * 256 + threadIdx.x;
  if (e < E_) atomicAdd(&cnt[dst[e]], 1);
}

__global__ __launch_bounds__(1024) void partial_k(const int* __restrict__ cnt,
                                                  int* __restrict__ psum) {
  __shared__ int sm[1024];
  const int tid = threadIdx.x;
  const int i = blockIdx.x * 1024 + tid;
  sm[tid] = (i < N_) ? cnt[i] : 0;
  __syncthreads();
  for (int off = 512; off > 0; off >>= 1) {
    if (tid < off) sm[tid] += sm[tid + off];
    __syncthreads();
  }
  if (tid == 0) psum[blockIdx.x] = sm[0];
}

__global__ __launch_bounds__(64) void scanp_k(int* __restrict__ psum) {
  const int tid = threadIdx.x;
  int v = (tid < NSC) ? psum[tid] : 0;
  const int orig = v;
#pragma unroll
  for (int off = 1; off < 64; off <<= 1) {
    const int u = __shfl_up(v, off);
    if (tid >= off) v += u;
  }
  if (tid < NSC) psum[tid] = v - orig;  // exclusive
}

__global__ __launch_bounds__(1024) void rowptr_k(const int* __restrict__ cnt,
                                                 const int* __restrict__ psum,
                                                 int* __restrict__ rowptr,
                                                 int* __restrict__ cursor) {
  __shared__ int sm[1024];
  const int tid = threadIdx.x;
  const int i = blockIdx.x * 1024 + tid;
  const int orig = (i < N_) ? cnt[i] : 0;
  sm[tid] = orig;
  __syncthreads();
  for (int off = 1; off < 1024; off <<= 1) {
    const int mine = sm[tid];
    const int u = (tid >= off) ? sm[tid - off] : 0;
    __syncthreads();
    sm[tid] = mine + u;
    __syncthreads();
  }
  const int excl = sm[tid] - orig + psum[blockIdx.x];
  if (i < N_) {
    rowptr[i] = excl;
    cursor[i] = excl;
  }
  if (i == 0) rowptr[N_] = E_;
}

__global__ void permute_k(const int* __restrict__ src,
                          const int* __restrict__ dst, int* __restrict__ cursor,
                          int* __restrict__ ss, int* __restrict__ ds) {
  const int e = blockIdx.x * 256 + threadIdx.x;
  if (e < E_) {
    const int d = dst[e];
    const int p = atomicAdd(&cursor[d], 1);
    ss[p] = src[e];
    ds[p] = d;
  }
}

// ---------------------------------------------------------------------------
// Fused aggregate + update, all-bf16 state. One wave per node (2 ch/lane).
//   agg = sum r[i]*f[ss[i]];  conv = deg*f[n] - agg
//   FIRST: v = -EPS*conv, store vb;  LAST: v = vb - EPS*(conv + diss*vb)
//   xb += EPS*v  (bf16 read-modify-write)
// ---------------------------------------------------------------------------
template <bool FIRST>
__global__ __launch_bounds__(256) void agg_update_k(
    unsigned int* __restrict__ xb, unsigned int* __restrict__ vb,
    const unsigned int* __restrict__ f, const unsigned int* __restrict__ diss,
    const float* __restrict__ deg, const float* __restrict__ r,
    const int* __restrict__ ss, const int* __restrict__ rowptr) {
  const int wid = threadIdx.x >> 6;
  const int lane = threadIdx.x & 63;
  const int n = blockIdx.x * 4 + wid;
  const int beg = rowptr[n];
  const int end = rowptr[n + 1];
  float ax = 0.f, ay = 0.f;
  for (int i = beg; i < end; ++i) {
    const float rv = r[i];
    const int s = ss[i];
    const unsigned int fv = f[(size_t)s * 64 + lane];
    ax = fmaf(rv, b2f((u16)(fv & 0xffffu)), ax);
    ay = fmaf(rv, b2f((u16)(fv >> 16)), ay);
  }
  const size_t idx = (size_t)n * 64 + lane;
  const unsigned int fnv = f[idx];
  const float dg = deg[n];
  const float cx = dg * b2f((u16)(fnv & 0xffffu)) - ax;
  const float cy = dg * b2f((u16)(fnv >> 16)) - ay;
  float vx, vy;
  if (FIRST) {
    vx = -EPS_ * cx;
    vy = -EPS_ * cy;
    vb[idx] = pk(vx, vy);
  } else {
    const unsigned int dv = diss[idx];
    const unsigned int vv = vb[idx];
    vx = b2f((u16)(vv & 0xffffu));
    vy = b2f((u16)(vv >> 16));
    vx = vx - EPS_ * (cx + b2f((u16)(dv & 0xffffu)) * vx);
    vy = vy - EPS_ * (cy + b2f((u16)(dv >> 16)) * vy);
  }
  const unsigned int xv = xb[idx];
  const float nx = b2f((u16)(xv & 0xffffu)) + EPS_ * vx;
  const float ny = b2f((u16)(xv >> 16)) + EPS_ * vy;
  xb[idx] = pk(nx, ny);
}

extern "C" void kernel_launch(void* const* d_in, const int* in_sizes, int n_in,
                              void* d_out, int out_size, void* d_ws,
                              size_t ws_size, hipStream_t stream) {
  const float* x_in = (const float*)d_in[0];
  const int* ei = (const int*)d_in[1];
  const int* src = ei;
  const int* dst = ei + E_;
  const float* emb_w = (const float*)d_in[2];
  const float* emb_b = (const float*)d_in[3];
  const float* lap_w = (const float*)d_in[4];
  const float* er_w1 = (const float*)d_in[5];
  const float* er_b1 = (const float*)d_in[6];
  const float* er_w2 = (const float*)d_in[7];
  const float* er_b2 = (const float*)d_in[8];
  const float* diss_w = (const float*)d_in[9];
  const float* diss_b = (const float*)d_in[10];
  const float* mlp_w1 = (const float*)d_in[11];
  const float* mlp_b1 = (const float*)d_in[12];
  const float* mlp_w2 = (const float*)d_in[13];
  const float* mlp_b2 = (const float*)d_in[14];
  const float* ro_w = (const float*)d_in[15];
  const float* ro_b = (const float*)d_in[16];
  float* out = (float*)d_out;

  // workspace layout (float units)
  const size_t NF = (size_t)N_ * H_;
  float* ws = (float*)d_ws;
  u16* xb = (u16*)ws;               // NF bf16 (x state)
  u16* vb = xb + NF;                // NF bf16 (v)
  u16* A = vb + NF;                 // NF bf16 (xin_b / P1 / f)
  u16* Bb = A + NF;                 // NF bf16 (P2 / diss)
  float* r = (float*)(Bb + NF);     // E (dst-sorted)
  float* deg = r + E_;              // N
  int* rowptr = (int*)(deg + N_);   // N+1
  int* cursor = rowptr + (N_ + 1);  // N
  int* ss = cursor + N_;            // E (src, dst-sorted)
  int* ds = ss + E_;                // E (dst, dst-sorted)
  int* psum = ds + E_;              // NSC
  u16* wb = (u16*)(psum + NSC);     // WB_TOTAL bf16
  float* bp = (float*)(wb + WB_TOTAL + (WB_TOTAL & 1));  // 3*256
  float* bfd = bp + 3 * 256;        // 3*256

  const int mm_grid = (N_ + 63) / 64;  // 782
  const int e_grid = (E_ + 255) / 256;

  // pack weights/biases, convert x_in
  convall_k<<<(WB_TOTAL + 255) / 256, 256, 0, stream>>>(
      emb_w, ro_w, er_w1, lap_w, diss_w, mlp_w1, mlp_w2, wb);
  biasp_k<<<3, 256, 0, stream>>>(er_b1, diss_b, bp, bfd);
  convx_k<<<(int)(NF / 1024), 256, 0, stream>>>(x_in, A);

  // CSR by dst (topology fixed for whole launch)
  hipMemsetAsync(cursor, 0, N_ * sizeof(int), stream);
  hist_k<<<e_grid, 256, 0, stream>>>(dst, cursor);
  partial_k<<<NSC, 1024, 0, stream>>>(cursor, psum);
  scanp_k<<<1, 64, 0, stream>>>(psum);
  rowptr_k<<<NSC, 1024, 0, stream>>>(cursor, psum, rowptr, cursor);
  permute_k<<<e_grid, 256, 0, stream>>>(src, dst, cursor, ss, ds);

  // xb = emb(x_in)
  mm_k<8, 0, 0, 0><<<mm_grid, 256, 0, stream>>>(A, wb + WB_EMB, emb_b, xb,
                                                nullptr);

  for (int b = 0; b < B_; ++b) {
    const u16* Wp = wb + WB_BLK + (size_t)b * 98304;
    const u16* Wfd = Wp + 32768;
    const u16* Wm1 = Wfd + 32768;
    const u16* Wm2 = Wm1 + 16384;
    const float* b2 = er_b2 + b;
    const float* w2 = er_w2 + (size_t)b * H_;

    // P1 = xb@W1a^T + b1, P2 = xb@W1b^T  (both bf16)
    mm_k<16, 0, 0, 0><<<mm_grid, 256, 0, stream>>>(xb, Wp, bp + b * 256, A, Bb);
    hipMemsetAsync(deg, 0, N_ * sizeof(float), stream);
    edge_r_k<<<E_ / 8, 256, 0, stream>>>(A, Bb, ss, ds, w2, b2, r, deg);

    for (int it = 0; it < ITERS_; ++it) {
      // f = xb@Wl^T (bf16); diss = relu(xb@Wd^T + bd) (bf16)
      mm_k<16, 0, 1, 0><<<mm_grid, 256, 0, stream>>>(xb, Wfd, bfd + b * 256, A,
                                                     Bb);
      if (it == 0)
        agg_update_k<true><<<N_ / 4, 256, 0, stream>>>(
            (unsigned int*)xb, (unsigned int*)vb, (const unsigned int*)A,
            (const unsigned int*)Bb, deg, r, ss, rowptr);
      else
        agg_update_k<false><<<N_ / 4, 256, 0, stream>>>(
            (unsigned int*)xb, (unsigned int*)vb, (const unsigned int*)A,
            (const unsigned int*)Bb, deg, r, ss, rowptr);
    }
    // xb = tanh(xb@Wm1^T + bm1) @ Wm2^T + bm2   (fused, LDS intermediate)
    mlp_k<<<mm_grid, 256, 0, stream>>>(xb, Wm1, mlp_b1 + b * H_, Wm2,
                                       mlp_b2 + b * H_, xb);
  }
  mm_k<4, 0, 0, 2><<<mm_grid, 256, 0, stream>>>(xb, wb + WB_RO, ro_b, out,
                                                nullptr);
}

// Round 7
// 1019.221 us; speedup vs baseline: 3.6572x; 1.0086x over previous
//
#include <hip/hip_runtime.h>
#include <math.h>

constexpr int N_ = 50000;
constexpr int E_ = 400000;
constexpr int H_ = 128;
constexpr int OUT_ = 64;
constexpr int B_ = 3;
constexpr int ITERS_ = 2;
constexpr float EPS_ = 0.01f;

typedef unsigned short u16;
typedef unsigned char u8;
typedef short v8s __attribute__((ext_vector_type(8)));
typedef float v4f __attribute__((ext_vector_type(4)));
typedef float v2f __attribute__((ext_vector_type(2)));

__device__ inline float b2f(u16 u) {
  union { unsigned int i; float f; } c;
  c.i = ((unsigned int)u) << 16;
  return c.f;
}
__device__ inline u16 f2b(float f) {
  union { float f; unsigned int u; } c;
  c.f = f;
  unsigned int r = c.u + 0x7fffu + ((c.u >> 16) & 1u);  // RNE
  return (u16)(r >> 16);
}
__device__ inline unsigned int pk(float a, float b) {
  return (unsigned int)f2b(a) | ((unsigned int)f2b(b) << 16);
}

// ---------------- fp8 e4m3 encode/decode (HW cvt if available) -------------
#if defined(__has_builtin)
#if __has_builtin(__builtin_amdgcn_cvt_pk_f32_fp8) && \
    __has_builtin(__builtin_amdgcn_cvt_pk_fp8_f32)
#define HW_FP8 1
#endif
#endif

#ifdef HW_FP8
__device__ inline v2f dec_lo(unsigned int v) {
  return __builtin_amdgcn_cvt_pk_f32_fp8(v, false);
}
__device__ inline v2f dec_hi(unsigned int v) {
  return __builtin_amdgcn_cvt_pk_f32_fp8(v, true);
}
__device__ inline u8 enc1(float x) {
  return (u8)(__builtin_amdgcn_cvt_pk_fp8_f32(x, x, 0, false) & 0xff);
}
#else
__device__ inline float fp8_dec1(u8 v) {
  const unsigned int s = v >> 7, e = (v >> 3) & 15, m = v & 7;
  float mag = e ? __uint_as_float(((e + 120u) << 23) | (m << 20))
                : (float)m * 0.001953125f;
  return s ? -mag : mag;
}
__device__ inline v2f dec_lo(unsigned int v) {
  v2f r;
  r.x = fp8_dec1((u8)(v & 0xff));
  r.y = fp8_dec1((u8)((v >> 8) & 0xff));
  return r;
}
__device__ inline v2f dec_hi(unsigned int v) {
  v2f r;
  r.x = fp8_dec1((u8)((v >> 16) & 0xff));
  r.y = fp8_dec1((u8)((v >> 24) & 0xff));
  return r;
}
__device__ inline u8 enc1(float x) {
  union { float f; unsigned int u; } c;
  c.f = x;
  const unsigned int sgn = (c.u >> 31) << 7;
  float af = fabsf(x);
  if (af >= 448.f) return (u8)(sgn | 0x7e);
  if (af < 0.015625f) {
    int m = (int)rintf(af * 512.f);
    if (m > 7) return (u8)(sgn | 0x08);
    return (u8)(sgn | m);
  }
  unsigned int u = c.u & 0x7fffffffu;
  u += 0x7ffffu + ((u >> 20) & 1u);
  unsigned int m3 = (u >> 20) & 7;
  int e8 = (int)(u >> 23) - 120;
  if (e8 >= 15 && m3 >= 7) return (u8)(sgn | 0x7e);
  if (e8 <= 0) {
    int m = (int)rintf(af * 512.f);
    if (m > 7) m = 7;
    return (u8)(sgn | m);
  }
  return (u8)(sgn | ((unsigned)e8 << 3) | m3);
}
#endif

// ---------------------------------------------------------------------------
// MFMA GEMM: Y[r, n] = act(Xb[r,:128] . Wb[n,:128] + bias[n])
// Block = 4 waves x 16 rows. A frag: lane l holds A[l&15][(l>>4)*8+j];
// B frag: B[(l>>4)*8+j][l&15]; D: row=(l>>4)*4+i, col=l&15.
// MODE 0: Y0 (cols<128) / Y1 (cols>=128); OT 0=bf16, 1=fp8.
// MODE 2: fp32 Y0, row stride 64 (readout).
// ---------------------------------------------------------------------------
template <int NCT, int ACT0, int ACT1, int MODE, int OT>
__global__ __launch_bounds__(256) void mm_k(
    const u16* __restrict__ Xb, const u16* __restrict__ Wb,
    const float* __restrict__ bias, void* __restrict__ Y0,
    void* __restrict__ Y1) {
  const int lane = threadIdx.x & 63;
  const int wv = threadIdx.x >> 6;
  const int rowbase = blockIdx.x * 64 + wv * 16;
  int arow = rowbase + (lane & 15);
  if (arow >= N_) arow = N_ - 1;
  const int kc = (lane >> 4) * 8;

  v8s a[4];
#pragma unroll
  for (int ks = 0; ks < 4; ++ks)
    a[ks] = *(const v8s*)(Xb + (size_t)arow * H_ + ks * 32 + kc);

  v4f acc[NCT];
#pragma unroll
  for (int ct = 0; ct < NCT; ++ct) acc[ct] = (v4f)0.f;

  const int bn = lane & 15;
#pragma unroll
  for (int ct = 0; ct < NCT; ++ct) {
    const u16* wp = Wb + (size_t)(ct * 16 + bn) * H_ + kc;
#pragma unroll
    for (int ks = 0; ks < 4; ++ks) {
      v8s b = *(const v8s*)(wp + ks * 32);
      acc[ct] = __builtin_amdgcn_mfma_f32_16x16x32_bf16(a[ks], b, acc[ct], 0, 0, 0);
    }
  }

  const int rbase = rowbase + (lane >> 4) * 4;
  const int ncol = lane & 15;
#pragma unroll
  for (int ct = 0; ct < NCT; ++ct) {
    const int n = ct * 16 + ncol;
    const float bv = bias[n];
#pragma unroll
    for (int i = 0; i < 4; ++i) {
      const int r = rbase + i;
      if (r >= N_) continue;
      float y = acc[ct][i] + bv;
      if (n < H_) {
        if (ACT0 == 1) y = fmaxf(y, 0.f);
        if (ACT0 == 2) y = tanhf(y);
      } else {
        if (ACT1 == 1) y = fmaxf(y, 0.f);
        if (ACT1 == 2) y = tanhf(y);
      }
      if (MODE == 0) {
        if (OT == 0) {
          if (n < H_)
            ((u16*)Y0)[(size_t)r * H_ + n] = f2b(y);
          else
            ((u16*)Y1)[(size_t)r * H_ + n - H_] = f2b(y);
        } else {
          const u8 q = enc1(y);
          if (n < H_)
            ((u8*)Y0)[(size_t)r * H_ + n] = q;
          else
            ((u8*)Y1)[(size_t)r * H_ + n - H_] = q;
        }
      } else {
        ((float*)Y0)[(size_t)r * OUT_ + n] = y;
      }
    }
  }
}

// ---------------------------------------------------------------------------
// Fused MLP: Yb = tanh(Xb@Wm1^T + bm1) @ Wm2^T + bm2, all bf16 I/O.
// Intermediate 64x128 tile staged in LDS.
// ---------------------------------------------------------------------------
__global__ __launch_bounds__(256) void mlp_k(
    const u16* __restrict__ Xb, const u16* __restrict__ Wm1,
    const float* __restrict__ bm1, const u16* __restrict__ Wm2,
    const float* __restrict__ bm2, u16* __restrict__ Yb) {
  __shared__ u16 tmp[64][136];
  const int lane = threadIdx.x & 63;
  const int wv = threadIdx.x >> 6;
  const int rowbase = blockIdx.x * 64 + wv * 16;
  int arow = rowbase + (lane & 15);
  if (arow >= N_) arow = N_ - 1;
  const int kc = (lane >> 4) * 8;
  const int bn = lane & 15;
  const int ncol = lane & 15;
  const int rloc = wv * 16 + (lane >> 4) * 4;

  v8s a[4];
#pragma unroll
  for (int ks = 0; ks < 4; ++ks)
    a[ks] = *(const v8s*)(Xb + (size_t)arow * H_ + ks * 32 + kc);

  v4f acc[8];
#pragma unroll
  for (int ct = 0; ct < 8; ++ct) acc[ct] = (v4f)0.f;
#pragma unroll
  for (int ct = 0; ct < 8; ++ct) {
    const u16* wp = Wm1 + (size_t)(ct * 16 + bn) * H_ + kc;
#pragma unroll
    for (int ks = 0; ks < 4; ++ks) {
      v8s b = *(const v8s*)(wp + ks * 32);
      acc[ct] = __builtin_amdgcn_mfma_f32_16x16x32_bf16(a[ks], b, acc[ct], 0, 0, 0);
    }
  }
#pragma unroll
  for (int ct = 0; ct < 8; ++ct) {
    const float bv = bm1[ct * 16 + ncol];
#pragma unroll
    for (int i = 0; i < 4; ++i)
      tmp[rloc + i][ct * 16 + ncol] = f2b(tanhf(acc[ct][i] + bv));
  }
  __syncthreads();

  const int rl2 = wv * 16 + (lane & 15);
  v8s a2[4];
#pragma unroll
  for (int ks = 0; ks < 4; ++ks)
    a2[ks] = *(const v8s*)&tmp[rl2][ks * 32 + kc];

  v4f acc2[8];
#pragma unroll
  for (int ct = 0; ct < 8; ++ct) acc2[ct] = (v4f)0.f;
#pragma unroll
  for (int ct = 0; ct < 8; ++ct) {
    const u16* wp = Wm2 + (size_t)(ct * 16 + bn) * H_ + kc;
#pragma unroll
    for (int ks = 0; ks < 4; ++ks) {
      v8s b = *(const v8s*)(wp + ks * 32);
      acc2[ct] = __builtin_amdgcn_mfma_f32_16x16x32_bf16(a2[ks], b, acc2[ct], 0, 0, 0);
    }
  }
  const int rbase = rowbase + (lane >> 4) * 4;
#pragma unroll
  for (int ct = 0; ct < 8; ++ct) {
    const float bv = bm2[ct * 16 + ncol];
#pragma unroll
    for (int i = 0; i < 4; ++i) {
      const int r = rbase + i;
      if (r < N_) Yb[(size_t)r * H_ + ct * 16 + ncol] = f2b(acc2[ct][i] + bv);
    }
  }
}

// ---------------------------------------------------------------------------
// Weight pack: all fp32 weights -> one bf16 arena.
// ---------------------------------------------------------------------------
constexpr int WB_EMB = 0;                 // 128x128
constexpr int WB_RO = 16384;              // 64x128
constexpr int WB_BLK = 24576;             // per block: 98304
constexpr int WB_TOTAL = 24576 + 3 * 98304;  // 319488

__global__ void convall_k(const float* __restrict__ emb_w,
                          const float* __restrict__ ro_w,
                          const float* __restrict__ er_w1,
                          const float* __restrict__ lap_w,
                          const float* __restrict__ diss_w,
                          const float* __restrict__ mlp_w1,
                          const float* __restrict__ mlp_w2,
                          u16* __restrict__ wb) {
  const int idx = blockIdx.x * 256 + threadIdx.x;
  if (idx >= WB_TOTAL) return;
  const float* src;
  size_t soff;
  if (idx < 16384) {
    src = emb_w; soff = idx;
  } else if (idx < 24576) {
    src = ro_w; soff = idx - 16384;
  } else {
    int t = idx - 24576;
    const int b = t / 98304;
    t -= b * 98304;
    if (t < 32768) {  // Wp: rows<128 -> er_w1 cols 0-127; rows>=128 -> cols 128-255
      const int r = t >> 7, c = t & 127;
      src = er_w1 + (size_t)b * 32768;
      soff = (r < 128) ? ((size_t)r * 256 + c) : ((size_t)(r - 128) * 256 + 128 + c);
    } else if (t < 65536) {  // Wfd: rows<128 lap, rows>=128 diss
      const int u = t - 32768;
      if (u < 16384) { src = lap_w + (size_t)b * 16384; soff = u; }
      else { src = diss_w + (size_t)b * 16384; soff = u - 16384; }
    } else if (t < 81920) {
      src = mlp_w1 + (size_t)b * 16384; soff = t - 65536;
    } else {
      src = mlp_w2 + (size_t)b * 16384; soff = t - 81920;
    }
  }
  wb[idx] = f2b(src[soff]);
}

// bias packs: bp[b] = [er_b1[b]; 0], bfd[b] = [0; diss_b[b]]
__global__ void biasp_k(const float* __restrict__ er_b1,
                        const float* __restrict__ diss_b,
                        float* __restrict__ bp, float* __restrict__ bfd) {
  const int b = blockIdx.x, t = threadIdx.x;
  bp[b * 256 + t] = (t < 128) ? er_b1[b * 128 + t] : 0.f;
  bfd[b * 256 + t] = (t < 128) ? 0.f : diss_b[b * 128 + (t - 128)];
}

// x_in fp32 -> bf16
__global__ void convx_k(const float* __restrict__ src, u16* __restrict__ dst) {
  const size_t i = ((size_t)blockIdx.x * 256 + threadIdx.x) * 4;
  const float4 v = *(const float4*)(src + i);
  ushort4 o;
  o.x = f2b(v.x); o.y = f2b(v.y); o.z = f2b(v.z); o.w = f2b(v.w);
  *(ushort4*)(dst + i) = o;
}

// ---------------------------------------------------------------------------
// Edge resistance, dst-sorted order, fp8 P tables (128 B rows):
//   r[i] = |w2 . relu(P1[ss[i]]+P2[ds[i]]) + b2|;  deg[src] += r.
// 32 lanes per edge, each lane owns 4 channels (one dword of fp8x4).
// ---------------------------------------------------------------------------
__global__ __launch_bounds__(256) void edge_r_k(
    const unsigned int* __restrict__ P1, const unsigned int* __restrict__ P2,
    const int* __restrict__ ss, const int* __restrict__ ds,
    const float* __restrict__ w2, const float* __restrict__ b2,
    float* __restrict__ r_out, float* __restrict__ deg) {
  const int tid = threadIdx.x;
  const int lane = tid & 63;
  const int half = lane >> 5;
  const int l = lane & 31;
  const int wid = tid >> 6;
  const size_t e = (size_t)blockIdx.x * 8 + wid * 2 + half;
  const float4 wv = *(const float4*)(w2 + l * 4);
  const int s = ss[e];
  const int d = ds[e];
  const unsigned int a4 = P1[(size_t)s * 32 + l];
  const unsigned int c4 = P2[(size_t)d * 32 + l];
  const v2f alo = dec_lo(a4), ahi = dec_hi(a4);
  const v2f clo = dec_lo(c4), chi = dec_hi(c4);
  float sum = fmaxf(alo.x + clo.x, 0.f) * wv.x;
  sum = fmaf(fmaxf(alo.y + clo.y, 0.f), wv.y, sum);
  sum = fmaf(fmaxf(ahi.x + chi.x, 0.f), wv.z, sum);
  sum = fmaf(fmaxf(ahi.y + chi.y, 0.f), wv.w, sum);
#pragma unroll
  for (int off = 16; off > 0; off >>= 1) sum += __shfl_xor(sum, off);
  if (l == 0) {
    const float rv = fabsf(sum + b2[0]);
    r_out[e] = rv;
    atomicAdd(&deg[s], rv);
  }
}

// ---------------------------------------------------------------------------
// CSR build (by dst): hist -> parallel scan -> sorted src/dst arrays.
// ---------------------------------------------------------------------------
constexpr int NSC = (N_ + 1023) / 1024;  // 49

__global__ void hist_k(const int* __restrict__ dst, int* __restrict__ cnt) {
  const int e = blockIdx.x * 256 + threadIdx.x;
  if (e < E_) atomicAdd(&cnt[dst[e]], 1);
}

__global__ __launch_bounds__(1024) void partial_k(const int* __restrict__ cnt,
                                                  int* __restrict__ psum) {
  __shared__ int sm[1024];
  const int tid = threadIdx.x;
  const int i = blockIdx.x * 1024 + tid;
  sm[tid] = (i < N_) ? cnt[i] : 0;
  __syncthreads();
  for (int off = 512; off > 0; off >>= 1) {
    if (tid < off) sm[tid] += sm[tid + off];
    __syncthreads();
  }
  if (tid == 0) psum[blockIdx.x] = sm[0];
}

__global__ __launch_bounds__(64) void scanp_k(int* __restrict__ psum) {
  const int tid = threadIdx.x;
  int v = (tid < NSC) ? psum[tid] : 0;
  const int orig = v;
#pragma unroll
  for (int off = 1; off < 64; off <<= 1) {
    const int u = __shfl_up(v, off);
    if (tid >= off) v += u;
  }
  if (tid < NSC) psum[tid] = v - orig;  // exclusive
}

__global__ __launch_bounds__(1024) void rowptr_k(const int* __restrict__ cnt,
                                                 const int* __restrict__ psum,
                                                 int* __restrict__ rowptr,
                                                 int* __restrict__ cursor) {
  __shared__ int sm[1024];
  const int tid = threadIdx.x;
  const int i = blockIdx.x * 1024 + tid;
  const int orig = (i < N_) ? cnt[i] : 0;
  sm[tid] = orig;
  __syncthreads();
  for (int off = 1; off < 1024; off <<= 1) {
    const int mine = sm[tid];
    const int u = (tid >= off) ? sm[tid - off] : 0;
    __syncthreads();
    sm[tid] = mine + u;
    __syncthreads();
  }
  const int excl = sm[tid] - orig + psum[blockIdx.x];
  if (i < N_) {
    rowptr[i] = excl;
    cursor[i] = excl;
  }
  if (i == 0) rowptr[N_] = E_;
}

__global__ void permute_k(const int* __restrict__ src,
                          const int* __restrict__ dst, int* __restrict__ cursor,
                          int* __restrict__ ss, int* __restrict__ ds) {
  const int e = blockIdx.x * 256 + threadIdx.x;
  if (e < E_) {
    const int d = dst[e];
    const int p = atomicAdd(&cursor[d], 1);
    ss[p] = src[e];
    ds[p] = d;
  }
}

// ---------------------------------------------------------------------------
// Fused aggregate + update. f/diss fp8 (128 B rows), xb/vb bf16.
// One wave per node; lane owns 2 channels (one fp8-pair = ushort).
//   agg = sum r[i]*f[ss[i]];  conv = deg*f[n] - agg
//   FIRST: v = -EPS*conv, store vb;  LAST: v = vb - EPS*(conv + diss*vb)
//   xb += EPS*v
// ---------------------------------------------------------------------------
template <bool FIRST>
__global__ __launch_bounds__(256) void agg_update_k(
    unsigned int* __restrict__ xb, unsigned int* __restrict__ vb,
    const u16* __restrict__ f8, const u16* __restrict__ diss8,
    const float* __restrict__ deg, const float* __restrict__ r,
    const int* __restrict__ ss, const int* __restrict__ rowptr) {
  const int wid = threadIdx.x >> 6;
  const int lane = threadIdx.x & 63;
  const int n = blockIdx.x * 4 + wid;
  const int beg = rowptr[n];
  const int end = rowptr[n + 1];
  float ax = 0.f, ay = 0.f;
  for (int i = beg; i < end; ++i) {
    const float rv = r[i];
    const int s = ss[i];
    const unsigned int fv = f8[(size_t)s * 64 + lane];
    const v2f fd = dec_lo(fv);
    ax = fmaf(rv, fd.x, ax);
    ay = fmaf(rv, fd.y, ay);
  }
  const size_t idx = (size_t)n * 64 + lane;
  const v2f fn = dec_lo((unsigned int)f8[idx]);
  const float dg = deg[n];
  const float cx = dg * fn.x - ax;
  const float cy = dg * fn.y - ay;
  float vx, vy;
  if (FIRST) {
    vx = -EPS_ * cx;
    vy = -EPS_ * cy;
    vb[idx] = pk(vx, vy);
  } else {
    const v2f dsv = dec_lo((unsigned int)diss8[idx]);
    const unsigned int vv = vb[idx];
    vx = b2f((u16)(vv & 0xffffu));
    vy = b2f((u16)(vv >> 16));
    vx = vx - EPS_ * (cx + dsv.x * vx);
    vy = vy - EPS_ * (cy + dsv.y * vy);
  }
  const unsigned int xv = xb[idx];
  const float nx = b2f((u16)(xv & 0xffffu)) + EPS_ * vx;
  const float ny = b2f((u16)(xv >> 16)) + EPS_ * vy;
  xb[idx] = pk(nx, ny);
}

extern "C" void kernel_launch(void* const* d_in, const int* in_sizes, int n_in,
                              void* d_out, int out_size, void* d_ws,
                              size_t ws_size, hipStream_t stream) {
  const float* x_in = (const float*)d_in[0];
  const int* ei = (const int*)d_in[1];
  const int* src = ei;
  const int* dst = ei + E_;
  const float* emb_w = (const float*)d_in[2];
  const float* emb_b = (const float*)d_in[3];
  const float* lap_w = (const float*)d_in[4];
  const float* er_w1 = (const float*)d_in[5];
  const float* er_b1 = (const float*)d_in[6];
  const float* er_w2 = (const float*)d_in[7];
  const float* er_b2 = (const float*)d_in[8];
  const float* diss_w = (const float*)d_in[9];
  const float* diss_b = (const float*)d_in[10];
  const float* mlp_w1 = (const float*)d_in[11];
  const float* mlp_b1 = (const float*)d_in[12];
  const float* mlp_w2 = (const float*)d_in[13];
  const float* mlp_b2 = (const float*)d_in[14];
  const float* ro_w = (const float*)d_in[15];
  const float* ro_b = (const float*)d_in[16];
  float* out = (float*)d_out;

  // workspace layout (float units)
  const size_t NF = (size_t)N_ * H_;
  float* ws = (float*)d_ws;
  u16* xb = (u16*)ws;               // NF bf16 (x state)
  u16* vb = xb + NF;                // NF bf16 (v)
  u16* A = vb + NF;                 // holds xin_b (bf16) OR P1/f (fp8, half used)
  u16* Bb = A + NF;                 // P2/diss (fp8, half used)
  float* r = (float*)(Bb + NF);     // E (dst-sorted)
  float* deg = r + E_;              // N
  int* rowptr = (int*)(deg + N_);   // N+1
  int* cursor = rowptr + (N_ + 1);  // N
  int* ss = cursor + N_;            // E (src, dst-sorted)
  int* ds = ss + E_;                // E (dst, dst-sorted)
  int* psum = ds + E_;              // NSC
  u16* wb = (u16*)(psum + NSC);     // WB_TOTAL bf16
  float* bp = (float*)(wb + WB_TOTAL + (WB_TOTAL & 1));  // 3*256
  float* bfd = bp + 3 * 256;        // 3*256

  const int mm_grid = (N_ + 63) / 64;  // 782
  const int e_grid = (E_ + 255) / 256;

  // pack weights/biases, convert x_in
  convall_k<<<(WB_TOTAL + 255) / 256, 256, 0, stream>>>(
      emb_w, ro_w, er_w1, lap_w, diss_w, mlp_w1, mlp_w2, wb);
  biasp_k<<<3, 256, 0, stream>>>(er_b1, diss_b, bp, bfd);
  convx_k<<<(int)(NF / 1024), 256, 0, stream>>>(x_in, A);

  // CSR by dst (topology fixed for whole launch)
  hipMemsetAsync(cursor, 0, N_ * sizeof(int), stream);
  hist_k<<<e_grid, 256, 0, stream>>>(dst, cursor);
  partial_k<<<NSC, 1024, 0, stream>>>(cursor, psum);
  scanp_k<<<1, 64, 0, stream>>>(psum);
  rowptr_k<<<NSC, 1024, 0, stream>>>(cursor, psum, rowptr, cursor);
  permute_k<<<e_grid, 256, 0, stream>>>(src, dst, cursor, ss, ds);

  // xb = emb(x_in)  (bf16 out)
  mm_k<8, 0, 0, 0, 0><<<mm_grid, 256, 0, stream>>>(A, wb + WB_EMB, emb_b, xb,
                                                   nullptr);

  for (int b = 0; b < B_; ++b) {
    const u16* Wp = wb + WB_BLK + (size_t)b * 98304;
    const u16* Wfd = Wp + 32768;
    const u16* Wm1 = Wfd + 32768;
    const u16* Wm2 = Wm1 + 16384;
    const float* b2 = er_b2 + b;
    const float* w2 = er_w2 + (size_t)b * H_;

    // P1 = xb@W1a^T + b1, P2 = xb@W1b^T  (both fp8)
    mm_k<16, 0, 0, 0, 1><<<mm_grid, 256, 0, stream>>>(xb, Wp, bp + b * 256, A,
                                                      Bb);
    hipMemsetAsync(deg, 0, N_ * sizeof(float), stream);
    edge_r_k<<<E_ / 8, 256, 0, stream>>>((const unsigned int*)A,
                                         (const unsigned int*)Bb, ss, ds, w2,
                                         b2, r, deg);

    for (int it = 0; it < ITERS_; ++it) {
      // f = xb@Wl^T (fp8); diss = relu(xb@Wd^T + bd) (fp8)
      mm_k<16, 0, 1, 0, 1><<<mm_grid, 256, 0, stream>>>(xb, Wfd, bfd + b * 256,
                                                        A, Bb);
      if (it == 0)
        agg_update_k<true><<<N_ / 4, 256, 0, stream>>>(
            (unsigned int*)xb, (unsigned int*)vb, A, Bb, deg, r, ss, rowptr);
      else
        agg_update_k<false><<<N_ / 4, 256, 0, stream>>>(
            (unsigned int*)xb, (unsigned int*)vb, A, Bb, deg, r, ss, rowptr);
    }
    // xb = tanh(xb@Wm1^T + bm1) @ Wm2^T + bm2   (fused, LDS intermediate)
    mlp_k<<<mm_grid, 256, 0, stream>>>(xb, Wm1, mlp_b1 + b * H_, Wm2,
                                       mlp_b2 + b * H_, xb);
  }
  mm_k<4, 0, 0, 2, 0><<<mm_grid, 256, 0, stream>>>(xb, wb + WB_RO, ro_b, out,
                                                   nullptr);
}

// Round 8
// 933.835 us; speedup vs baseline: 3.9916x; 1.0914x over previous
//
#include <hip/hip_runtime.h>
#include <math.h>

constexpr int N_ = 50000;
constexpr int E_ = 400000;
constexpr int H_ = 128;
constexpr int OUT_ = 64;
constexpr int B_ = 3;
constexpr int ITERS_ = 2;
constexpr float EPS_ = 0.01f;

typedef unsigned short u16;
typedef unsigned char u8;
typedef short v8s __attribute__((ext_vector_type(8)));
typedef float v4f __attribute__((ext_vector_type(4)));
typedef float v2f __attribute__((ext_vector_type(2)));

__device__ inline float b2f(u16 u) {
  union { unsigned int i; float f; } c;
  c.i = ((unsigned int)u) << 16;
  return c.f;
}
__device__ inline u16 f2b(float f) {
  union { float f; unsigned int u; } c;
  c.f = f;
  unsigned int r = c.u + 0x7fffu + ((c.u >> 16) & 1u);  // RNE
  return (u16)(r >> 16);
}
__device__ inline unsigned int pk(float a, float b) {
  return (unsigned int)f2b(a) | ((unsigned int)f2b(b) << 16);
}

#if defined(__has_builtin)
#if __has_builtin(__builtin_nontemporal_load)
#define NT_LOAD(p) __builtin_nontemporal_load(p)
#endif
#endif
#ifndef NT_LOAD
#define NT_LOAD(p) (*(p))
#endif

// ---------------- fp8 e4m3 encode/decode (HW cvt if available) -------------
#if defined(__has_builtin)
#if __has_builtin(__builtin_amdgcn_cvt_pk_f32_fp8) && \
    __has_builtin(__builtin_amdgcn_cvt_pk_fp8_f32)
#define HW_FP8 1
#endif
#endif

#ifdef HW_FP8
__device__ inline v2f dec_lo(unsigned int v) {
  return __builtin_amdgcn_cvt_pk_f32_fp8(v, false);
}
__device__ inline v2f dec_hi(unsigned int v) {
  return __builtin_amdgcn_cvt_pk_f32_fp8(v, true);
}
__device__ inline u8 enc1(float x) {
  return (u8)(__builtin_amdgcn_cvt_pk_fp8_f32(x, x, 0, false) & 0xff);
}
#else
__device__ inline float fp8_dec1(u8 v) {
  const unsigned int s = v >> 7, e = (v >> 3) & 15, m = v & 7;
  float mag = e ? __uint_as_float(((e + 120u) << 23) | (m << 20))
                : (float)m * 0.001953125f;
  return s ? -mag : mag;
}
__device__ inline v2f dec_lo(unsigned int v) {
  v2f r;
  r.x = fp8_dec1((u8)(v & 0xff));
  r.y = fp8_dec1((u8)((v >> 8) & 0xff));
  return r;
}
__device__ inline v2f dec_hi(unsigned int v) {
  v2f r;
  r.x = fp8_dec1((u8)((v >> 16) & 0xff));
  r.y = fp8_dec1((u8)((v >> 24) & 0xff));
  return r;
}
__device__ inline u8 enc1(float x) {
  union { float f; unsigned int u; } c;
  c.f = x;
  const unsigned int sgn = (c.u >> 31) << 7;
  float af = fabsf(x);
  if (af >= 448.f) return (u8)(sgn | 0x7e);
  if (af < 0.015625f) {
    int m = (int)rintf(af * 512.f);
    if (m > 7) return (u8)(sgn | 0x08);
    return (u8)(sgn | m);
  }
  unsigned int u = c.u & 0x7fffffffu;
  u += 0x7ffffu + ((u >> 20) & 1u);
  unsigned int m3 = (u >> 20) & 7;
  int e8 = (int)(u >> 23) - 120;
  if (e8 >= 15 && m3 >= 7) return (u8)(sgn | 0x7e);
  if (e8 <= 0) {
    int m = (int)rintf(af * 512.f);
    if (m > 7) m = 7;
    return (u8)(sgn | m);
  }
  return (u8)(sgn | ((unsigned)e8 << 3) | m3);
}
#endif

// ---------------------------------------------------------------------------
// MFMA GEMM: Y[r, n] = act(Xb[r,:128] . Wb[n,:128] + bias[n])
// Block = 4 waves x 16 rows. A frag: lane l holds A[l&15][(l>>4)*8+j];
// B frag: B[(l>>4)*8+j][l&15]; D: row=(l>>4)*4+i, col=l&15.
// MODE 0: Y0 (cols<128) / Y1 (cols>=128); OT 0=bf16, 1=fp8.
// MODE 2: fp32 Y0, row stride 64 (readout).
// ---------------------------------------------------------------------------
template <int NCT, int ACT0, int ACT1, int MODE, int OT>
__global__ __launch_bounds__(256) void mm_k(
    const u16* __restrict__ Xb, const u16* __restrict__ Wb,
    const float* __restrict__ bias, void* __restrict__ Y0,
    void* __restrict__ Y1) {
  const int lane = threadIdx.x & 63;
  const int wv = threadIdx.x >> 6;
  const int rowbase = blockIdx.x * 64 + wv * 16;
  int arow = rowbase + (lane & 15);
  if (arow >= N_) arow = N_ - 1;
  const int kc = (lane >> 4) * 8;

  v8s a[4];
#pragma unroll
  for (int ks = 0; ks < 4; ++ks)
    a[ks] = *(const v8s*)(Xb + (size_t)arow * H_ + ks * 32 + kc);

  v4f acc[NCT];
#pragma unroll
  for (int ct = 0; ct < NCT; ++ct) acc[ct] = (v4f)0.f;

  const int bn = lane & 15;
#pragma unroll
  for (int ct = 0; ct < NCT; ++ct) {
    const u16* wp = Wb + (size_t)(ct * 16 + bn) * H_ + kc;
#pragma unroll
    for (int ks = 0; ks < 4; ++ks) {
      v8s b = *(const v8s*)(wp + ks * 32);
      acc[ct] = __builtin_amdgcn_mfma_f32_16x16x32_bf16(a[ks], b, acc[ct], 0, 0, 0);
    }
  }

  const int rbase = rowbase + (lane >> 4) * 4;
  const int ncol = lane & 15;
#pragma unroll
  for (int ct = 0; ct < NCT; ++ct) {
    const int n = ct * 16 + ncol;
    const float bv = bias[n];
#pragma unroll
    for (int i = 0; i < 4; ++i) {
      const int r = rbase + i;
      if (r >= N_) continue;
      float y = acc[ct][i] + bv;
      if (n < H_) {
        if (ACT0 == 1) y = fmaxf(y, 0.f);
        if (ACT0 == 2) y = tanhf(y);
      } else {
        if (ACT1 == 1) y = fmaxf(y, 0.f);
        if (ACT1 == 2) y = tanhf(y);
      }
      if (MODE == 0) {
        if (OT == 0) {
          if (n < H_)
            ((u16*)Y0)[(size_t)r * H_ + n] = f2b(y);
          else
            ((u16*)Y1)[(size_t)r * H_ + n - H_] = f2b(y);
        } else {
          const u8 q = enc1(y);
          if (n < H_)
            ((u8*)Y0)[(size_t)r * H_ + n] = q;
          else
            ((u8*)Y1)[(size_t)r * H_ + n - H_] = q;
        }
      } else {
        ((float*)Y0)[(size_t)r * OUT_ + n] = y;
      }
    }
  }
}

// ---------------------------------------------------------------------------
// Fused MLP: Yb = tanh(Xb@Wm1^T + bm1) @ Wm2^T + bm2, all bf16 I/O.
// Intermediate 64x128 tile staged in LDS.
// ---------------------------------------------------------------------------
__global__ __launch_bounds__(256) void mlp_k(
    const u16* __restrict__ Xb, const u16* __restrict__ Wm1,
    const float* __restrict__ bm1, const u16* __restrict__ Wm2,
    const float* __restrict__ bm2, u16* __restrict__ Yb) {
  __shared__ u16 tmp[64][136];
  const int lane = threadIdx.x & 63;
  const int wv = threadIdx.x >> 6;
  const int rowbase = blockIdx.x * 64 + wv * 16;
  int arow = rowbase + (lane & 15);
  if (arow >= N_) arow = N_ - 1;
  const int kc = (lane >> 4) * 8;
  const int bn = lane & 15;
  const int ncol = lane & 15;
  const int rloc = wv * 16 + (lane >> 4) * 4;

  v8s a[4];
#pragma unroll
  for (int ks = 0; ks < 4; ++ks)
    a[ks] = *(const v8s*)(Xb + (size_t)arow * H_ + ks * 32 + kc);

  v4f acc[8];
#pragma unroll
  for (int ct = 0; ct < 8; ++ct) acc[ct] = (v4f)0.f;
#pragma unroll
  for (int ct = 0; ct < 8; ++ct) {
    const u16* wp = Wm1 + (size_t)(ct * 16 + bn) * H_ + kc;
#pragma unroll
    for (int ks = 0; ks < 4; ++ks) {
      v8s b = *(const v8s*)(wp + ks * 32);
      acc[ct] = __builtin_amdgcn_mfma_f32_16x16x32_bf16(a[ks], b, acc[ct], 0, 0, 0);
    }
  }
#pragma unroll
  for (int ct = 0; ct < 8; ++ct) {
    const float bv = bm1[ct * 16 + ncol];
#pragma unroll
    for (int i = 0; i < 4; ++i)
      tmp[rloc + i][ct * 16 + ncol] = f2b(tanhf(acc[ct][i] + bv));
  }
  __syncthreads();

  const int rl2 = wv * 16 + (lane & 15);
  v8s a2[4];
#pragma unroll
  for (int ks = 0; ks < 4; ++ks)
    a2[ks] = *(const v8s*)&tmp[rl2][ks * 32 + kc];

  v4f acc2[8];
#pragma unroll
  for (int ct = 0; ct < 8; ++ct) acc2[ct] = (v4f)0.f;
#pragma unroll
  for (int ct = 0; ct < 8; ++ct) {
    const u16* wp = Wm2 + (size_t)(ct * 16 + bn) * H_ + kc;
#pragma unroll
    for (int ks = 0; ks < 4; ++ks) {
      v8s b = *(const v8s*)(wp + ks * 32);
      acc2[ct] = __builtin_amdgcn_mfma_f32_16x16x32_bf16(a2[ks], b, acc2[ct], 0, 0, 0);
    }
  }
  const int rbase = rowbase + (lane >> 4) * 4;
#pragma unroll
  for (int ct = 0; ct < 8; ++ct) {
    const float bv = bm2[ct * 16 + ncol];
#pragma unroll
    for (int i = 0; i < 4; ++i) {
      const int r = rbase + i;
      if (r < N_) Yb[(size_t)r * H_ + ct * 16 + ncol] = f2b(acc2[ct][i] + bv);
    }
  }
}

// ---------------------------------------------------------------------------
// Weight pack: all fp32 weights -> one bf16 arena.
// ---------------------------------------------------------------------------
constexpr int WB_EMB = 0;                 // 128x128
constexpr int WB_RO = 16384;              // 64x128
constexpr int WB_BLK = 24576;             // per block: 98304
constexpr int WB_TOTAL = 24576 + 3 * 98304;  // 319488

__global__ void convall_k(const float* __restrict__ emb_w,
                          const float* __restrict__ ro_w,
                          const float* __restrict__ er_w1,
                          const float* __restrict__ lap_w,
                          const float* __restrict__ diss_w,
                          const float* __restrict__ mlp_w1,
                          const float* __restrict__ mlp_w2,
                          u16* __restrict__ wb) {
  const int idx = blockIdx.x * 256 + threadIdx.x;
  if (idx >= WB_TOTAL) return;
  const float* src;
  size_t soff;
  if (idx < 16384) {
    src = emb_w; soff = idx;
  } else if (idx < 24576) {
    src = ro_w; soff = idx - 16384;
  } else {
    int t = idx - 24576;
    const int b = t / 98304;
    t -= b * 98304;
    if (t < 32768) {  // Wp: rows<128 -> er_w1 cols 0-127; rows>=128 -> cols 128-255
      const int r = t >> 7, c = t & 127;
      src = er_w1 + (size_t)b * 32768;
      soff = (r < 128) ? ((size_t)r * 256 + c) : ((size_t)(r - 128) * 256 + 128 + c);
    } else if (t < 65536) {  // Wfd: rows<128 lap, rows>=128 diss
      const int u = t - 32768;
      if (u < 16384) { src = lap_w + (size_t)b * 16384; soff = u; }
      else { src = diss_w + (size_t)b * 16384; soff = u - 16384; }
    } else if (t < 81920) {
      src = mlp_w1 + (size_t)b * 16384; soff = t - 65536;
    } else {
      src = mlp_w2 + (size_t)b * 16384; soff = t - 81920;
    }
  }
  wb[idx] = f2b(src[soff]);
}

// bias packs: bp[b] = [er_b1[b]; 0], bfd[b] = [0; diss_b[b]]
__global__ void biasp_k(const float* __restrict__ er_b1,
                        const float* __restrict__ diss_b,
                        float* __restrict__ bp, float* __restrict__ bfd) {
  const int b = blockIdx.x, t = threadIdx.x;
  bp[b * 256 + t] = (t < 128) ? er_b1[b * 128 + t] : 0.f;
  bfd[b * 256 + t] = (t < 128) ? 0.f : diss_b[b * 128 + (t - 128)];
}

// x_in fp32 -> bf16
__global__ void convx_k(const float* __restrict__ src, u16* __restrict__ dst) {
  const size_t i = ((size_t)blockIdx.x * 256 + threadIdx.x) * 4;
  const float4 v = *(const float4*)(src + i);
  ushort4 o;
  o.x = f2b(v.x); o.y = f2b(v.y); o.z = f2b(v.z); o.w = f2b(v.w);
  *(ushort4*)(dst + i) = o;
}

// ---------------------------------------------------------------------------
// Edge resistance, dst-sorted order, fp8 P tables (128 B rows):
//   r[i] = |w2 . relu(P1[ss[i]]+P2[ds[i]]) + b2|;  deg[src] += r.
// 32 lanes per edge, each lane owns 4 channels (one dword of fp8x4).
// ---------------------------------------------------------------------------
__global__ __launch_bounds__(256) void edge_r_k(
    const unsigned int* __restrict__ P1, const unsigned int* __restrict__ P2,
    const int* __restrict__ ss, const int* __restrict__ ds,
    const float* __restrict__ w2, const float* __restrict__ b2,
    float* __restrict__ r_out, float* __restrict__ deg) {
  const int tid = threadIdx.x;
  const int lane = tid & 63;
  const int half = lane >> 5;
  const int l = lane & 31;
  const int wid = tid >> 6;
  const size_t e = (size_t)blockIdx.x * 8 + wid * 2 + half;
  const float4 wv = *(const float4*)(w2 + l * 4);
  const int s = ss[e];
  const int d = ds[e];
  const unsigned int a4 = P1[(size_t)s * 32 + l];
  const unsigned int c4 = P2[(size_t)d * 32 + l];
  const v2f alo = dec_lo(a4), ahi = dec_hi(a4);
  const v2f clo = dec_lo(c4), chi = dec_hi(c4);
  float sum = fmaxf(alo.x + clo.x, 0.f) * wv.x;
  sum = fmaf(fmaxf(alo.y + clo.y, 0.f), wv.y, sum);
  sum = fmaf(fmaxf(ahi.x + chi.x, 0.f), wv.z, sum);
  sum = fmaf(fmaxf(ahi.y + chi.y, 0.f), wv.w, sum);
#pragma unroll
  for (int off = 16; off > 0; off >>= 1) sum += __shfl_xor(sum, off);
  if (l == 0) {
    const float rv = fabsf(sum + b2[0]);
    r_out[e] = rv;
    atomicAdd(&deg[s], rv);
  }
}

// ---------------------------------------------------------------------------
// CSR build (by dst): hist -> parallel scan -> sorted src/dst arrays.
// ---------------------------------------------------------------------------
constexpr int NSC = (N_ + 1023) / 1024;  // 49

__global__ void hist_k(const int* __restrict__ dst, int* __restrict__ cnt) {
  const int e = blockIdx.x * 256 + threadIdx.x;
  if (e < E_) atomicAdd(&cnt[dst[e]], 1);
}

__global__ __launch_bounds__(1024) void partial_k(const int* __restrict__ cnt,
                                                  int* __restrict__ psum) {
  __shared__ int sm[1024];
  const int tid = threadIdx.x;
  const int i = blockIdx.x * 1024 + tid;
  sm[tid] = (i < N_) ? cnt[i] : 0;
  __syncthreads();
  for (int off = 512; off > 0; off >>= 1) {
    if (tid < off) sm[tid] += sm[tid + off];
    __syncthreads();
  }
  if (tid == 0) psum[blockIdx.x] = sm[0];
}

__global__ __launch_bounds__(64) void scanp_k(int* __restrict__ psum) {
  const int tid = threadIdx.x;
  int v = (tid < NSC) ? psum[tid] : 0;
  const int orig = v;
#pragma unroll
  for (int off = 1; off < 64; off <<= 1) {
    const int u = __shfl_up(v, off);
    if (tid >= off) v += u;
  }
  if (tid < NSC) psum[tid] = v - orig;  // exclusive
}

__global__ __launch_bounds__(1024) void rowptr_k(const int* __restrict__ cnt,
                                                 const int* __restrict__ psum,
                                                 int* __restrict__ rowptr,
                                                 int* __restrict__ cursor) {
  __shared__ int sm[1024];
  const int tid = threadIdx.x;
  const int i = blockIdx.x * 1024 + tid;
  const int orig = (i < N_) ? cnt[i] : 0;
  sm[tid] = orig;
  __syncthreads();
  for (int off = 1; off < 1024; off <<= 1) {
    const int mine = sm[tid];
    const int u = (tid >= off) ? sm[tid - off] : 0;
    __syncthreads();
    sm[tid] = mine + u;
    __syncthreads();
  }
  const int excl = sm[tid] - orig + psum[blockIdx.x];
  if (i < N_) {
    rowptr[i] = excl;
    cursor[i] = excl;
  }
  if (i == 0) rowptr[N_] = E_;
}

__global__ void permute_k(const int* __restrict__ src,
                          const int* __restrict__ dst, int* __restrict__ cursor,
                          int* __restrict__ ss, int* __restrict__ ds) {
  const int e = blockIdx.x * 256 + threadIdx.x;
  if (e < E_) {
    const int d = dst[e];
    const int p = atomicAdd(&cursor[d], 1);
    ss[p] = src[e];
    ds[p] = d;
  }
}

// ---------------------------------------------------------------------------
// Fused aggregate + update. f/diss fp8 (128 B rows), xb/vb bf16.
// One wave per node; lane owns 2 channels (one fp8-pair = ushort).
// Edge loop unrolled 4-deep: 4 independent row-gathers in flight per wave
// (latency-bound fix, r7 post-mortem). r/ss loads nontemporal (no L2 value).
//   agg = sum r[i]*f[ss[i]];  conv = deg*f[n] - agg
//   FIRST: v = -EPS*conv, store vb;  LAST: v = vb - EPS*(conv + diss*vb)
//   xb += EPS*v
// ---------------------------------------------------------------------------
template <bool FIRST>
__global__ __launch_bounds__(256) void agg_update_k(
    unsigned int* __restrict__ xb, unsigned int* __restrict__ vb,
    const u16* __restrict__ f8, const u16* __restrict__ diss8,
    const float* __restrict__ deg, const float* __restrict__ r,
    const int* __restrict__ ss, const int* __restrict__ rowptr) {
  const int wid = threadIdx.x >> 6;
  const int lane = threadIdx.x & 63;
  const int n = blockIdx.x * 4 + wid;
  const int beg = rowptr[n];
  const int end = rowptr[n + 1];
  float ax = 0.f, ay = 0.f;
  for (int i = beg; i < end; i += 4) {
    const int e1 = (i + 1 < end) ? i + 1 : i;
    const int e2 = (i + 2 < end) ? i + 2 : i;
    const int e3 = (i + 3 < end) ? i + 3 : i;
    const int s0 = NT_LOAD(ss + i);
    const int s1 = NT_LOAD(ss + e1);
    const int s2 = NT_LOAD(ss + e2);
    const int s3 = NT_LOAD(ss + e3);
    const float r0 = NT_LOAD(r + i);
    const float r1 = (i + 1 < end) ? NT_LOAD(r + e1) : 0.f;
    const float r2 = (i + 2 < end) ? NT_LOAD(r + e2) : 0.f;
    const float r3 = (i + 3 < end) ? NT_LOAD(r + e3) : 0.f;
    const unsigned int f0 = f8[(size_t)s0 * 64 + lane];
    const unsigned int f1 = f8[(size_t)s1 * 64 + lane];
    const unsigned int f2 = f8[(size_t)s2 * 64 + lane];
    const unsigned int f3 = f8[(size_t)s3 * 64 + lane];
    const v2f d0 = dec_lo(f0);
    const v2f d1 = dec_lo(f1);
    const v2f d2 = dec_lo(f2);
    const v2f d3 = dec_lo(f3);
    ax = fmaf(r0, d0.x, ax);
    ay = fmaf(r0, d0.y, ay);
    ax = fmaf(r1, d1.x, ax);
    ay = fmaf(r1, d1.y, ay);
    ax = fmaf(r2, d2.x, ax);
    ay = fmaf(r2, d2.y, ay);
    ax = fmaf(r3, d3.x, ax);
    ay = fmaf(r3, d3.y, ay);
  }
  const size_t idx = (size_t)n * 64 + lane;
  const v2f fn = dec_lo((unsigned int)f8[idx]);
  const float dg = deg[n];
  const float cx = dg * fn.x - ax;
  const float cy = dg * fn.y - ay;
  float vx, vy;
  if (FIRST) {
    vx = -EPS_ * cx;
    vy = -EPS_ * cy;
    vb[idx] = pk(vx, vy);
  } else {
    const v2f dsv = dec_lo((unsigned int)diss8[idx]);
    const unsigned int vv = vb[idx];
    vx = b2f((u16)(vv & 0xffffu));
    vy = b2f((u16)(vv >> 16));
    vx = vx - EPS_ * (cx + dsv.x * vx);
    vy = vy - EPS_ * (cy + dsv.y * vy);
  }
  const unsigned int xv = xb[idx];
  const float nx = b2f((u16)(xv & 0xffffu)) + EPS_ * vx;
  const float ny = b2f((u16)(xv >> 16)) + EPS_ * vy;
  xb[idx] = pk(nx, ny);
}

extern "C" void kernel_launch(void* const* d_in, const int* in_sizes, int n_in,
                              void* d_out, int out_size, void* d_ws,
                              size_t ws_size, hipStream_t stream) {
  const float* x_in = (const float*)d_in[0];
  const int* ei = (const int*)d_in[1];
  const int* src = ei;
  const int* dst = ei + E_;
  const float* emb_w = (const float*)d_in[2];
  const float* emb_b = (const float*)d_in[3];
  const float* lap_w = (const float*)d_in[4];
  const float* er_w1 = (const float*)d_in[5];
  const float* er_b1 = (const float*)d_in[6];
  const float* er_w2 = (const float*)d_in[7];
  const float* er_b2 = (const float*)d_in[8];
  const float* diss_w = (const float*)d_in[9];
  const float* diss_b = (const float*)d_in[10];
  const float* mlp_w1 = (const float*)d_in[11];
  const float* mlp_b1 = (const float*)d_in[12];
  const float* mlp_w2 = (const float*)d_in[13];
  const float* mlp_b2 = (const float*)d_in[14];
  const float* ro_w = (const float*)d_in[15];
  const float* ro_b = (const float*)d_in[16];
  float* out = (float*)d_out;

  // workspace layout (float units)
  const size_t NF = (size_t)N_ * H_;
  float* ws = (float*)d_ws;
  u16* xb = (u16*)ws;               // NF bf16 (x state)
  u16* vb = xb + NF;                // NF bf16 (v)
  u16* A = vb + NF;                 // holds xin_b (bf16) OR P1/f (fp8, half used)
  u16* Bb = A + NF;                 // P2/diss (fp8, half used)
  float* r = (float*)(Bb + NF);     // E (dst-sorted)
  float* deg = r + E_;              // N
  int* rowptr = (int*)(deg + N_);   // N+1
  int* cursor = rowptr + (N_ + 1);  // N
  int* ss = cursor + N_;            // E (src, dst-sorted)
  int* ds = ss + E_;                // E (dst, dst-sorted)
  int* psum = ds + E_;              // NSC
  u16* wb = (u16*)(psum + NSC);     // WB_TOTAL bf16
  float* bp = (float*)(wb + WB_TOTAL + (WB_TOTAL & 1));  // 3*256
  float* bfd = bp + 3 * 256;        // 3*256

  const int mm_grid = (N_ + 63) / 64;  // 782
  const int e_grid = (E_ + 255) / 256;

  // pack weights/biases, convert x_in
  convall_k<<<(WB_TOTAL + 255) / 256, 256, 0, stream>>>(
      emb_w, ro_w, er_w1, lap_w, diss_w, mlp_w1, mlp_w2, wb);
  biasp_k<<<3, 256, 0, stream>>>(er_b1, diss_b, bp, bfd);
  convx_k<<<(int)(NF / 1024), 256, 0, stream>>>(x_in, A);

  // CSR by dst (topology fixed for whole launch)
  hipMemsetAsync(cursor, 0, N_ * sizeof(int), stream);
  hist_k<<<e_grid, 256, 0, stream>>>(dst, cursor);
  partial_k<<<NSC, 1024, 0, stream>>>(cursor, psum);
  scanp_k<<<1, 64, 0, stream>>>(psum);
  rowptr_k<<<NSC, 1024, 0, stream>>>(cursor, psum, rowptr, cursor);
  permute_k<<<e_grid, 256, 0, stream>>>(src, dst, cursor, ss, ds);

  // xb = emb(x_in)  (bf16 out)
  mm_k<8, 0, 0, 0, 0><<<mm_grid, 256, 0, stream>>>(A, wb + WB_EMB, emb_b, xb,
                                                   nullptr);

  for (int b = 0; b < B_; ++b) {
    const u16* Wp = wb + WB_BLK + (size_t)b * 98304;
    const u16* Wfd = Wp + 32768;
    const u16* Wm1 = Wfd + 32768;
    const u16* Wm2 = Wm1 + 16384;
    const float* b2 = er_b2 + b;
    const float* w2 = er_w2 + (size_t)b * H_;

    // P1 = xb@W1a^T + b1, P2 = xb@W1b^T  (both fp8)
    mm_k<16, 0, 0, 0, 1><<<mm_grid, 256, 0, stream>>>(xb, Wp, bp + b * 256, A,
                                                      Bb);
    hipMemsetAsync(deg, 0, N_ * sizeof(float), stream);
    edge_r_k<<<E_ / 8, 256, 0, stream>>>((const unsigned int*)A,
                                         (const unsigned int*)Bb, ss, ds, w2,
                                         b2, r, deg);

    for (int it = 0; it < ITERS_; ++it) {
      // f = xb@Wl^T (fp8); diss = relu(xb@Wd^T + bd) (fp8)
      mm_k<16, 0, 1, 0, 1><<<mm_grid, 256, 0, stream>>>(xb, Wfd, bfd + b * 256,
                                                        A, Bb);
      if (it == 0)
        agg_update_k<true><<<N_ / 4, 256, 0, stream>>>(
            (unsigned int*)xb, (unsigned int*)vb, A, Bb, deg, r, ss, rowptr);
      else
        agg_update_k<false><<<N_ / 4, 256, 0, stream>>>(
            (unsigned int*)xb, (unsigned int*)vb, A, Bb, deg, r, ss, rowptr);
    }
    // xb = tanh(xb@Wm1^T + bm1) @ Wm2^T + bm2   (fused, LDS intermediate)
    mlp_k<<<mm_grid, 256, 0, stream>>>(xb, Wm1, mlp_b1 + b * H_, Wm2,
                                       mlp_b2 + b * H_, xb);
  }
  mm_k<4, 0, 0, 2, 0><<<mm_grid, 256, 0, stream>>>(xb, wb + WB_RO, ro_b, out,
                                                   nullptr);
}

// Round 9
// 802.823 us; speedup vs baseline: 4.6430x; 1.1632x over previous
//
#include <hip/hip_runtime.h>
#include <math.h>

constexpr int N_ = 50000;
constexpr int E_ = 400000;
constexpr int H_ = 128;
constexpr int OUT_ = 64;
constexpr int B_ = 3;
constexpr int ITERS_ = 2;
constexpr float EPS_ = 0.01f;

typedef unsigned short u16;
typedef unsigned char u8;
typedef short v8s __attribute__((ext_vector_type(8)));
typedef float v4f __attribute__((ext_vector_type(4)));
typedef float v2f __attribute__((ext_vector_type(2)));

__device__ inline float b2f(u16 u) {
  union { unsigned int i; float f; } c;
  c.i = ((unsigned int)u) << 16;
  return c.f;
}
__device__ inline u16 f2b(float f) {
  union { float f; unsigned int u; } c;
  c.f = f;
  unsigned int r = c.u + 0x7fffu + ((c.u >> 16) & 1u);  // RNE
  return (u16)(r >> 16);
}
__device__ inline unsigned int pk(float a, float b) {
  return (unsigned int)f2b(a) | ((unsigned int)f2b(b) << 16);
}

#if defined(__has_builtin)
#if __has_builtin(__builtin_nontemporal_load)
#define NT_LOAD(p) __builtin_nontemporal_load(p)
#endif
#endif
#ifndef NT_LOAD
#define NT_LOAD(p) (*(p))
#endif

// ---------------- fp8 e4m3 encode/decode (HW cvt if available) -------------
#if defined(__has_builtin)
#if __has_builtin(__builtin_amdgcn_cvt_pk_f32_fp8) && \
    __has_builtin(__builtin_amdgcn_cvt_pk_fp8_f32)
#define HW_FP8 1
#endif
#endif

#ifdef HW_FP8
__device__ inline v2f dec_lo(unsigned int v) {
  return __builtin_amdgcn_cvt_pk_f32_fp8(v, false);
}
__device__ inline v2f dec_hi(unsigned int v) {
  return __builtin_amdgcn_cvt_pk_f32_fp8(v, true);
}
__device__ inline u8 enc1(float x) {
  return (u8)(__builtin_amdgcn_cvt_pk_fp8_f32(x, x, 0, false) & 0xff);
}
#else
__device__ inline float fp8_dec1(u8 v) {
  const unsigned int s = v >> 7, e = (v >> 3) & 15, m = v & 7;
  float mag = e ? __uint_as_float(((e + 120u) << 23) | (m << 20))
                : (float)m * 0.001953125f;
  return s ? -mag : mag;
}
__device__ inline v2f dec_lo(unsigned int v) {
  v2f r;
  r.x = fp8_dec1((u8)(v & 0xff));
  r.y = fp8_dec1((u8)((v >> 8) & 0xff));
  return r;
}
__device__ inline v2f dec_hi(unsigned int v) {
  v2f r;
  r.x = fp8_dec1((u8)((v >> 16) & 0xff));
  r.y = fp8_dec1((u8)((v >> 24) & 0xff));
  return r;
}
__device__ inline u8 enc1(float x) {
  union { float f; unsigned int u; } c;
  c.f = x;
  const unsigned int sgn = (c.u >> 31) << 7;
  float af = fabsf(x);
  if (af >= 448.f) return (u8)(sgn | 0x7e);
  if (af < 0.015625f) {
    int m = (int)rintf(af * 512.f);
    if (m > 7) return (u8)(sgn | 0x08);
    return (u8)(sgn | m);
  }
  unsigned int u = c.u & 0x7fffffffu;
  u += 0x7ffffu + ((u >> 20) & 1u);
  unsigned int m3 = (u >> 20) & 7;
  int e8 = (int)(u >> 23) - 120;
  if (e8 >= 15 && m3 >= 7) return (u8)(sgn | 0x7e);
  if (e8 <= 0) {
    int m = (int)rintf(af * 512.f);
    if (m > 7) m = 7;
    return (u8)(sgn | m);
  }
  return (u8)(sgn | ((unsigned)e8 << 3) | m3);
}
#endif

// ---------------------------------------------------------------------------
// Col-sliced MFMA GEMM: block = NW waves over the SAME 64 rows; wave w owns
// cols [64w, 64w+64). All 16 B-fragments hoisted into VGPRs up front (one
// latency exposure), then 4 row-tiles x 16 MFMA reuse them (r8 post-mortem:
// the old interleaved form was 10x off roofline, latency-bound on B loads).
// A frag: lane l holds A[l&15][(l>>4)*8+j]; B frag: B[(l>>4)*8+j][l&15];
// D: row=(l>>4)*4+i, col=l&15.
// Output cols route by 128-seg: seg = n>>7 -> y0..y3, act A0..A3.
// OT: 0 = bf16 (stride H), 1 = fp8 (stride H), 2 = fp32 (stride OUT_).
// ---------------------------------------------------------------------------
template <int NW, int OT, int A0, int A1, int A2, int A3>
__global__ __launch_bounds__(NW * 64) void mmw_k(
    const u16* __restrict__ Xb, const u16* __restrict__ Wb,
    const float* __restrict__ bias, void* __restrict__ y0,
    void* __restrict__ y1, void* __restrict__ y2, void* __restrict__ y3) {
  const int lane = threadIdx.x & 63;
  const int wv = threadIdx.x >> 6;
  const int rowbase = blockIdx.x * 64;
  const int cb = wv * 64;
  const int bn = lane & 15;
  const int kc = (lane >> 4) * 8;

  // hoisted B fragments: 16 independent loads, one drain
  v8s bf[4][4];
#pragma unroll
  for (int ct = 0; ct < 4; ++ct) {
    const u16* wp = Wb + (size_t)(cb + ct * 16 + bn) * H_ + kc;
#pragma unroll
    for (int ks = 0; ks < 4; ++ks) bf[ct][ks] = *(const v8s*)(wp + ks * 32);
  }

  v4f acc[4][4];
#pragma unroll
  for (int ct = 0; ct < 4; ++ct)
#pragma unroll
    for (int rt = 0; rt < 4; ++rt) acc[ct][rt] = (v4f)0.f;

#pragma unroll
  for (int rt = 0; rt < 4; ++rt) {
    int arow = rowbase + rt * 16 + bn;
    if (arow >= N_) arow = N_ - 1;
    v8s a[4];
#pragma unroll
    for (int ks = 0; ks < 4; ++ks)
      a[ks] = *(const v8s*)(Xb + (size_t)arow * H_ + ks * 32 + kc);
#pragma unroll
    for (int ct = 0; ct < 4; ++ct)
#pragma unroll
      for (int ks = 0; ks < 4; ++ks)
        acc[ct][rt] =
            __builtin_amdgcn_mfma_f32_16x16x32_bf16(a[ks], bf[ct][ks],
                                                    acc[ct][rt], 0, 0, 0);
  }

  const int ncol = lane & 15;
  const int rsub = (lane >> 4) * 4;
#pragma unroll
  for (int ct = 0; ct < 4; ++ct) {
    const int n = cb + ct * 16 + ncol;
    const int seg = n >> 7;
    const float bv = bias[n];
    void* yp = (seg == 0) ? y0 : (seg == 1) ? y1 : (seg == 2) ? y2 : y3;
    const int act = (seg == 0) ? A0 : (seg == 1) ? A1 : (seg == 2) ? A2 : A3;
    const int off = n & 127;
#pragma unroll
    for (int rt = 0; rt < 4; ++rt) {
#pragma unroll
      for (int i = 0; i < 4; ++i) {
        const int r = rowbase + rt * 16 + rsub + i;
        if (r >= N_) continue;
        float yv = acc[ct][rt][i] + bv;
        if (act == 1) yv = fmaxf(yv, 0.f);
        if (act == 2) yv = tanhf(yv);
        if (OT == 0)
          ((u16*)yp)[(size_t)r * H_ + off] = f2b(yv);
        else if (OT == 1)
          ((u8*)yp)[(size_t)r * H_ + off] = enc1(yv);
        else
          ((float*)yp)[(size_t)r * OUT_ + n] = yv;
      }
    }
  }
}

// ---------------------------------------------------------------------------
// Fused MLP, col-sliced: 2 waves x 64 cols over 64 rows; LDS intermediate.
// Yb = tanh(Xb@Wm1^T + bm1) @ Wm2^T + bm2  (bf16 in/out, in-place safe:
// block only touches its own 64 rows; layer-1 reads complete before barrier).
// ---------------------------------------------------------------------------
__global__ __launch_bounds__(128) void mlp2_k(
    const u16* __restrict__ Xb, const u16* __restrict__ Wm1,
    const float* __restrict__ bm1, const u16* __restrict__ Wm2,
    const float* __restrict__ bm2, u16* __restrict__ Yb) {
  __shared__ u16 tmp[64][136];
  const int lane = threadIdx.x & 63;
  const int wv = threadIdx.x >> 6;
  const int rowbase = blockIdx.x * 64;
  const int cb = wv * 64;
  const int bn = lane & 15;
  const int kc = (lane >> 4) * 8;
  const int ncol = lane & 15;
  const int rsub = (lane >> 4) * 4;

  // ---- layer 1 ----
  v8s bf[4][4];
#pragma unroll
  for (int ct = 0; ct < 4; ++ct) {
    const u16* wp = Wm1 + (size_t)(cb + ct * 16 + bn) * H_ + kc;
#pragma unroll
    for (int ks = 0; ks < 4; ++ks) bf[ct][ks] = *(const v8s*)(wp + ks * 32);
  }
  v4f acc[4][4];
#pragma unroll
  for (int ct = 0; ct < 4; ++ct)
#pragma unroll
    for (int rt = 0; rt < 4; ++rt) acc[ct][rt] = (v4f)0.f;
#pragma unroll
  for (int rt = 0; rt < 4; ++rt) {
    int arow = rowbase + rt * 16 + bn;
    if (arow >= N_) arow = N_ - 1;
    v8s a[4];
#pragma unroll
    for (int ks = 0; ks < 4; ++ks)
      a[ks] = *(const v8s*)(Xb + (size_t)arow * H_ + ks * 32 + kc);
#pragma unroll
    for (int ct = 0; ct < 4; ++ct)
#pragma unroll
      for (int ks = 0; ks < 4; ++ks)
        acc[ct][rt] =
            __builtin_amdgcn_mfma_f32_16x16x32_bf16(a[ks], bf[ct][ks],
                                                    acc[ct][rt], 0, 0, 0);
  }
#pragma unroll
  for (int ct = 0; ct < 4; ++ct) {
    const float bv = bm1[cb + ct * 16 + ncol];
#pragma unroll
    for (int rt = 0; rt < 4; ++rt)
#pragma unroll
      for (int i = 0; i < 4; ++i)
        tmp[rt * 16 + rsub + i][cb + ct * 16 + ncol] =
            f2b(tanhf(acc[ct][rt][i] + bv));
  }
  __syncthreads();

  // ---- layer 2 ----
#pragma unroll
  for (int ct = 0; ct < 4; ++ct) {
    const u16* wp = Wm2 + (size_t)(cb + ct * 16 + bn) * H_ + kc;
#pragma unroll
    for (int ks = 0; ks < 4; ++ks) bf[ct][ks] = *(const v8s*)(wp + ks * 32);
  }
#pragma unroll
  for (int ct = 0; ct < 4; ++ct)
#pragma unroll
    for (int rt = 0; rt < 4; ++rt) acc[ct][rt] = (v4f)0.f;
#pragma unroll
  for (int rt = 0; rt < 4; ++rt) {
    const int arow = rt * 16 + bn;
    v8s a[4];
#pragma unroll
    for (int ks = 0; ks < 4; ++ks)
      a[ks] = *(const v8s*)&tmp[arow][ks * 32 + kc];
#pragma unroll
    for (int ct = 0; ct < 4; ++ct)
#pragma unroll
      for (int ks = 0; ks < 4; ++ks)
        acc[ct][rt] =
            __builtin_amdgcn_mfma_f32_16x16x32_bf16(a[ks], bf[ct][ks],
                                                    acc[ct][rt], 0, 0, 0);
  }
#pragma unroll
  for (int ct = 0; ct < 4; ++ct) {
    const float bv = bm2[cb + ct * 16 + ncol];
#pragma unroll
    for (int rt = 0; rt < 4; ++rt)
#pragma unroll
      for (int i = 0; i < 4; ++i) {
        const int r = rowbase + rt * 16 + rsub + i;
        if (r < N_)
          Yb[(size_t)r * H_ + cb + ct * 16 + ncol] = f2b(acc[ct][rt][i] + bv);
      }
  }
}

// ---------------------------------------------------------------------------
// Weight pack: all fp32 weights -> one bf16 arena.
// ---------------------------------------------------------------------------
constexpr int WB_EMB = 0;                 // 128x128
constexpr int WB_RO = 16384;              // 64x128
constexpr int WB_BLK = 24576;             // per block: 98304
constexpr int WB_TOTAL = 24576 + 3 * 98304;  // 319488

__global__ void convall_k(const float* __restrict__ emb_w,
                          const float* __restrict__ ro_w,
                          const float* __restrict__ er_w1,
                          const float* __restrict__ lap_w,
                          const float* __restrict__ diss_w,
                          const float* __restrict__ mlp_w1,
                          const float* __restrict__ mlp_w2,
                          u16* __restrict__ wb) {
  const int idx = blockIdx.x * 256 + threadIdx.x;
  if (idx >= WB_TOTAL) return;
  const float* src;
  size_t soff;
  if (idx < 16384) {
    src = emb_w; soff = idx;
  } else if (idx < 24576) {
    src = ro_w; soff = idx - 16384;
  } else {
    int t = idx - 24576;
    const int b = t / 98304;
    t -= b * 98304;
    if (t < 32768) {  // Wp: rows<128 -> er_w1 cols 0-127; rows>=128 -> cols 128-255
      const int r = t >> 7, c = t & 127;
      src = er_w1 + (size_t)b * 32768;
      soff = (r < 128) ? ((size_t)r * 256 + c) : ((size_t)(r - 128) * 256 + 128 + c);
    } else if (t < 65536) {  // Wfd: rows<128 lap, rows>=128 diss
      const int u = t - 32768;
      if (u < 16384) { src = lap_w + (size_t)b * 16384; soff = u; }
      else { src = diss_w + (size_t)b * 16384; soff = u - 16384; }
    } else if (t < 81920) {
      src = mlp_w1 + (size_t)b * 16384; soff = t - 65536;
    } else {
      src = mlp_w2 + (size_t)b * 16384; soff = t - 81920;
    }
  }
  wb[idx] = f2b(src[soff]);
}

// bp512[b] = [er_b1[b]; 0(128); 0(128); diss_b[b]] for the merged 512-col GEMM
// bfd[b]   = [0(128); diss_b[b]] for the it=1 f/diss GEMM
__global__ void biasp_k(const float* __restrict__ er_b1,
                        const float* __restrict__ diss_b,
                        float* __restrict__ bp512, float* __restrict__ bfd) {
  const int b = blockIdx.x, t = threadIdx.x;  // 512 threads
  float v = 0.f;
  if (t < 128) v = er_b1[b * 128 + t];
  else if (t >= 384) v = diss_b[b * 128 + (t - 384)];
  bp512[b * 512 + t] = v;
  if (t < 256) bfd[b * 256 + t] = (t < 128) ? 0.f : diss_b[b * 128 + (t - 128)];
}

// x_in fp32 -> bf16
__global__ void convx_k(const float* __restrict__ src, u16* __restrict__ dst) {
  const size_t i = ((size_t)blockIdx.x * 256 + threadIdx.x) * 4;
  const float4 v = *(const float4*)(src + i);
  ushort4 o;
  o.x = f2b(v.x); o.y = f2b(v.y); o.z = f2b(v.z); o.w = f2b(v.w);
  *(ushort4*)(dst + i) = o;
}

// ---------------------------------------------------------------------------
// Edge resistance, dst-sorted order, fp8 P tables (128 B rows):
//   r[i] = |w2 . relu(P1[ss[i]]+P2[ds[i]]) + b2|;  deg[src] += r.
// ---------------------------------------------------------------------------
__global__ __launch_bounds__(256) void edge_r_k(
    const unsigned int* __restrict__ P1, const unsigned int* __restrict__ P2,
    const int* __restrict__ ss, const int* __restrict__ ds,
    const float* __restrict__ w2, const float* __restrict__ b2,
    float* __restrict__ r_out, float* __restrict__ deg) {
  const int tid = threadIdx.x;
  const int lane = tid & 63;
  const int half = lane >> 5;
  const int l = lane & 31;
  const int wid = tid >> 6;
  const size_t e = (size_t)blockIdx.x * 8 + wid * 2 + half;
  const float4 wv = *(const float4*)(w2 + l * 4);
  const int s = ss[e];
  const int d = ds[e];
  const unsigned int a4 = P1[(size_t)s * 32 + l];
  const unsigned int c4 = P2[(size_t)d * 32 + l];
  const v2f alo = dec_lo(a4), ahi = dec_hi(a4);
  const v2f clo = dec_lo(c4), chi = dec_hi(c4);
  float sum = fmaxf(alo.x + clo.x, 0.f) * wv.x;
  sum = fmaf(fmaxf(alo.y + clo.y, 0.f), wv.y, sum);
  sum = fmaf(fmaxf(ahi.x + chi.x, 0.f), wv.z, sum);
  sum = fmaf(fmaxf(ahi.y + chi.y, 0.f), wv.w, sum);
#pragma unroll
  for (int off = 16; off > 0; off >>= 1) sum += __shfl_xor(sum, off);
  if (l == 0) {
    const float rv = fabsf(sum + b2[0]);
    r_out[e] = rv;
    atomicAdd(&deg[s], rv);
  }
}

// ---------------------------------------------------------------------------
// CSR build (by dst): hist -> parallel scan -> sorted src/dst arrays.
// ---------------------------------------------------------------------------
constexpr int NSC = (N_ + 1023) / 1024;  // 49

__global__ void hist_k(const int* __restrict__ dst, int* __restrict__ cnt) {
  const int e = blockIdx.x * 256 + threadIdx.x;
  if (e < E_) atomicAdd(&cnt[dst[e]], 1);
}

__global__ __launch_bounds__(1024) void partial_k(const int* __restrict__ cnt,
                                                  int* __restrict__ psum) {
  __shared__ int sm[1024];
  const int tid = threadIdx.x;
  const int i = blockIdx.x * 1024 + tid;
  sm[tid] = (i < N_) ? cnt[i] : 0;
  __syncthreads();
  for (int off = 512; off > 0; off >>= 1) {
    if (tid < off) sm[tid] += sm[tid + off];
    __syncthreads();
  }
  if (tid == 0) psum[blockIdx.x] = sm[0];
}

__global__ __launch_bounds__(64) void scanp_k(int* __restrict__ psum) {
  const int tid = threadIdx.x;
  int v = (tid < NSC) ? psum[tid] : 0;
  const int orig = v;
#pragma unroll
  for (int off = 1; off < 64; off <<= 1) {
    const int u = __shfl_up(v, off);
    if (tid >= off) v += u;
  }
  if (tid < NSC) psum[tid] = v - orig;  // exclusive
}

__global__ __launch_bounds__(1024) void rowptr_k(const int* __restrict__ cnt,
                                                 const int* __restrict__ psum,
                                                 int* __restrict__ rowptr,
                                                 int* __restrict__ cursor) {
  __shared__ int sm[1024];
  const int tid = threadIdx.x;
  const int i = blockIdx.x * 1024 + tid;
  const int orig = (i < N_) ? cnt[i] : 0;
  sm[tid] = orig;
  __syncthreads();
  for (int off = 1; off < 1024; off <<= 1) {
    const int mine = sm[tid];
    const int u = (tid >= off) ? sm[tid - off] : 0;
    __syncthreads();
    sm[tid] = mine + u;
    __syncthreads();
  }
  const int excl = sm[tid] - orig + psum[blockIdx.x];
  if (i < N_) {
    rowptr[i] = excl;
    cursor[i] = excl;
  }
  if (i == 0) rowptr[N_] = E_;
}

__global__ void permute_k(const int* __restrict__ src,
                          const int* __restrict__ dst, int* __restrict__ cursor,
                          int* __restrict__ ss, int* __restrict__ ds) {
  const int e = blockIdx.x * 256 + threadIdx.x;
  if (e < E_) {
    const int d = dst[e];
    const int p = atomicAdd(&cursor[d], 1);
    ss[p] = src[e];
    ds[p] = d;
  }
}

// ---------------------------------------------------------------------------
// Fused aggregate + update. f/diss fp8 (128 B rows), xb/vb bf16.
// One wave per node; 4-deep unrolled gather (latency cover, r7 fix).
// ---------------------------------------------------------------------------
template <bool FIRST>
__global__ __launch_bounds__(256) void agg_update_k(
    unsigned int* __restrict__ xb, unsigned int* __restrict__ vb,
    const u16* __restrict__ f8, const u16* __restrict__ diss8,
    const float* __restrict__ deg, const float* __restrict__ r,
    const int* __restrict__ ss, const int* __restrict__ rowptr) {
  const int wid = threadIdx.x >> 6;
  const int lane = threadIdx.x & 63;
  const int n = blockIdx.x * 4 + wid;
  const int beg = rowptr[n];
  const int end = rowptr[n + 1];
  float ax = 0.f, ay = 0.f;
  for (int i = beg; i < end; i += 4) {
    const int e1 = (i + 1 < end) ? i + 1 : i;
    const int e2 = (i + 2 < end) ? i + 2 : i;
    const int e3 = (i + 3 < end) ? i + 3 : i;
    const int s0 = NT_LOAD(ss + i);
    const int s1 = NT_LOAD(ss + e1);
    const int s2 = NT_LOAD(ss + e2);
    const int s3 = NT_LOAD(ss + e3);
    const float r0 = NT_LOAD(r + i);
    const float r1 = (i + 1 < end) ? NT_LOAD(r + e1) : 0.f;
    const float r2 = (i + 2 < end) ? NT_LOAD(r + e2) : 0.f;
    const float r3 = (i + 3 < end) ? NT_LOAD(r + e3) : 0.f;
    const unsigned int f0 = f8[(size_t)s0 * 64 + lane];
    const unsigned int f1 = f8[(size_t)s1 * 64 + lane];
    const unsigned int f2 = f8[(size_t)s2 * 64 + lane];
    const unsigned int f3 = f8[(size_t)s3 * 64 + lane];
    const v2f d0 = dec_lo(f0);
    const v2f d1 = dec_lo(f1);
    const v2f d2 = dec_lo(f2);
    const v2f d3 = dec_lo(f3);
    ax = fmaf(r0, d0.x, ax);
    ay = fmaf(r0, d0.y, ay);
    ax = fmaf(r1, d1.x, ax);
    ay = fmaf(r1, d1.y, ay);
    ax = fmaf(r2, d2.x, ax);
    ay = fmaf(r2, d2.y, ay);
    ax = fmaf(r3, d3.x, ax);
    ay = fmaf(r3, d3.y, ay);
  }
  const size_t idx = (size_t)n * 64 + lane;
  const v2f fn = dec_lo((unsigned int)f8[idx]);
  const float dg = deg[n];
  const float cx = dg * fn.x - ax;
  const float cy = dg * fn.y - ay;
  float vx, vy;
  if (FIRST) {
    vx = -EPS_ * cx;
    vy = -EPS_ * cy;
    vb[idx] = pk(vx, vy);
  } else {
    const v2f dsv = dec_lo((unsigned int)diss8[idx]);
    const unsigned int vv = vb[idx];
    vx = b2f((u16)(vv & 0xffffu));
    vy = b2f((u16)(vv >> 16));
    vx = vx - EPS_ * (cx + dsv.x * vx);
    vy = vy - EPS_ * (cy + dsv.y * vy);
  }
  const unsigned int xv = xb[idx];
  const float nx = b2f((u16)(xv & 0xffffu)) + EPS_ * vx;
  const float ny = b2f((u16)(xv >> 16)) + EPS_ * vy;
  xb[idx] = pk(nx, ny);
}

extern "C" void kernel_launch(void* const* d_in, const int* in_sizes, int n_in,
                              void* d_out, int out_size, void* d_ws,
                              size_t ws_size, hipStream_t stream) {
  const float* x_in = (const float*)d_in[0];
  const int* ei = (const int*)d_in[1];
  const int* src = ei;
  const int* dst = ei + E_;
  const float* emb_w = (const float*)d_in[2];
  const float* emb_b = (const float*)d_in[3];
  const float* lap_w = (const float*)d_in[4];
  const float* er_w1 = (const float*)d_in[5];
  const float* er_b1 = (const float*)d_in[6];
  const float* er_w2 = (const float*)d_in[7];
  const float* er_b2 = (const float*)d_in[8];
  const float* diss_w = (const float*)d_in[9];
  const float* diss_b = (const float*)d_in[10];
  const float* mlp_w1 = (const float*)d_in[11];
  const float* mlp_b1 = (const float*)d_in[12];
  const float* mlp_w2 = (const float*)d_in[13];
  const float* mlp_b2 = (const float*)d_in[14];
  const float* ro_w = (const float*)d_in[15];
  const float* ro_b = (const float*)d_in[16];
  float* out = (float*)d_out;

  // workspace layout
  const size_t NF = (size_t)N_ * H_;
  u16* xb = (u16*)d_ws;             // NF bf16 (x state)
  u16* vb = xb + NF;                // NF bf16 (v)
  u16* xinb = vb + NF;              // NF bf16 (x_in converted)
  u8* P1 = (u8*)(xinb + NF);        // NF fp8
  u8* P2 = P1 + NF;                 // NF fp8
  u8* F8 = P2 + NF;                 // NF fp8
  u8* D8 = F8 + NF;                 // NF fp8
  float* r = (float*)(D8 + NF);     // E (dst-sorted)
  float* deg = r + E_;              // N
  int* rowptr = (int*)(deg + N_);   // N+1
  int* cursor = rowptr + (N_ + 1);  // N
  int* ss = cursor + N_;            // E (src, dst-sorted)
  int* ds = ss + E_;                // E (dst, dst-sorted)
  int* psum = ds + E_;              // NSC
  u16* wb = (u16*)(psum + NSC);     // WB_TOTAL bf16
  float* bp512 = (float*)(wb + WB_TOTAL + (WB_TOTAL & 1));  // 3*512
  float* bfd = bp512 + 3 * 512;     // 3*256

  const int g64 = (N_ + 63) / 64;  // 782
  const int e_grid = (E_ + 255) / 256;

  // pack weights/biases, convert x_in
  convall_k<<<(WB_TOTAL + 255) / 256, 256, 0, stream>>>(
      emb_w, ro_w, er_w1, lap_w, diss_w, mlp_w1, mlp_w2, wb);
  biasp_k<<<3, 512, 0, stream>>>(er_b1, diss_b, bp512, bfd);
  convx_k<<<(int)(NF / 1024), 256, 0, stream>>>(x_in, xinb);

  // CSR by dst (topology fixed for whole launch)
  hipMemsetAsync(cursor, 0, N_ * sizeof(int), stream);
  hist_k<<<e_grid, 256, 0, stream>>>(dst, cursor);
  partial_k<<<NSC, 1024, 0, stream>>>(cursor, psum);
  scanp_k<<<1, 64, 0, stream>>>(psum);
  rowptr_k<<<NSC, 1024, 0, stream>>>(cursor, psum, rowptr, cursor);
  permute_k<<<e_grid, 256, 0, stream>>>(src, dst, cursor, ss, ds);

  // xb = emb(x_in)  (bf16 out, 128 cols -> 2 waves)
  mmw_k<2, 0, 0, 0, 0, 0><<<g64, 128, 0, stream>>>(
      xinb, wb + WB_EMB, emb_b, xb, nullptr, nullptr, nullptr);

  for (int b = 0; b < B_; ++b) {
    const u16* Wp = wb + WB_BLK + (size_t)b * 98304;   // 256 rows (er split)
    const u16* Wfd = Wp + 32768;                       // 256 rows (lap;diss)
    const u16* Wm1 = Wfd + 32768;
    const u16* Wm2 = Wm1 + 16384;
    const float* b2 = er_b2 + b;
    const float* w2 = er_w2 + (size_t)b * H_;

    // Merged it=0 GEMM: [P1 | P2 | f | diss] = xb @ [Wp;Wfd]^T  (512 cols,
    // Wp/Wfd contiguous in arena). acts: {none,none,none,relu}, all fp8.
    mmw_k<8, 1, 0, 0, 0, 1><<<g64, 512, 0, stream>>>(
        xb, Wp, bp512 + b * 512, P1, P2, F8, D8);
    hipMemsetAsync(deg, 0, N_ * sizeof(float), stream);
    edge_r_k<<<E_ / 8, 256, 0, stream>>>((const unsigned int*)P1,
                                         (const unsigned int*)P2, ss, ds, w2,
                                         b2, r, deg);

    // it = 0 (uses F8/D8 from merged GEMM)
    agg_update_k<true><<<N_ / 4, 256, 0, stream>>>(
        (unsigned int*)xb, (unsigned int*)vb, (const u16*)F8, (const u16*)D8,
        deg, r, ss, rowptr);
    // it = 1: recompute f/diss from updated xb
    mmw_k<4, 1, 0, 1, 0, 0><<<g64, 256, 0, stream>>>(
        xb, Wfd, bfd + b * 256, F8, D8, nullptr, nullptr);
    agg_update_k<false><<<N_ / 4, 256, 0, stream>>>(
        (unsigned int*)xb, (unsigned int*)vb, (const u16*)F8, (const u16*)D8,
        deg, r, ss, rowptr);

    // xb = tanh(xb@Wm1^T + bm1) @ Wm2^T + bm2
    mlp2_k<<<g64, 128, 0, stream>>>(xb, Wm1, mlp_b1 + b * H_, Wm2,
                                    mlp_b2 + b * H_, xb);
  }
  mmw_k<1, 2, 0, 0, 0, 0><<<g64, 64, 0, stream>>>(
      xb, wb + WB_RO, ro_b, out, nullptr, nullptr, nullptr);
}

// Round 10
// 726.241 us; speedup vs baseline: 5.1326x; 1.1054x over previous
//
#include <hip/hip_runtime.h>
#include <math.h>

constexpr int N_ = 50000;
constexpr int E_ = 400000;
constexpr int H_ = 128;
constexpr int OUT_ = 64;
constexpr int B_ = 3;
constexpr int ITERS_ = 2;
constexpr float EPS_ = 0.01f;

typedef unsigned short u16;
typedef unsigned char u8;
typedef short v8s __attribute__((ext_vector_type(8)));
typedef float v4f __attribute__((ext_vector_type(4)));
typedef float v2f __attribute__((ext_vector_type(2)));

__device__ inline float b2f(u16 u) {
  union { unsigned int i; float f; } c;
  c.i = ((unsigned int)u) << 16;
  return c.f;
}
__device__ inline u16 f2b(float f) {
  union { float f; unsigned int u; } c;
  c.f = f;
  unsigned int r = c.u + 0x7fffu + ((c.u >> 16) & 1u);  // RNE
  return (u16)(r >> 16);
}
__device__ inline unsigned int pk(float a, float b) {
  return (unsigned int)f2b(a) | ((unsigned int)f2b(b) << 16);
}

#if defined(__has_builtin)
#if __has_builtin(__builtin_nontemporal_load)
#define NT_LOAD(p) __builtin_nontemporal_load(p)
#endif
#endif
#ifndef NT_LOAD
#define NT_LOAD(p) (*(p))
#endif

// ---------------- fp8 e4m3 encode/decode (HW cvt if available) -------------
#if defined(__has_builtin)
#if __has_builtin(__builtin_amdgcn_cvt_pk_f32_fp8) && \
    __has_builtin(__builtin_amdgcn_cvt_pk_fp8_f32)
#define HW_FP8 1
#endif
#endif

#ifdef HW_FP8
__device__ inline v2f dec_lo(unsigned int v) {
  return __builtin_amdgcn_cvt_pk_f32_fp8(v, false);
}
__device__ inline v2f dec_hi(unsigned int v) {
  return __builtin_amdgcn_cvt_pk_f32_fp8(v, true);
}
__device__ inline u8 enc1(float x) {
  return (u8)(__builtin_amdgcn_cvt_pk_fp8_f32(x, x, 0, false) & 0xff);
}
#else
__device__ inline float fp8_dec1(u8 v) {
  const unsigned int s = v >> 7, e = (v >> 3) & 15, m = v & 7;
  float mag = e ? __uint_as_float(((e + 120u) << 23) | (m << 20))
                : (float)m * 0.001953125f;
  return s ? -mag : mag;
}
__device__ inline v2f dec_lo(unsigned int v) {
  v2f r;
  r.x = fp8_dec1((u8)(v & 0xff));
  r.y = fp8_dec1((u8)((v >> 8) & 0xff));
  return r;
}
__device__ inline v2f dec_hi(unsigned int v) {
  v2f r;
  r.x = fp8_dec1((u8)((v >> 16) & 0xff));
  r.y = fp8_dec1((u8)((v >> 24) & 0xff));
  return r;
}
__device__ inline u8 enc1(float x) {
  union { float f; unsigned int u; } c;
  c.f = x;
  const unsigned int sgn = (c.u >> 31) << 7;
  float af = fabsf(x);
  if (af >= 448.f) return (u8)(sgn | 0x7e);
  if (af < 0.015625f) {
    int m = (int)rintf(af * 512.f);
    if (m > 7) return (u8)(sgn | 0x08);
    return (u8)(sgn | m);
  }
  unsigned int u = c.u & 0x7fffffffu;
  u += 0x7ffffu + ((u >> 20) & 1u);
  unsigned int m3 = (u >> 20) & 7;
  int e8 = (int)(u >> 23) - 120;
  if (e8 >= 15 && m3 >= 7) return (u8)(sgn | 0x7e);
  if (e8 <= 0) {
    int m = (int)rintf(af * 512.f);
    if (m > 7) m = 7;
    return (u8)(sgn | m);
  }
  return (u8)(sgn | ((unsigned)e8 << 3) | m3);
}
#endif

// ---------------------------------------------------------------------------
// Register-budgeted MFMA GEMM (r9 post-mortem: 16 B-frags/wave overflowed the
// allocator -> per-row-tile reloads; 8 frags fit). Wave owns 32 cols x 64 rows:
// B = 8 v8s (32 VGPR, held across row loop), acc = 32 VGPR, A transient.
// Block = NWC waves col-split; grid.y = col-groups of NWC*32.
// A frag: lane l holds A[l&15][(l>>4)*8+j]; B frag: B[(l>>4)*8+j][l&15];
// D: row=(l>>4)*4+i, col=l&15.
// Output routing by 128-col segment: seg = n>>7 -> y0..y3 with act A0..A3.
// OT: 0 = bf16 (stride H), 1 = fp8 (stride H), 2 = fp32 (stride OUT_).
// ---------------------------------------------------------------------------
template <int NWC, int OT, int A0, int A1, int A2, int A3>
__global__ __launch_bounds__(NWC * 64) void gemm_k(
    const u16* __restrict__ Xb, const u16* __restrict__ Wb,
    const float* __restrict__ bias, void* __restrict__ y0,
    void* __restrict__ y1, void* __restrict__ y2, void* __restrict__ y3) {
  const int lane = threadIdx.x & 63;
  const int wv = threadIdx.x >> 6;
  const int rowbase = blockIdx.x * 64;
  const int cb = blockIdx.y * (NWC * 32) + wv * 32;
  const int bn = lane & 15;
  const int kc = (lane >> 4) * 8;

  v8s bf[2][4];
#pragma unroll
  for (int ct = 0; ct < 2; ++ct) {
    const u16* wp = Wb + (size_t)(cb + ct * 16 + bn) * H_ + kc;
#pragma unroll
    for (int ks = 0; ks < 4; ++ks) bf[ct][ks] = *(const v8s*)(wp + ks * 32);
  }

  v4f acc[2][4];
#pragma unroll
  for (int ct = 0; ct < 2; ++ct)
#pragma unroll
    for (int rt = 0; rt < 4; ++rt) acc[ct][rt] = (v4f)0.f;

#pragma unroll
  for (int rt = 0; rt < 4; ++rt) {
    int arow = rowbase + rt * 16 + bn;
    if (arow >= N_) arow = N_ - 1;
    v8s a[4];
#pragma unroll
    for (int ks = 0; ks < 4; ++ks)
      a[ks] = *(const v8s*)(Xb + (size_t)arow * H_ + ks * 32 + kc);
#pragma unroll
    for (int ct = 0; ct < 2; ++ct)
#pragma unroll
      for (int ks = 0; ks < 4; ++ks)
        acc[ct][rt] = __builtin_amdgcn_mfma_f32_16x16x32_bf16(
            a[ks], bf[ct][ks], acc[ct][rt], 0, 0, 0);
  }

  const int ncol = lane & 15;
  const int rsub = (lane >> 4) * 4;
#pragma unroll
  for (int ct = 0; ct < 2; ++ct) {
    const int n = cb + ct * 16 + ncol;
    const int seg = n >> 7;
    const float bv = bias[n];
    void* yp = (seg == 0) ? y0 : (seg == 1) ? y1 : (seg == 2) ? y2 : y3;
    const int act = (seg == 0) ? A0 : (seg == 1) ? A1 : (seg == 2) ? A2 : A3;
    const int off = n & 127;
#pragma unroll
    for (int rt = 0; rt < 4; ++rt) {
#pragma unroll
      for (int i = 0; i < 4; ++i) {
        const int r = rowbase + rt * 16 + rsub + i;
        if (r >= N_) continue;
        float yv = acc[ct][rt][i] + bv;
        if (act == 1) yv = fmaxf(yv, 0.f);
        if (act == 2) yv = tanhf(yv);
        if (OT == 0)
          ((u16*)yp)[(size_t)r * H_ + off] = f2b(yv);
        else if (OT == 1)
          ((u8*)yp)[(size_t)r * H_ + off] = enc1(yv);
        else
          ((float*)yp)[(size_t)r * OUT_ + n] = yv;
      }
    }
  }
}

// ---------------------------------------------------------------------------
// Fused MLP, register-budgeted: 4 waves x 32 cols, 64 rows/block.
// Yb = tanh(Xb@Wm1^T + bm1) @ Wm2^T + bm2. LDS tmp padded to 140 u16/row
// (row stride 70 dwords; 6*row mod 32 distinct for 16 rows -> conflict-free).
// In-place safe: block owns its 64 rows; layer-1 reads complete pre-barrier.
// ---------------------------------------------------------------------------
__global__ __launch_bounds__(256) void mlp3_k(
    const u16* __restrict__ Xb, const u16* __restrict__ Wm1,
    const float* __restrict__ bm1, const u16* __restrict__ Wm2,
    const float* __restrict__ bm2, u16* __restrict__ Yb) {
  __shared__ u16 tmp[64][140];
  const int lane = threadIdx.x & 63;
  const int wv = threadIdx.x >> 6;
  const int rowbase = blockIdx.x * 64;
  const int cb = wv * 32;
  const int bn = lane & 15;
  const int kc = (lane >> 4) * 8;
  const int ncol = lane & 15;
  const int rsub = (lane >> 4) * 4;

  // ---- layer 1 ----
  v8s bf[2][4];
#pragma unroll
  for (int ct = 0; ct < 2; ++ct) {
    const u16* wp = Wm1 + (size_t)(cb + ct * 16 + bn) * H_ + kc;
#pragma unroll
    for (int ks = 0; ks < 4; ++ks) bf[ct][ks] = *(const v8s*)(wp + ks * 32);
  }
  v4f acc[2][4];
#pragma unroll
  for (int ct = 0; ct < 2; ++ct)
#pragma unroll
    for (int rt = 0; rt < 4; ++rt) acc[ct][rt] = (v4f)0.f;
#pragma unroll
  for (int rt = 0; rt < 4; ++rt) {
    int arow = rowbase + rt * 16 + bn;
    if (arow >= N_) arow = N_ - 1;
    v8s a[4];
#pragma unroll
    for (int ks = 0; ks < 4; ++ks)
      a[ks] = *(const v8s*)(Xb + (size_t)arow * H_ + ks * 32 + kc);
#pragma unroll
    for (int ct = 0; ct < 2; ++ct)
#pragma unroll
      for (int ks = 0; ks < 4; ++ks)
        acc[ct][rt] = __builtin_amdgcn_mfma_f32_16x16x32_bf16(
            a[ks], bf[ct][ks], acc[ct][rt], 0, 0, 0);
  }
#pragma unroll
  for (int ct = 0; ct < 2; ++ct) {
    const float bv = bm1[cb + ct * 16 + ncol];
#pragma unroll
    for (int rt = 0; rt < 4; ++rt)
#pragma unroll
      for (int i = 0; i < 4; ++i)
        tmp[rt * 16 + rsub + i][cb + ct * 16 + ncol] =
            f2b(tanhf(acc[ct][rt][i] + bv));
  }
  __syncthreads();

  // ---- layer 2 ----
#pragma unroll
  for (int ct = 0; ct < 2; ++ct) {
    const u16* wp = Wm2 + (size_t)(cb + ct * 16 + bn) * H_ + kc;
#pragma unroll
    for (int ks = 0; ks < 4; ++ks) bf[ct][ks] = *(const v8s*)(wp + ks * 32);
  }
#pragma unroll
  for (int ct = 0; ct < 2; ++ct)
#pragma unroll
    for (int rt = 0; rt < 4; ++rt) acc[ct][rt] = (v4f)0.f;
#pragma unroll
  for (int rt = 0; rt < 4; ++rt) {
    const int arow = rt * 16 + bn;
    v8s a[4];
#pragma unroll
    for (int ks = 0; ks < 4; ++ks)
      a[ks] = *(const v8s*)&tmp[arow][ks * 32 + kc];
#pragma unroll
    for (int ct = 0; ct < 2; ++ct)
#pragma unroll
      for (int ks = 0; ks < 4; ++ks)
        acc[ct][rt] = __builtin_amdgcn_mfma_f32_16x16x32_bf16(
            a[ks], bf[ct][ks], acc[ct][rt], 0, 0, 0);
  }
#pragma unroll
  for (int ct = 0; ct < 2; ++ct) {
    const float bv = bm2[cb + ct * 16 + ncol];
#pragma unroll
    for (int rt = 0; rt < 4; ++rt)
#pragma unroll
      for (int i = 0; i < 4; ++i) {
        const int r = rowbase + rt * 16 + rsub + i;
        if (r < N_)
          Yb[(size_t)r * H_ + cb + ct * 16 + ncol] = f2b(acc[ct][rt][i] + bv);
      }
  }
}

// ---------------------------------------------------------------------------
// Weight pack: all fp32 weights -> one bf16 arena.
// ---------------------------------------------------------------------------
constexpr int WB_EMB = 0;                 // 128x128
constexpr int WB_RO = 16384;              // 64x128
constexpr int WB_BLK = 24576;             // per block: 98304
constexpr int WB_TOTAL = 24576 + 3 * 98304;  // 319488

__global__ void convall_k(const float* __restrict__ emb_w,
                          const float* __restrict__ ro_w,
                          const float* __restrict__ er_w1,
                          const float* __restrict__ lap_w,
                          const float* __restrict__ diss_w,
                          const float* __restrict__ mlp_w1,
                          const float* __restrict__ mlp_w2,
                          u16* __restrict__ wb) {
  const int idx = blockIdx.x * 256 + threadIdx.x;
  if (idx >= WB_TOTAL) return;
  const float* src;
  size_t soff;
  if (idx < 16384) {
    src = emb_w; soff = idx;
  } else if (idx < 24576) {
    src = ro_w; soff = idx - 16384;
  } else {
    int t = idx - 24576;
    const int b = t / 98304;
    t -= b * 98304;
    if (t < 32768) {  // Wp: rows<128 -> er_w1 cols 0-127; rows>=128 -> cols 128-255
      const int r = t >> 7, c = t & 127;
      src = er_w1 + (size_t)b * 32768;
      soff = (r < 128) ? ((size_t)r * 256 + c) : ((size_t)(r - 128) * 256 + 128 + c);
    } else if (t < 65536) {  // Wfd: rows<128 lap, rows>=128 diss
      const int u = t - 32768;
      if (u < 16384) { src = lap_w + (size_t)b * 16384; soff = u; }
      else { src = diss_w + (size_t)b * 16384; soff = u - 16384; }
    } else if (t < 81920) {
      src = mlp_w1 + (size_t)b * 16384; soff = t - 65536;
    } else {
      src = mlp_w2 + (size_t)b * 16384; soff = t - 81920;
    }
  }
  wb[idx] = f2b(src[soff]);
}

// bp512[b] = [er_b1[b]; 0(128); 0(128); diss_b[b]]; bfd[b] = [0; diss_b[b]]
__global__ void biasp_k(const float* __restrict__ er_b1,
                        const float* __restrict__ diss_b,
                        float* __restrict__ bp512, float* __restrict__ bfd) {
  const int b = blockIdx.x, t = threadIdx.x;  // 512 threads
  float v = 0.f;
  if (t < 128) v = er_b1[b * 128 + t];
  else if (t >= 384) v = diss_b[b * 128 + (t - 384)];
  bp512[b * 512 + t] = v;
  if (t < 256) bfd[b * 256 + t] = (t < 128) ? 0.f : diss_b[b * 128 + (t - 128)];
}

// x_in fp32 -> bf16
__global__ void convx_k(const float* __restrict__ src, u16* __restrict__ dst) {
  const size_t i = ((size_t)blockIdx.x * 256 + threadIdx.x) * 4;
  const float4 v = *(const float4*)(src + i);
  ushort4 o;
  o.x = f2b(v.x); o.y = f2b(v.y); o.z = f2b(v.z); o.w = f2b(v.w);
  *(ushort4*)(dst + i) = o;
}

// ---------------------------------------------------------------------------
// Edge resistance, dst-sorted order, fp8 P tables (128 B rows):
//   r[i] = |w2 . relu(P1[ss[i]]+P2[ds[i]]) + b2|;  deg[src] += r.
// ---------------------------------------------------------------------------
__global__ __launch_bounds__(256) void edge_r_k(
    const unsigned int* __restrict__ P1, const unsigned int* __restrict__ P2,
    const int* __restrict__ ss, const int* __restrict__ ds,
    const float* __restrict__ w2, const float* __restrict__ b2,
    float* __restrict__ r_out, float* __restrict__ deg) {
  const int tid = threadIdx.x;
  const int lane = tid & 63;
  const int half = lane >> 5;
  const int l = lane & 31;
  const int wid = tid >> 6;
  const size_t e = (size_t)blockIdx.x * 8 + wid * 2 + half;
  const float4 wv = *(const float4*)(w2 + l * 4);
  const int s = ss[e];
  const int d = ds[e];
  const unsigned int a4 = P1[(size_t)s * 32 + l];
  const unsigned int c4 = P2[(size_t)d * 32 + l];
  const v2f alo = dec_lo(a4), ahi = dec_hi(a4);
  const v2f clo = dec_lo(c4), chi = dec_hi(c4);
  float sum = fmaxf(alo.x + clo.x, 0.f) * wv.x;
  sum = fmaf(fmaxf(alo.y + clo.y, 0.f), wv.y, sum);
  sum = fmaf(fmaxf(ahi.x + chi.x, 0.f), wv.z, sum);
  sum = fmaf(fmaxf(ahi.y + chi.y, 0.f), wv.w, sum);
#pragma unroll
  for (int off = 16; off > 0; off >>= 1) sum += __shfl_xor(sum, off);
  if (l == 0) {
    const float rv = fabsf(sum + b2[0]);
    r_out[e] = rv;
    atomicAdd(&deg[s], rv);
  }
}

// ---------------------------------------------------------------------------
// CSR build (by dst): hist -> parallel scan -> sorted src/dst arrays.
// ---------------------------------------------------------------------------
constexpr int NSC = (N_ + 1023) / 1024;  // 49

__global__ void hist_k(const int* __restrict__ dst, int* __restrict__ cnt) {
  const int e = blockIdx.x * 256 + threadIdx.x;
  if (e < E_) atomicAdd(&cnt[dst[e]], 1);
}

__global__ __launch_bounds__(1024) void partial_k(const int* __restrict__ cnt,
                                                  int* __restrict__ psum) {
  __shared__ int sm[1024];
  const int tid = threadIdx.x;
  const int i = blockIdx.x * 1024 + tid;
  sm[tid] = (i < N_) ? cnt[i] : 0;
  __syncthreads();
  for (int off = 512; off > 0; off >>= 1) {
    if (tid < off) sm[tid] += sm[tid + off];
    __syncthreads();
  }
  if (tid == 0) psum[blockIdx.x] = sm[0];
}

__global__ __launch_bounds__(64) void scanp_k(int* __restrict__ psum) {
  const int tid = threadIdx.x;
  int v = (tid < NSC) ? psum[tid] : 0;
  const int orig = v;
#pragma unroll
  for (int off = 1; off < 64; off <<= 1) {
    const int u = __shfl_up(v, off);
    if (tid >= off) v += u;
  }
  if (tid < NSC) psum[tid] = v - orig;  // exclusive
}

__global__ __launch_bounds__(1024) void rowptr_k(const int* __restrict__ cnt,
                                                 const int* __restrict__ psum,
                                                 int* __restrict__ rowptr,
                                                 int* __restrict__ cursor) {
  __shared__ int sm[1024];
  const int tid = threadIdx.x;
  const int i = blockIdx.x * 1024 + tid;
  const int orig = (i < N_) ? cnt[i] : 0;
  sm[tid] = orig;
  __syncthreads();
  for (int off = 1; off < 1024; off <<= 1) {
    const int mine = sm[tid];
    const int u = (tid >= off) ? sm[tid - off] : 0;
    __syncthreads();
    sm[tid] = mine + u;
    __syncthreads();
  }
  const int excl = sm[tid] - orig + psum[blockIdx.x];
  if (i < N_) {
    rowptr[i] = excl;
    cursor[i] = excl;
  }
  if (i == 0) rowptr[N_] = E_;
}

__global__ void permute_k(const int* __restrict__ src,
                          const int* __restrict__ dst, int* __restrict__ cursor,
                          int* __restrict__ ss, int* __restrict__ ds) {
  const int e = blockIdx.x * 256 + threadIdx.x;
  if (e < E_) {
    const int d = dst[e];
    const int p = atomicAdd(&cursor[d], 1);
    ss[p] = src[e];
    ds[p] = d;
  }
}

// ---------------------------------------------------------------------------
// Fused aggregate + update. f/diss fp8 (128 B rows), xb/vb bf16.
// One wave per node; 4-deep unrolled gather (latency cover, r7 fix).
// ---------------------------------------------------------------------------
template <bool FIRST>
__global__ __launch_bounds__(256) void agg_update_k(
    unsigned int* __restrict__ xb, unsigned int* __restrict__ vb,
    const u16* __restrict__ f8, const u16* __restrict__ diss8,
    const float* __restrict__ deg, const float* __restrict__ r,
    const int* __restrict__ ss, const int* __restrict__ rowptr) {
  const int wid = threadIdx.x >> 6;
  const int lane = threadIdx.x & 63;
  const int n = blockIdx.x * 4 + wid;
  const int beg = rowptr[n];
  const int end = rowptr[n + 1];
  float ax = 0.f, ay = 0.f;
  for (int i = beg; i < end; i += 4) {
    const int e1 = (i + 1 < end) ? i + 1 : i;
    const int e2 = (i + 2 < end) ? i + 2 : i;
    const int e3 = (i + 3 < end) ? i + 3 : i;
    const int s0 = NT_LOAD(ss + i);
    const int s1 = NT_LOAD(ss + e1);
    const int s2 = NT_LOAD(ss + e2);
    const int s3 = NT_LOAD(ss + e3);
    const float r0 = NT_LOAD(r + i);
    const float r1 = (i + 1 < end) ? NT_LOAD(r + e1) : 0.f;
    const float r2 = (i + 2 < end) ? NT_LOAD(r + e2) : 0.f;
    const float r3 = (i + 3 < end) ? NT_LOAD(r + e3) : 0.f;
    const unsigned int f0 = f8[(size_t)s0 * 64 + lane];
    const unsigned int f1 = f8[(size_t)s1 * 64 + lane];
    const unsigned int f2 = f8[(size_t)s2 * 64 + lane];
    const unsigned int f3 = f8[(size_t)s3 * 64 + lane];
    const v2f d0 = dec_lo(f0);
    const v2f d1 = dec_lo(f1);
    const v2f d2 = dec_lo(f2);
    const v2f d3 = dec_lo(f3);
    ax = fmaf(r0, d0.x, ax);
    ay = fmaf(r0, d0.y, ay);
    ax = fmaf(r1, d1.x, ax);
    ay = fmaf(r1, d1.y, ay);
    ax = fmaf(r2, d2.x, ax);
    ay = fmaf(r2, d2.y, ay);
    ax = fmaf(r3, d3.x, ax);
    ay = fmaf(r3, d3.y, ay);
  }
  const size_t idx = (size_t)n * 64 + lane;
  const v2f fn = dec_lo((unsigned int)f8[idx]);
  const float dg = deg[n];
  const float cx = dg * fn.x - ax;
  const float cy = dg * fn.y - ay;
  float vx, vy;
  if (FIRST) {
    vx = -EPS_ * cx;
    vy = -EPS_ * cy;
    vb[idx] = pk(vx, vy);
  } else {
    const v2f dsv = dec_lo((unsigned int)diss8[idx]);
    const unsigned int vv = vb[idx];
    vx = b2f((u16)(vv & 0xffffu));
    vy = b2f((u16)(vv >> 16));
    vx = vx - EPS_ * (cx + dsv.x * vx);
    vy = vy - EPS_ * (cy + dsv.y * vy);
  }
  const unsigned int xv = xb[idx];
  const float nx = b2f((u16)(xv & 0xffffu)) + EPS_ * vx;
  const float ny = b2f((u16)(xv >> 16)) + EPS_ * vy;
  xb[idx] = pk(nx, ny);
}

extern "C" void kernel_launch(void* const* d_in, const int* in_sizes, int n_in,
                              void* d_out, int out_size, void* d_ws,
                              size_t ws_size, hipStream_t stream) {
  const float* x_in = (const float*)d_in[0];
  const int* ei = (const int*)d_in[1];
  const int* src = ei;
  const int* dst = ei + E_;
  const float* emb_w = (const float*)d_in[2];
  const float* emb_b = (const float*)d_in[3];
  const float* lap_w = (const float*)d_in[4];
  const float* er_w1 = (const float*)d_in[5];
  const float* er_b1 = (const float*)d_in[6];
  const float* er_w2 = (const float*)d_in[7];
  const float* er_b2 = (const float*)d_in[8];
  const float* diss_w = (const float*)d_in[9];
  const float* diss_b = (const float*)d_in[10];
  const float* mlp_w1 = (const float*)d_in[11];
  const float* mlp_b1 = (const float*)d_in[12];
  const float* mlp_w2 = (const float*)d_in[13];
  const float* mlp_b2 = (const float*)d_in[14];
  const float* ro_w = (const float*)d_in[15];
  const float* ro_b = (const float*)d_in[16];
  float* out = (float*)d_out;

  // workspace layout
  const size_t NF = (size_t)N_ * H_;
  u16* xb = (u16*)d_ws;             // NF bf16 (x state)
  u16* vb = xb + NF;                // NF bf16 (v)
  u16* xinb = vb + NF;              // NF bf16 (x_in converted)
  u8* P1 = (u8*)(xinb + NF);        // NF fp8
  u8* P2 = P1 + NF;                 // NF fp8
  u8* F8 = P2 + NF;                 // NF fp8
  u8* D8 = F8 + NF;                 // NF fp8
  float* r = (float*)(D8 + NF);     // E (dst-sorted)
  float* deg = r + E_;              // N
  int* rowptr = (int*)(deg + N_);   // N+1
  int* cursor = rowptr + (N_ + 1);  // N
  int* ss = cursor + N_;            // E (src, dst-sorted)
  int* ds = ss + E_;                // E (dst, dst-sorted)
  int* psum = ds + E_;              // NSC
  u16* wb = (u16*)(psum + NSC);     // WB_TOTAL bf16
  float* bp512 = (float*)(wb + WB_TOTAL + (WB_TOTAL & 1));  // 3*512
  float* bfd = bp512 + 3 * 512;     // 3*256

  const int g64 = (N_ + 63) / 64;  // 782
  const int e_grid = (E_ + 255) / 256;

  // pack weights/biases, convert x_in
  convall_k<<<(WB_TOTAL + 255) / 256, 256, 0, stream>>>(
      emb_w, ro_w, er_w1, lap_w, diss_w, mlp_w1, mlp_w2, wb);
  biasp_k<<<3, 512, 0, stream>>>(er_b1, diss_b, bp512, bfd);
  convx_k<<<(int)(NF / 1024), 256, 0, stream>>>(x_in, xinb);

  // CSR by dst (topology fixed for whole launch)
  hipMemsetAsync(cursor, 0, N_ * sizeof(int), stream);
  hist_k<<<e_grid, 256, 0, stream>>>(dst, cursor);
  partial_k<<<NSC, 1024, 0, stream>>>(cursor, psum);
  scanp_k<<<1, 64, 0, stream>>>(psum);
  rowptr_k<<<NSC, 1024, 0, stream>>>(cursor, psum, rowptr, cursor);
  permute_k<<<e_grid, 256, 0, stream>>>(src, dst, cursor, ss, ds);

  // xb = emb(x_in)  (bf16 out, 128 cols)
  gemm_k<4, 0, 0, 0, 0, 0><<<dim3(g64, 1), 256, 0, stream>>>(
      xinb, wb + WB_EMB, emb_b, xb, nullptr, nullptr, nullptr);

  for (int b = 0; b < B_; ++b) {
    const u16* Wp = wb + WB_BLK + (size_t)b * 98304;   // 256 rows (er split)
    const u16* Wfd = Wp + 32768;                       // 256 rows (lap;diss)
    const u16* Wm1 = Wfd + 32768;
    const u16* Wm2 = Wm1 + 16384;
    const float* b2 = er_b2 + b;
    const float* w2 = er_w2 + (size_t)b * H_;

    // Merged it=0 GEMM: [P1 | P2 | f | diss] = xb @ [Wp;Wfd]^T (512 cols).
    gemm_k<4, 1, 0, 0, 0, 1><<<dim3(g64, 4), 256, 0, stream>>>(
        xb, Wp, bp512 + b * 512, P1, P2, F8, D8);
    hipMemsetAsync(deg, 0, N_ * sizeof(float), stream);
    edge_r_k<<<E_ / 8, 256, 0, stream>>>((const unsigned int*)P1,
                                         (const unsigned int*)P2, ss, ds, w2,
                                         b2, r, deg);

    // it = 0 (uses F8/D8 from merged GEMM)
    agg_update_k<true><<<N_ / 4, 256, 0, stream>>>(
        (unsigned int*)xb, (unsigned int*)vb, (const u16*)F8, (const u16*)D8,
        deg, r, ss, rowptr);
    // it = 1: recompute f/diss from updated xb
    gemm_k<4, 1, 0, 1, 0, 0><<<dim3(g64, 2), 256, 0, stream>>>(
        xb, Wfd, bfd + b * 256, F8, D8, nullptr, nullptr);
    agg_update_k<false><<<N_ / 4, 256, 0, stream>>>(
        (unsigned int*)xb, (unsigned int*)vb, (const u16*)F8, (const u16*)D8,
        deg, r, ss, rowptr);

    // xb = tanh(xb@Wm1^T + bm1) @ Wm2^T + bm2
    mlp3_k<<<g64, 256, 0, stream>>>(xb, Wm1, mlp_b1 + b * H_, Wm2,
                                    mlp_b2 + b * H_, xb);
  }
  gemm_k<2, 2, 0, 0, 0, 0><<<dim3(g64, 1), 128, 0, stream>>>(
      xb, wb + WB_RO, ro_b, out, nullptr, nullptr, nullptr);
}